// Round 1
// baseline (2642.601 us; speedup 1.0000x reference)
//
#include <hip/hip_runtime.h>
#include <math.h>

#define NN 16384
#define EE 262144
#define HH 256

#define INV_SQRT_3f 0.57735026918962576f
#define INV_SQRT_Hf 0.0625f
#define INV_SQRT_2f 0.70710678118654752f
#define SSILU_SCALE 1.6666666666666667f

typedef __attribute__((ext_vector_type(8))) short bf16x8;
typedef __attribute__((ext_vector_type(4))) float f32x4;

__device__ __forceinline__ float ssilu_f(float v) {
    return v * (1.0f / (1.0f + __expf(-v))) * SSILU_SCALE;
}
__device__ __forceinline__ float b2f(short s) {
    unsigned int u = ((unsigned int)(unsigned short)s) << 16;
    return __uint_as_float(u);
}
__device__ __forceinline__ short f2b(float f) {
    unsigned int u = __float_as_uint(f);
    unsigned int r = (u + 0x7fff + ((u >> 16) & 1)) >> 16;
    return (short)r;
}

// ---------------- LayerNorm: one block per row, split-bf16 out ----------------
__global__ void __launch_bounds__(256) ln_kernel(const float* __restrict__ x,
                                                 const float* __restrict__ g,
                                                 const float* __restrict__ b,
                                                 short* __restrict__ oh,
                                                 short* __restrict__ ol) {
    int n = blockIdx.x;
    int t = threadIdx.x;
    float v = x[(long)n * HH + t];
    float s = v, s2 = v * v;
    #pragma unroll
    for (int off = 32; off > 0; off >>= 1) {
        s  += __shfl_down(s, off);
        s2 += __shfl_down(s2, off);
    }
    __shared__ float red[8];
    int wave = t >> 6, lane = t & 63;
    if (lane == 0) { red[wave] = s; red[4 + wave] = s2; }
    __syncthreads();
    __shared__ float mr[2];
    if (t == 0) {
        float ts = red[0] + red[1] + red[2] + red[3];
        float ts2 = red[4] + red[5] + red[6] + red[7];
        float mean = ts * (1.0f / HH);
        float var = ts2 * (1.0f / HH) - mean * mean;
        mr[0] = mean;
        mr[1] = rsqrtf(var + 1e-5f);
    }
    __syncthreads();
    float o = (v - mr[0]) * mr[1] * g[t] + b[t];
    short hh = f2b(o);
    oh[(long)n * HH + t] = hh;
    ol[(long)n * HH + t] = f2b(o - b2f(hh));
}

// ---- ALL weight transposes + hi/lo splits in ONE kernel (now incl. W_rbf) ----
struct WtArgs {
    const float* W[12];
    int K[12];
    int N[12];
    int off[13];   // cumulative element offsets; off[12] = total
};

__global__ void __launch_bounds__(256) wt_split_all(WtArgs a,
                                                    short* __restrict__ WTh,
                                                    short* __restrict__ WTl) {
    int idx = blockIdx.x * 256 + threadIdx.x;
    int s = 0;
    #pragma unroll
    for (int i = 1; i < 12; i++) s += (idx >= a.off[i]) ? 1 : 0;
    int local = idx - a.off[s];
    int K = a.K[s], N = a.N[s];
    int k = local / N, n = local - k * N;
    float w = a.W[s][local];
    short hh = f2b(w);
    long o = (long)a.off[s] + (long)n * K + k;
    WTh[o] = hh;
    WTl[o] = f2b(w - b2f(hh));
}

// ---- fp32 -> hi/lo split (count % 1024 == 0) ----
__global__ void __launch_bounds__(256) split4_kernel(const float* __restrict__ in,
                                                     short* __restrict__ h,
                                                     short* __restrict__ l) {
    long i = ((long)blockIdx.x * 256 + threadIdx.x) * 4;
    float4 v = *(const float4*)(in + i);
    short4 oh, ol;
    oh.x = f2b(v.x); ol.x = f2b(v.x - b2f(oh.x));
    oh.y = f2b(v.y); ol.y = f2b(v.y - b2f(oh.y));
    oh.z = f2b(v.z); ol.z = f2b(v.z - b2f(oh.z));
    oh.w = f2b(v.w); ol.w = f2b(v.w - b2f(oh.w));
    *(short4*)(h + i) = oh;
    *(short4*)(l + i) = ol;
}

// ---- split-bf16 MFMA GEMM v2: C = (Ah+Al)(M,K) @ (Wh+Wl)^T(N,K) [+bias][ssilu]
// C ~= Ah@Wh + Al@Wh + Ah@Wl. block = 4 waves, 128 rows x 64 cols;
// wave = 32 rows (2 frags) x 64 cols (4 tiles) = 8 acc tiles.
// K-loop chunk 32 with register prefetch of next chunk.
// M%128==0, N%64==0, K%32==0. out: Cl!=null -> split; act&2 -> bf16; else fp32.
__global__ void __launch_bounds__(256) mfma_gemm(const short* __restrict__ Ah,
                                                 const short* __restrict__ Al,
                                                 const short* __restrict__ Wh,
                                                 const short* __restrict__ Wl,
                                                 const float* __restrict__ bias,
                                                 void* __restrict__ Ch,
                                                 short* __restrict__ Cl,
                                                 int M, int K, int N, int act) {
    int tid = threadIdx.x;
    int wave = tid >> 6, lane = tid & 63;
    int quad = lane >> 4, l16 = lane & 15;
    long bm = (long)blockIdx.x * 128 + wave * 32;
    long bn = (long)blockIdx.y * 64;
    long a0 = (bm + l16) * K + quad * 8;
    long a1 = a0 + (long)16 * K;
    long w0 = (bn + l16) * K + quad * 8;

    f32x4 acc[2][4];
    #pragma unroll
    for (int f = 0; f < 2; f++)
        #pragma unroll
        for (int t = 0; t < 4; t++) acc[f][t] = (f32x4){0.f, 0.f, 0.f, 0.f};

    bf16x8 cah[2], cal[2], cbh[4], cbl[4];
    cah[0] = *(const bf16x8*)(Ah + a0);
    cah[1] = *(const bf16x8*)(Ah + a1);
    cal[0] = *(const bf16x8*)(Al + a0);
    cal[1] = *(const bf16x8*)(Al + a1);
    #pragma unroll
    for (int t = 0; t < 4; t++) {
        long wo = w0 + (long)t * 16 * K;
        cbh[t] = *(const bf16x8*)(Wh + wo);
        cbl[t] = *(const bf16x8*)(Wl + wo);
    }

    for (int k0 = 0; k0 < K; k0 += 32) {
        int k1 = k0 + 32;
        bf16x8 nah[2], nal[2], nbh[4], nbl[4];
        if (k1 < K) {
            nah[0] = *(const bf16x8*)(Ah + a0 + k1);
            nah[1] = *(const bf16x8*)(Ah + a1 + k1);
            nal[0] = *(const bf16x8*)(Al + a0 + k1);
            nal[1] = *(const bf16x8*)(Al + a1 + k1);
            #pragma unroll
            for (int t = 0; t < 4; t++) {
                long wo = w0 + (long)t * 16 * K + k1;
                nbh[t] = *(const bf16x8*)(Wh + wo);
                nbl[t] = *(const bf16x8*)(Wl + wo);
            }
        }
        #pragma unroll
        for (int t = 0; t < 4; t++) {
            #pragma unroll
            for (int f = 0; f < 2; f++) {
                acc[f][t] = __builtin_amdgcn_mfma_f32_16x16x32_bf16(cah[f], cbh[t], acc[f][t], 0, 0, 0);
                acc[f][t] = __builtin_amdgcn_mfma_f32_16x16x32_bf16(cal[f], cbh[t], acc[f][t], 0, 0, 0);
                acc[f][t] = __builtin_amdgcn_mfma_f32_16x16x32_bf16(cah[f], cbl[t], acc[f][t], 0, 0, 0);
            }
        }
        if (k1 < K) {
            cah[0] = nah[0]; cah[1] = nah[1];
            cal[0] = nal[0]; cal[1] = nal[1];
            #pragma unroll
            for (int t = 0; t < 4; t++) { cbh[t] = nbh[t]; cbl[t] = nbl[t]; }
        }
    }

    #pragma unroll
    for (int f = 0; f < 2; f++) {
        long row0 = bm + f * 16 + quad * 4;
        #pragma unroll
        for (int t = 0; t < 4; t++) {
            long col = bn + t * 16 + l16;
            float bv = bias ? bias[col] : 0.f;
            #pragma unroll
            for (int r = 0; r < 4; r++) {
                float v = acc[f][t][r] + bv;
                if (act & 1) v = ssilu_f(v);
                long idx = (row0 + r) * N + col;
                if (Cl) {
                    short hh = f2b(v);
                    ((short*)Ch)[idx] = hh;
                    Cl[idx] = f2b(v - b2f(hh));
                } else if (act & 2) {
                    ((short*)Ch)[idx] = f2b(v);
                } else {
                    ((float*)Ch)[idx] = v;
                }
            }
        }
    }
}

// ---------------- edge sort (counting sort by dst) ----------------
__global__ void __launch_bounds__(256) zero_kernel(int* __restrict__ p, int n) {
    int i = blockIdx.x * 256 + threadIdx.x;
    if (i < n) p[i] = 0;
}

__global__ void __launch_bounds__(256) hist_kernel(const int* __restrict__ eidx,
                                                   int* __restrict__ cnt) {
    int e = blockIdx.x * 256 + threadIdx.x;
    atomicAdd(&cnt[eidx[EE + e]], 1);
}

__global__ void __launch_bounds__(256) scan_kernel(int* __restrict__ cursor,
                                                   int* __restrict__ rowptr) {
    int t = threadIdx.x;
    int base_i = t * 64;
    int tsum = 0;
    for (int i = 0; i < 64; i++) tsum += cursor[base_i + i];
    __shared__ int ls[256];
    ls[t] = tsum;
    __syncthreads();
    for (int off = 1; off < 256; off <<= 1) {
        int v = (t >= off) ? ls[t - off] : 0;
        __syncthreads();
        ls[t] += v;
        __syncthreads();
    }
    int running = ls[t] - tsum;
    for (int i = 0; i < 64; i++) {
        int c = cursor[base_i + i];
        rowptr[base_i + i] = running;
        cursor[base_i + i] = running;
        running += c;
    }
    if (t == 255) rowptr[NN] = running;
}

__global__ void __launch_bounds__(256) scatter_kernel(const int* __restrict__ eidx,
                                                      int* __restrict__ cursor,
                                                      int* __restrict__ perm) {
    int e = blockIdx.x * 256 + threadIdx.x;
    int d_ = eidx[EE + e];
    int pos = atomicAdd(&cursor[d_], 1);
    perm[pos] = e;
}

__global__ void __launch_bounds__(256) deg_hist_kernel(const int* __restrict__ rowptr,
                                                       int* __restrict__ dhist) {
    int n = blockIdx.x * 256 + threadIdx.x;
    int deg = rowptr[n + 1] - rowptr[n];
    atomicAdd(&dhist[min(deg, 63)], 1);
}

__global__ void __launch_bounds__(64) deg_scan_kernel(int* __restrict__ dhist) {
    if (threadIdx.x == 0) {
        int run = 0;
        for (int b = 63; b >= 0; b--) {
            int c = dhist[b];
            dhist[b] = run;
            run += c;
        }
    }
}

__global__ void __launch_bounds__(256) deg_scatter_kernel(const int* __restrict__ rowptr,
                                                          int* __restrict__ dhist,
                                                          int* __restrict__ nodeorder) {
    int n = blockIdx.x * 256 + threadIdx.x;
    int deg = min(rowptr[n + 1] - rowptr[n], 63);
    int pos = atomicAdd(&dhist[deg], 1);
    nodeorder[pos] = n;
}

// ---------------- Node-gather edge kernel: CSR, no atomics ----------------
// rbfh = rbf @ W_rbf + b computed on the MATRIX pipe (split-bf16 MFMA 16x16x32)
// instead of per-edge VALU FMAs. Per 16-edge chunk: A (16x64) split into LDS,
// B from pre-transposed/split W_rbf^T (768x64, L2-resident). Output produced in
// 3 col-blocks of 256 through a small LDS buffer and consumed immediately:
//   pass0: dxa += m1*xh ; pass1: dv += vr*m2 ; pass2: dv += ev*m3.
// Epilogue also emits the hi/lo split of vecacc (feeds phase-3 GEMMs directly).
#define EPB 16

__global__ void __launch_bounds__(256) node_gather_kernel(
        const float* __restrict__ rbf,
        const short* __restrict__ Wrh,      // W_rbf^T hi (768 x 64 bf16)
        const short* __restrict__ Wrl,      // W_rbf^T lo
        const float* __restrict__ b_rbf,
        const float* __restrict__ xh,
        const float* __restrict__ vec,
        const float* __restrict__ ev,
        const int* __restrict__ eidx,
        const float* __restrict__ x,
        const int* __restrict__ perm,
        const int* __restrict__ rowptr,
        const int* __restrict__ nodeorder,
        float* __restrict__ x1,
        float* __restrict__ vecacc,
        short* __restrict__ vah,
        short* __restrict__ val) {
    int n = nodeorder[blockIdx.x];
    int t = threadIdx.x;
    int wave = t >> 6, lane = t & 63;
    int quad = lane >> 4, l16 = lane & 15;
    int beg = rowptr[n], deg = rowptr[n + 1] - beg;

    __shared__ __align__(16) short ah_s[EPB][72];   // A hi, padded row (144B) vs bank conflicts
    __shared__ __align__(16) short al_s[EPB][72];   // A lo
    __shared__ float mm[EPB][265];                  // 16 x 256 rbfh col-block, stride 265 (conflict-free)
    __shared__ int eid_s[EPB], src_s[EPB];
    __shared__ float ev_s[EPB][3];

    float dxa = 0.f, dv0 = 0.f, dv1 = 0.f, dv2 = 0.f;

    // loop-invariant bias for this thread's output columns
    float bb[3][4];
    #pragma unroll
    for (int s = 0; s < 3; s++)
        #pragma unroll
        for (int tt = 0; tt < 4; tt++)
            bb[s][tt] = b_rbf[s * 256 + wave * 64 + tt * 16 + l16];

    for (int b0 = 0; b0 < deg; b0 += EPB) {
        int cnt = min(EPB, deg - b0);
        __syncthreads();   // previous chunk's LDS reads done
        if (t < cnt) {
            int eid = perm[beg + b0 + t];
            eid_s[t] = eid;
            src_s[t] = eidx[eid];
        }
        __syncthreads();
        // rbf rows -> split-bf16 A tile in LDS
        #pragma unroll
        for (int i = 0; i < (EPB * 64) / 256; i++) {
            int idx = i * 256 + t;
            int e = idx >> 6, k = idx & 63;
            float r = (e < cnt) ? rbf[(long)eid_s[e] * 64 + k] : 0.f;
            short hh = f2b(r);
            ah_s[e][k] = hh;
            al_s[e][k] = f2b(r - b2f(hh));
        }
        if (t < cnt * 3) {
            int e = t / 3, d = t % 3;
            ev_s[e][d] = ev[(long)eid_s[e] * 3 + d];
        }
        __syncthreads();
        // A fragments (same data for all 4 waves): row=l16, k=ks*32+quad*8..+7
        bf16x8 afh[2], afl[2];
        #pragma unroll
        for (int ks = 0; ks < 2; ks++) {
            afh[ks] = *(const bf16x8*)(&ah_s[l16][ks * 32 + quad * 8]);
            afl[ks] = *(const bf16x8*)(&al_s[l16][ks * 32 + quad * 8]);
        }

        #pragma unroll
        for (int s = 0; s < 3; s++) {
            f32x4 acc[4];
            #pragma unroll
            for (int tt = 0; tt < 4; tt++) {
                int col = s * 256 + wave * 64 + tt * 16 + l16;
                float bv = bb[s][tt];
                acc[tt] = (f32x4){bv, bv, bv, bv};
                #pragma unroll
                for (int ks = 0; ks < 2; ks++) {
                    bf16x8 bh = *(const bf16x8*)(Wrh + (long)col * 64 + ks * 32 + quad * 8);
                    bf16x8 bl = *(const bf16x8*)(Wrl + (long)col * 64 + ks * 32 + quad * 8);
                    acc[tt] = __builtin_amdgcn_mfma_f32_16x16x32_bf16(afh[ks], bh, acc[tt], 0, 0, 0);
                    acc[tt] = __builtin_amdgcn_mfma_f32_16x16x32_bf16(afl[ks], bh, acc[tt], 0, 0, 0);
                    acc[tt] = __builtin_amdgcn_mfma_f32_16x16x32_bf16(afh[ks], bl, acc[tt], 0, 0, 0);
                }
            }
            __syncthreads();   // prior pass's mm reads complete before overwrite
            #pragma unroll
            for (int tt = 0; tt < 4; tt++) {
                #pragma unroll
                for (int r = 0; r < 4; r++)
                    mm[quad * 4 + r][wave * 64 + tt * 16 + l16] = acc[tt][r];
            }
            __syncthreads();
            if (s == 0) {
                for (int e = 0; e < cnt; e++) {
                    int sr = src_s[e];
                    dxa += mm[e][t] * xh[(long)sr * 768 + t];
                }
            } else if (s == 1) {
                for (int e = 0; e < cnt; e++) {
                    int sr = src_s[e];
                    float m2 = mm[e][t] * xh[(long)sr * 768 + 256 + t] *
                               (INV_SQRT_3f * INV_SQRT_Hf);
                    const float* vr = vec + (long)sr * 768;
                    dv0 += vr[t] * m2;
                    dv1 += vr[256 + t] * m2;
                    dv2 += vr[512 + t] * m2;
                }
            } else {
                for (int e = 0; e < cnt; e++) {
                    int sr = src_s[e];
                    float m3 = mm[e][t] * xh[(long)sr * 768 + 512 + t] * INV_SQRT_Hf;
                    dv0 += m3 * ev_s[e][0];
                    dv1 += m3 * ev_s[e][1];
                    dv2 += m3 * ev_s[e][2];
                }
            }
        }
    }

    long nb = (long)n * 256 + t;
    x1[nb] = x[nb] + dxa;
    long vb = (long)n * 768 + t;
    float vv0 = vec[vb] + dv0;
    float vv1 = vec[vb + 256] + dv1;
    float vv2 = vec[vb + 512] + dv2;
    vecacc[vb]       = vv0;
    vecacc[vb + 256] = vv1;
    vecacc[vb + 512] = vv2;
    short h0 = f2b(vv0), h1 = f2b(vv1), h2 = f2b(vv2);
    vah[vb]       = h0;  val[vb]       = f2b(vv0 - b2f(h0));
    vah[vb + 256] = h1;  val[vb + 256] = f2b(vv1 - b2f(h1));
    vah[vb + 512] = h2;  val[vb + 512] = f2b(vv2 - b2f(h2));
}

// ---------------- vec_dot + vnorm + cat(x, vnorm), split out ----------------
__global__ void __launch_bounds__(256) vdot_cat_kernel(const float* __restrict__ vec1,
                                                       const short* __restrict__ vec2,
                                                       const float* __restrict__ x1,
                                                       float* __restrict__ vdot,
                                                       short* __restrict__ cath,
                                                       short* __restrict__ catl) {
    int idx = blockIdx.x * 256 + threadIdx.x;
    int n = idx >> 8, h = idx & 255;
    float dsum = 0.f, s2 = 0.f;
    #pragma unroll
    for (int d = 0; d < 3; d++) {
        long r = (long)(n * 3 + d) * 256 + h;
        float a = vec1[r];
        float b = b2f(vec2[r]);
        dsum += a * b;
        s2 += b * b;
    }
    vdot[idx] = dsum * INV_SQRT_Hf;
    float xv = x1[idx];
    short hh = f2b(xv);
    cath[(long)n * 512 + h] = hh;
    catl[(long)n * 512 + h] = f2b(xv - b2f(hh));
    float vn = sqrtf(s2 + 1e-8f);
    short vh = f2b(vn);
    cath[(long)n * 512 + 256 + h] = vh;
    catl[(long)n * 512 + 256 + h] = f2b(vn - b2f(vh));
}

// ---------------- x/vec update after xv MLP (IN-PLACE) ----------------
__global__ void __launch_bounds__(256) e4_kernel(float* __restrict__ x1,
                                                 float* __restrict__ vecacc,
                                                 const float* __restrict__ vec1,
                                                 const float* __restrict__ vdot,
                                                 const short* __restrict__ xvh_h,
                                                 const short* __restrict__ xvh_l) {
    int idx = blockIdx.x * 256 + threadIdx.x;
    int n = idx >> 8, h = idx & 255;
    long b0 = (long)n * 768 + h;
    float xv1 = b2f(xvh_h[b0])       + b2f(xvh_l[b0]);
    float xv2 = b2f(xvh_h[b0 + 256]) + b2f(xvh_l[b0 + 256]);
    float xv3 = b2f(xvh_h[b0 + 512]) + b2f(xvh_l[b0 + 512]);
    x1[idx] = x1[idx] + (xv1 + xv2 * vdot[idx]) * INV_SQRT_2f;
    #pragma unroll
    for (int d = 0; d < 3; d++) {
        long r = (long)(n * 3 + d) * 256 + h;
        vecacc[r] = vecacc[r] + xv3 * vec1[r];
    }
}

// ---------------- norm over d + concat(x fp32, norm), split out ----------------
__global__ void __launch_bounds__(256) normcat_kernel(const float* __restrict__ xin,
                                                      const short* __restrict__ w,
                                                      short* __restrict__ cath,
                                                      short* __restrict__ catl,
                                                      int Cx, int C, int shift) {
    int idx = blockIdx.x * 256 + threadIdx.x;
    int cols = 1 << shift;
    int n = idx >> shift, c = idx & (cols - 1);
    float v;
    if (c < Cx) {
        v = xin[(long)n * Cx + c];
    } else {
        int cc = c - Cx;
        float s = 0.f;
        #pragma unroll
        for (int d = 0; d < 3; d++) {
            float a = b2f(w[(long)(n * 3 + d) * C + cc]);
            s += a * a;
        }
        v = sqrtf(s);
    }
    short hh = f2b(v);
    cath[idx] = hh;
    catl[idx] = f2b(v - b2f(hh));
}

// ---------------- gated block 1 epilogue ----------------
__global__ void __launch_bounds__(256) gate1_kernel(const float* __restrict__ h1,
                                                    const short* __restrict__ w2h,
                                                    const short* __restrict__ w2l,
                                                    float* __restrict__ x3,
                                                    short* __restrict__ vecCh,
                                                    short* __restrict__ vecCl) {
    int idx = blockIdx.x * 256 + threadIdx.x;
    int n = idx >> 7, c = idx & 127;
    x3[idx] = ssilu_f(h1[(long)n * 256 + c]);
    float vn = h1[(long)n * 256 + 128 + c];
    #pragma unroll
    for (int d = 0; d < 3; d++) {
        long r = (long)(n * 3 + d) * 128 + c;
        float wv = b2f(w2h[r]) + b2f(w2l[r]);
        float v = vn * wv;
        short hh = f2b(v);
        vecCh[r] = hh;
        vecCl[r] = f2b(v - b2f(hh));
    }
}

// ---------------- vecC @ o2_Wv2 (K=128, Nc=1): one wave per row ----------------
__global__ void __launch_bounds__(256) g12_kernel(const short* __restrict__ vecCh,
                                                  const short* __restrict__ vecCl,
                                                  const float* __restrict__ Wv2,
                                                  float* __restrict__ w4) {
    int row = blockIdx.x * 4 + (threadIdx.x >> 6);
    int lane = threadIdx.x & 63;
    long r0 = (long)row * 128 + lane;
    float v0 = b2f(vecCh[r0]) + b2f(vecCl[r0]);
    float v1 = b2f(vecCh[r0 + 64]) + b2f(vecCl[r0 + 64]);
    float s = v0 * Wv2[lane] + v1 * Wv2[64 + lane];
    #pragma unroll
    for (int off = 32; off > 0; off >>= 1) s += __shfl_down(s, off);
    if (lane == 0) w4[row] = s;
}

// ---------------- final: out[n,d] = (t5[n,:]@Wu2[:,1] + b2[1]) * w4[n,d] ----------
__global__ void __launch_bounds__(256) final_kernel(const float* __restrict__ t5,
                                                    const float* __restrict__ Wu2,
                                                    const float* __restrict__ bu2,
                                                    const float* __restrict__ w4,
                                                    float* __restrict__ out) {
    int n = blockIdx.x * 4 + (threadIdx.x >> 6);
    int lane = threadIdx.x & 63;
    float s = t5[(long)n * 128 + lane] * Wu2[lane * 2 + 1] +
              t5[(long)n * 128 + 64 + lane] * Wu2[(64 + lane) * 2 + 1];
    #pragma unroll
    for (int off = 32; off > 0; off >>= 1) s += __shfl_down(s, off);
    float val = __shfl(s, 0) + bu2[1];
    if (lane < 3) out[(long)n * 3 + lane] = val * w4[(long)n * 3 + lane];
}

extern "C" void kernel_launch(void* const* d_in, const int* in_sizes, int n_in,
                              void* d_out, int out_size, void* d_ws, size_t ws_size,
                              hipStream_t stream) {
    const float* x          = (const float*)d_in[0];
    const float* vec        = (const float*)d_in[1];
    const float* edge_rbf   = (const float*)d_in[2];
    const float* edge_vector= (const float*)d_in[3];
    const float* ln_g       = (const float*)d_in[4];
    const float* ln_b       = (const float*)d_in[5];
    const float* W_x1       = (const float*)d_in[6];
    const float* b_x1       = (const float*)d_in[7];
    const float* W_x2       = (const float*)d_in[8];
    const float* b_x2       = (const float*)d_in[9];
    const float* W_rbf      = (const float*)d_in[10];
    const float* b_rbf      = (const float*)d_in[11];
    const float* W_vp       = (const float*)d_in[12];
    const float* W_xv1      = (const float*)d_in[13];
    const float* b_xv1      = (const float*)d_in[14];
    const float* W_xv2      = (const float*)d_in[15];
    const float* b_xv2      = (const float*)d_in[16];
    const float* o1_Wv1     = (const float*)d_in[17];
    const float* o1_Wv2     = (const float*)d_in[18];
    const float* o1_Wu1     = (const float*)d_in[19];
    const float* o1_bu1     = (const float*)d_in[20];
    const float* o1_Wu2     = (const float*)d_in[21];
    const float* o1_bu2     = (const float*)d_in[22];
    const float* o2_Wv1     = (const float*)d_in[23];
    const float* o2_Wv2     = (const float*)d_in[24];
    const float* o2_Wu1     = (const float*)d_in[25];
    const float* o2_bu1     = (const float*)d_in[26];
    const float* o2_Wu2     = (const float*)d_in[27];
    const float* o2_bu2     = (const float*)d_in[28];
    const int*   edge_index = (const int*)d_in[29];
    float* out = (float*)d_out;
    float* ws  = (float*)d_ws;

    const size_t S = (size_t)NN * 256;
    const size_t Q = S / 4;              // 1,048,576 floats = 4 MiB
    // ---- arena in units of Q; peak 52Q = 208 MiB (proven safe) ----
    float* x1      = ws;                     // Q0-3   (fp32 S)
    float* vecacc  = ws + 4 * Q;             // Q4-15  (fp32 3S)
    short* wtb     = (short*)(ws + 16 * Q);  // Q16-17 weights hi + lo (2x1114112 shorts = 4.46 MB < 8 MB)
    const long WLO = 1114112;
    // phase 1
    short* xln_h = (short*)(ws + 18 * Q);    // Q18-19 (dead after t1 gemm)
    short* xln_l = (short*)(ws + 20 * Q);    // Q20-21
    short* t1_h  = (short*)(ws + 22 * Q);    // Q22-23 (dead after xh gemm)
    short* t1_l  = (short*)(ws + 24 * Q);    // Q24-25
    float* xh    = ws + 30 * Q;              // Q30-41 (fp32 3S, dead after gather)
    // phase 2 sort scratch (dead before vdot is written)
    int* rowptr    = (int*)(ws + 48 * Q);
    int* cursor    = rowptr + (NN + 1);
    int* dhist     = cursor + NN;
    int* nodeorder = dhist + 64;
    int* perm      = nodeorder + NN;
    // phase 3 (vah/val_ now written by node_gather directly)
    short* vah   = (short*)(ws + 18 * Q);    // Q18-23 (3S bf16)
    short* val_  = (short*)(ws + 24 * Q);    // Q24-29
    float* vec1  = ws + 30 * Q;              // Q30-41 (fp32 3S, live till e4)
    short* vec2b = (short*)(ws + 42 * Q);    // Q42-47 (bf16 3S)
    float* vdot  = ws + 48 * Q;              // Q48-51 (fp32 S, live till e4)
    short* catb_h = (short*)(ws + 18 * Q);   // Q18-21 (vah dead after vp gemms)
    short* catb_l = (short*)(ws + 22 * Q);   // Q22-25
    short* t2_h  = (short*)(ws + 26 * Q);    // Q26-27
    short* t2_l  = (short*)(ws + 28 * Q);    // Q28-29
    short* xvh_h = (short*)(ws + 18 * Q);    // Q18-23 (catb dead)
    short* xvh_l = (short*)(ws + 42 * Q);    // Q42-47 (vec2 dead)
    // phase 4
    short* vah2  = (short*)(ws + 18 * Q);    // Q18-23
    short* val2  = (short*)(ws + 24 * Q);    // Q24-29
    short* w1b   = (short*)(ws + 30 * Q);    // Q30-35 (bf16 3S)
    short* w2_h  = (short*)(ws + 36 * Q);    // Q36-38
    short* w2_l  = (short*)(ws + 39 * Q);    // Q39-41
    short* cat2_h = (short*)(ws + 42 * Q);   // Q42-45
    short* cat2_l = (short*)(ws + 46 * Q);   // Q46-49
    short* t4_h  = (short*)(ws + 18 * Q);    // Q18-19
    short* t4_l  = (short*)(ws + 20 * Q);    // Q20-21
    float* h1    = ws + 22 * Q;              // Q22-25 (fp32 S)
    float* x3    = ws + 26 * Q;              // Q26-27 (fp32 S/2)
    short* vecC_h = (short*)(ws + 28 * Q);   // Q28-30
    short* vecC_l = (short*)(ws + 31 * Q);   // Q31-33
    // phase 5
    short* w3b   = (short*)(ws + 34 * Q);    // Q34-36
    float* w4    = ws + 37 * Q;              // Q37
    short* cat3_h = (short*)(ws + 38 * Q);   // Q38-39
    short* cat3_l = (short*)(ws + 40 * Q);   // Q40-41
    float* t5    = ws + 42 * Q;              // Q42-43

    // weight hi/lo offsets (shorts)
    short* WT_x1    = wtb;
    short* WT_x2    = wtb + 65536;
    short* WT_vp    = wtb + 262144;
    short* WT_xv1   = wtb + 393216;
    short* WT_xv2   = wtb + 524288;
    short* WT_o1Wv1 = wtb + 720896;
    short* WT_o1Wv2 = wtb + 786432;
    short* WT_o1Wu1 = wtb + 819200;
    short* WT_o1Wu2 = wtb + 950272;
    short* WT_o2Wv1 = wtb + 1015808;
    short* WT_o2Wu1 = wtb + 1032192;
    short* WT_rbf   = wtb + 1064960;         // 768 x 64

    // Phase 0: all weight transposes + splits in one launch (incl. W_rbf^T)
    WtArgs wa;
    const float* wsrc[12] = {W_x1, W_x2, W_vp, W_xv1, W_xv2, o1_Wv1, o1_Wv2,
                             o1_Wu1, o1_Wu2, o2_Wv1, o2_Wu1, W_rbf};
    int wk[12] = {256, 256, 256, 512, 256, 256, 256, 512, 256, 128, 256, 64};
    int wn[12] = {256, 768, 512, 256, 768, 256, 128, 256, 256, 128, 128, 768};
    int off = 0;
    for (int i = 0; i < 12; i++) {
        wa.W[i] = wsrc[i]; wa.K[i] = wk[i]; wa.N[i] = wn[i];
        wa.off[i] = off; off += wk[i] * wn[i];
    }
    wa.off[12] = off;  // 1,114,112
    wt_split_all<<<off / 256, 256, 0, stream>>>(wa, wtb, wtb + WLO);

    // Phase 1: node MLP
    ln_kernel<<<NN, 256, 0, stream>>>(x, ln_g, ln_b, xln_h, xln_l);
    mfma_gemm<<<dim3(NN / 128, 4), 256, 0, stream>>>(xln_h, xln_l, WT_x1, WT_x1 + WLO,
                                                     b_x1, t1_h, t1_l, NN, 256, 256, 1);
    mfma_gemm<<<dim3(NN / 128, 12), 256, 0, stream>>>(t1_h, t1_l, WT_x2, WT_x2 + WLO,
                                                      b_x2, xh, nullptr, NN, 256, 768, 0);

    // Phase 2: sort edges by dst; node order by desc degree; CSR gather (no atomics)
    zero_kernel<<<(NN + 64 + 255) / 256, 256, 0, stream>>>(cursor, NN + 64);
    hist_kernel<<<EE / 256, 256, 0, stream>>>(edge_index, cursor);
    scan_kernel<<<1, 256, 0, stream>>>(cursor, rowptr);
    scatter_kernel<<<EE / 256, 256, 0, stream>>>(edge_index, cursor, perm);
    deg_hist_kernel<<<NN / 256, 256, 0, stream>>>(rowptr, dhist);
    deg_scan_kernel<<<1, 64, 0, stream>>>(dhist);
    deg_scatter_kernel<<<NN / 256, 256, 0, stream>>>(rowptr, dhist, nodeorder);
    node_gather_kernel<<<NN, 256, 0, stream>>>(edge_rbf, WT_rbf, WT_rbf + WLO,
                                               b_rbf, xh, vec, edge_vector, edge_index,
                                               x, perm, rowptr, nodeorder, x1, vecacc,
                                               vah, val_);

    // Phase 3: vp, vdot/vnorm, xv MLP, in-place updates
    mfma_gemm<<<dim3(3 * NN / 128, 4), 256, 0, stream>>>(vah, val_, WT_vp, WT_vp + WLO,
                                                         nullptr, vec1, nullptr,
                                                         3 * NN, 256, 256, 0);
    mfma_gemm<<<dim3(3 * NN / 128, 4), 256, 0, stream>>>(vah, val_, WT_vp + 65536,
                                                         WT_vp + WLO + 65536,
                                                         nullptr, vec2b, nullptr,
                                                         3 * NN, 256, 256, 2);
    vdot_cat_kernel<<<NN, 256, 0, stream>>>(vec1, vec2b, x1, vdot, catb_h, catb_l);
    mfma_gemm<<<dim3(NN / 128, 4), 256, 0, stream>>>(catb_h, catb_l, WT_xv1, WT_xv1 + WLO,
                                                     b_xv1, t2_h, t2_l, NN, 512, 256, 1);
    mfma_gemm<<<dim3(NN / 128, 12), 256, 0, stream>>>(t2_h, t2_l, WT_xv2, WT_xv2 + WLO,
                                                      b_xv2, xvh_h, xvh_l, NN, 256, 768, 0);
    e4_kernel<<<NN, 256, 0, stream>>>(x1, vecacc, vec1, vdot, xvh_h, xvh_l);

    // Phase 4: gated equivariant block 1
    split4_kernel<<<3 * S / 1024, 256, 0, stream>>>(vecacc, vah2, val2);
    mfma_gemm<<<dim3(3 * NN / 128, 4), 256, 0, stream>>>(vah2, val2, WT_o1Wv1, WT_o1Wv1 + WLO,
                                                         nullptr, w1b, nullptr,
                                                         3 * NN, 256, 256, 2);
    mfma_gemm<<<dim3(3 * NN / 128, 2), 256, 0, stream>>>(vah2, val2, WT_o1Wv2, WT_o1Wv2 + WLO,
                                                         nullptr, w2_h, w2_l,
                                                         3 * NN, 256, 128, 0);
    normcat_kernel<<<NN * 512 / 256, 256, 0, stream>>>(x1, w1b, cat2_h, cat2_l, 256, 256, 9);
    mfma_gemm<<<dim3(NN / 128, 4), 256, 0, stream>>>(cat2_h, cat2_l, WT_o1Wu1, WT_o1Wu1 + WLO,
                                                     o1_bu1, t4_h, t4_l, NN, 512, 256, 1);
    mfma_gemm<<<dim3(NN / 128, 4), 256, 0, stream>>>(t4_h, t4_l, WT_o1Wu2, WT_o1Wu2 + WLO,
                                                     o1_bu2, h1, nullptr, NN, 256, 256, 0);
    gate1_kernel<<<NN * 128 / 256, 256, 0, stream>>>(h1, w2_h, w2_l, x3, vecC_h, vecC_l);

    // Phase 5: gated equivariant block 2 + output
    mfma_gemm<<<dim3(3 * NN / 128, 2), 256, 0, stream>>>(vecC_h, vecC_l, WT_o2Wv1,
                                                         WT_o2Wv1 + WLO, nullptr,
                                                         w3b, nullptr, 3 * NN, 128, 128, 2);
    g12_kernel<<<3 * NN / 4, 256, 0, stream>>>(vecC_h, vecC_l, o2_Wv2, w4);
    normcat_kernel<<<NN * 256 / 256, 256, 0, stream>>>(x3, w3b, cat3_h, cat3_l, 128, 128, 8);
    mfma_gemm<<<dim3(NN / 128, 2), 256, 0, stream>>>(cat3_h, cat3_l, WT_o2Wu1, WT_o2Wu1 + WLO,
                                                     o2_bu1, t5, nullptr, NN, 256, 128, 1);
    final_kernel<<<NN / 4, 256, 0, stream>>>(t5, o2_Wu2, o2_bu2, w4, out);
}

// Round 2
// 2429.814 us; speedup vs baseline: 1.0876x; 1.0876x over previous
//
#include <hip/hip_runtime.h>
#include <math.h>

#define NN 16384
#define EE 262144
#define HH 256

#define INV_SQRT_3f 0.57735026918962576f
#define INV_SQRT_Hf 0.0625f
#define INV_SQRT_2f 0.70710678118654752f
#define SSILU_SCALE 1.6666666666666667f

typedef __attribute__((ext_vector_type(8))) short bf16x8;
typedef __attribute__((ext_vector_type(4))) float f32x4;

__device__ __forceinline__ float ssilu_f(float v) {
    return v * (1.0f / (1.0f + __expf(-v))) * SSILU_SCALE;
}
__device__ __forceinline__ float b2f(short s) {
    unsigned int u = ((unsigned int)(unsigned short)s) << 16;
    return __uint_as_float(u);
}
__device__ __forceinline__ short f2b(float f) {
    unsigned int u = __float_as_uint(f);
    unsigned int r = (u + 0x7fff + ((u >> 16) & 1)) >> 16;
    return (short)r;
}

// ---------------- LayerNorm: one block per row, split-bf16 out ----------------
__global__ void __launch_bounds__(256) ln_kernel(const float* __restrict__ x,
                                                 const float* __restrict__ g,
                                                 const float* __restrict__ b,
                                                 short* __restrict__ oh,
                                                 short* __restrict__ ol) {
    int n = blockIdx.x;
    int t = threadIdx.x;
    float v = x[(long)n * HH + t];
    float s = v, s2 = v * v;
    #pragma unroll
    for (int off = 32; off > 0; off >>= 1) {
        s  += __shfl_down(s, off);
        s2 += __shfl_down(s2, off);
    }
    __shared__ float red[8];
    int wave = t >> 6, lane = t & 63;
    if (lane == 0) { red[wave] = s; red[4 + wave] = s2; }
    __syncthreads();
    __shared__ float mr[2];
    if (t == 0) {
        float ts = red[0] + red[1] + red[2] + red[3];
        float ts2 = red[4] + red[5] + red[6] + red[7];
        float mean = ts * (1.0f / HH);
        float var = ts2 * (1.0f / HH) - mean * mean;
        mr[0] = mean;
        mr[1] = rsqrtf(var + 1e-5f);
    }
    __syncthreads();
    float o = (v - mr[0]) * mr[1] * g[t] + b[t];
    short hh = f2b(o);
    oh[(long)n * HH + t] = hh;
    ol[(long)n * HH + t] = f2b(o - b2f(hh));
}

// ---- ALL weight transposes + hi/lo splits in ONE kernel (incl. W_rbf) ----
struct WtArgs {
    const float* W[12];
    int K[12];
    int N[12];
    int off[13];   // cumulative element offsets; off[12] = total
};

__global__ void __launch_bounds__(256) wt_split_all(WtArgs a,
                                                    short* __restrict__ WTh,
                                                    short* __restrict__ WTl) {
    int idx = blockIdx.x * 256 + threadIdx.x;
    int s = 0;
    #pragma unroll
    for (int i = 1; i < 12; i++) s += (idx >= a.off[i]) ? 1 : 0;
    int local = idx - a.off[s];
    int K = a.K[s], N = a.N[s];
    int k = local / N, n = local - k * N;
    float w = a.W[s][local];
    short hh = f2b(w);
    long o = (long)a.off[s] + (long)n * K + k;
    WTh[o] = hh;
    WTl[o] = f2b(w - b2f(hh));
}

// ---- fp32 -> hi/lo split (count % 1024 == 0) ----
__global__ void __launch_bounds__(256) split4_kernel(const float* __restrict__ in,
                                                     short* __restrict__ h,
                                                     short* __restrict__ l) {
    long i = ((long)blockIdx.x * 256 + threadIdx.x) * 4;
    float4 v = *(const float4*)(in + i);
    short4 oh, ol;
    oh.x = f2b(v.x); ol.x = f2b(v.x - b2f(oh.x));
    oh.y = f2b(v.y); ol.y = f2b(v.y - b2f(oh.y));
    oh.z = f2b(v.z); ol.z = f2b(v.z - b2f(oh.z));
    oh.w = f2b(v.w); ol.w = f2b(v.w - b2f(oh.w));
    *(short4*)(h + i) = oh;
    *(short4*)(l + i) = ol;
}

// ---- split-bf16 MFMA GEMM v2: C = (Ah+Al)(M,K) @ (Wh+Wl)^T(N,K) [+bias][ssilu]
__global__ void __launch_bounds__(256) mfma_gemm(const short* __restrict__ Ah,
                                                 const short* __restrict__ Al,
                                                 const short* __restrict__ Wh,
                                                 const short* __restrict__ Wl,
                                                 const float* __restrict__ bias,
                                                 void* __restrict__ Ch,
                                                 short* __restrict__ Cl,
                                                 int M, int K, int N, int act) {
    int tid = threadIdx.x;
    int wave = tid >> 6, lane = tid & 63;
    int quad = lane >> 4, l16 = lane & 15;
    long bm = (long)blockIdx.x * 128 + wave * 32;
    long bn = (long)blockIdx.y * 64;
    long a0 = (bm + l16) * K + quad * 8;
    long a1 = a0 + (long)16 * K;
    long w0 = (bn + l16) * K + quad * 8;

    f32x4 acc[2][4];
    #pragma unroll
    for (int f = 0; f < 2; f++)
        #pragma unroll
        for (int t = 0; t < 4; t++) acc[f][t] = (f32x4){0.f, 0.f, 0.f, 0.f};

    bf16x8 cah[2], cal[2], cbh[4], cbl[4];
    cah[0] = *(const bf16x8*)(Ah + a0);
    cah[1] = *(const bf16x8*)(Ah + a1);
    cal[0] = *(const bf16x8*)(Al + a0);
    cal[1] = *(const bf16x8*)(Al + a1);
    #pragma unroll
    for (int t = 0; t < 4; t++) {
        long wo = w0 + (long)t * 16 * K;
        cbh[t] = *(const bf16x8*)(Wh + wo);
        cbl[t] = *(const bf16x8*)(Wl + wo);
    }

    for (int k0 = 0; k0 < K; k0 += 32) {
        int k1 = k0 + 32;
        bf16x8 nah[2], nal[2], nbh[4], nbl[4];
        if (k1 < K) {
            nah[0] = *(const bf16x8*)(Ah + a0 + k1);
            nah[1] = *(const bf16x8*)(Ah + a1 + k1);
            nal[0] = *(const bf16x8*)(Al + a0 + k1);
            nal[1] = *(const bf16x8*)(Al + a1 + k1);
            #pragma unroll
            for (int t = 0; t < 4; t++) {
                long wo = w0 + (long)t * 16 * K + k1;
                nbh[t] = *(const bf16x8*)(Wh + wo);
                nbl[t] = *(const bf16x8*)(Wl + wo);
            }
        }
        #pragma unroll
        for (int t = 0; t < 4; t++) {
            #pragma unroll
            for (int f = 0; f < 2; f++) {
                acc[f][t] = __builtin_amdgcn_mfma_f32_16x16x32_bf16(cah[f], cbh[t], acc[f][t], 0, 0, 0);
                acc[f][t] = __builtin_amdgcn_mfma_f32_16x16x32_bf16(cal[f], cbh[t], acc[f][t], 0, 0, 0);
                acc[f][t] = __builtin_amdgcn_mfma_f32_16x16x32_bf16(cah[f], cbl[t], acc[f][t], 0, 0, 0);
            }
        }
        if (k1 < K) {
            cah[0] = nah[0]; cah[1] = nah[1];
            cal[0] = nal[0]; cal[1] = nal[1];
            #pragma unroll
            for (int t = 0; t < 4; t++) { cbh[t] = nbh[t]; cbl[t] = nbl[t]; }
        }
    }

    #pragma unroll
    for (int f = 0; f < 2; f++) {
        long row0 = bm + f * 16 + quad * 4;
        #pragma unroll
        for (int t = 0; t < 4; t++) {
            long col = bn + t * 16 + l16;
            float bv = bias ? bias[col] : 0.f;
            #pragma unroll
            for (int r = 0; r < 4; r++) {
                float v = acc[f][t][r] + bv;
                if (act & 1) v = ssilu_f(v);
                long idx = (row0 + r) * N + col;
                if (Cl) {
                    short hh = f2b(v);
                    ((short*)Ch)[idx] = hh;
                    Cl[idx] = f2b(v - b2f(hh));
                } else if (act & 2) {
                    ((short*)Ch)[idx] = f2b(v);
                } else {
                    ((float*)Ch)[idx] = v;
                }
            }
        }
    }
}

// ---------------- edge sort (counting sort by dst) ----------------
__global__ void __launch_bounds__(256) zero_kernel(int* __restrict__ p, int n) {
    int i = blockIdx.x * 256 + threadIdx.x;
    if (i < n) p[i] = 0;
}

__global__ void __launch_bounds__(256) hist_kernel(const int* __restrict__ eidx,
                                                   int* __restrict__ cnt) {
    int e = blockIdx.x * 256 + threadIdx.x;
    atomicAdd(&cnt[eidx[EE + e]], 1);
}

__global__ void __launch_bounds__(256) scan_kernel(int* __restrict__ cursor,
                                                   int* __restrict__ rowptr) {
    int t = threadIdx.x;
    int base_i = t * 64;
    int tsum = 0;
    for (int i = 0; i < 64; i++) tsum += cursor[base_i + i];
    __shared__ int ls[256];
    ls[t] = tsum;
    __syncthreads();
    for (int off = 1; off < 256; off <<= 1) {
        int v = (t >= off) ? ls[t - off] : 0;
        __syncthreads();
        ls[t] += v;
        __syncthreads();
    }
    int running = ls[t] - tsum;
    for (int i = 0; i < 64; i++) {
        int c = cursor[base_i + i];
        rowptr[base_i + i] = running;
        cursor[base_i + i] = running;
        running += c;
    }
    if (t == 255) rowptr[NN] = running;
}

__global__ void __launch_bounds__(256) scatter_kernel(const int* __restrict__ eidx,
                                                      int* __restrict__ cursor,
                                                      int* __restrict__ perm) {
    int e = blockIdx.x * 256 + threadIdx.x;
    int d_ = eidx[EE + e];
    int pos = atomicAdd(&cursor[d_], 1);
    perm[pos] = e;
}

__global__ void __launch_bounds__(256) deg_hist_kernel(const int* __restrict__ rowptr,
                                                       int* __restrict__ dhist) {
    int n = blockIdx.x * 256 + threadIdx.x;
    int deg = rowptr[n + 1] - rowptr[n];
    atomicAdd(&dhist[min(deg, 63)], 1);
}

__global__ void __launch_bounds__(64) deg_scan_kernel(int* __restrict__ dhist) {
    if (threadIdx.x == 0) {
        int run = 0;
        for (int b = 63; b >= 0; b--) {
            int c = dhist[b];
            dhist[b] = run;
            run += c;
        }
    }
}

__global__ void __launch_bounds__(256) deg_scatter_kernel(const int* __restrict__ rowptr,
                                                          int* __restrict__ dhist,
                                                          int* __restrict__ nodeorder) {
    int n = blockIdx.x * 256 + threadIdx.x;
    int deg = min(rowptr[n + 1] - rowptr[n], 63);
    int pos = atomicAdd(&dhist[deg], 1);
    nodeorder[pos] = n;
}

// ---------------- Node-gather edge kernel: CSR, no atomics ----------------
// v3: rbfh on the matrix pipe (proven round-1 fragment mapping), but the MFMA
// accumulator is consumed IN REGISTERS: lane (quad,l16) holds m[e=quad*4+r][col],
// exactly the (edge,col) pair its gather-consume product needs. Per-lane partial
// sums over the lane's 4 edges; ONE cross-quad shfl_xor reduce per node in the
// epilogue. No mm LDS buffer, no in-loop barriers beyond round-0's 3 staging
// barriers. Sections processed sequentially so only one acc[4] is live.
#define EPB 16

__global__ void __launch_bounds__(256) node_gather_kernel(
        const float* __restrict__ rbf,
        const short* __restrict__ Wrh,      // W_rbf^T hi (768 x 64 bf16)
        const short* __restrict__ Wrl,      // W_rbf^T lo
        const float* __restrict__ b_rbf,
        const float* __restrict__ xh,
        const float* __restrict__ vec,
        const float* __restrict__ ev,
        const int* __restrict__ eidx,
        const float* __restrict__ x,
        const int* __restrict__ perm,
        const int* __restrict__ rowptr,
        const int* __restrict__ nodeorder,
        float* __restrict__ x1,
        float* __restrict__ vecacc,
        short* __restrict__ vah,
        short* __restrict__ val) {
    int n = nodeorder[blockIdx.x];
    int t = threadIdx.x;
    int wave = t >> 6, lane = t & 63;
    int quad = lane >> 4, l16 = lane & 15;
    int beg = rowptr[n], deg = rowptr[n + 1] - beg;

    __shared__ __align__(16) short ah_s[EPB][72];   // A hi, padded rows
    __shared__ __align__(16) short al_s[EPB][72];   // A lo
    __shared__ int eid_s[EPB], src_s[EPB];
    __shared__ float ev_s[EPB][3];

    // per-lane partials: this lane's 4 edges (quad) x 4 columns (tt);
    // cross-quad reduce happens once, in the epilogue.
    float dxa_p[4] = {0.f, 0.f, 0.f, 0.f};
    float dv0_p[4] = {0.f, 0.f, 0.f, 0.f};
    float dv1_p[4] = {0.f, 0.f, 0.f, 0.f};
    float dv2_p[4] = {0.f, 0.f, 0.f, 0.f};

    int colb = wave * 64 + l16;    // this lane's column base; + tt*16

    float bb[3][4];
    #pragma unroll
    for (int s = 0; s < 3; s++)
        #pragma unroll
        for (int tt = 0; tt < 4; tt++)
            bb[s][tt] = b_rbf[s * 256 + colb + tt * 16];

    for (int b0 = 0; b0 < deg; b0 += EPB) {
        int cnt = min(EPB, deg - b0);
        __syncthreads();   // previous chunk's LDS reads done
        if (t < cnt) {
            int eid = perm[beg + b0 + t];
            eid_s[t] = eid;
            src_s[t] = eidx[eid];
        }
        __syncthreads();
        // rbf rows -> split-bf16 A tile in LDS
        #pragma unroll
        for (int i = 0; i < (EPB * 64) / 256; i++) {
            int idx = i * 256 + t;
            int e = idx >> 6, k = idx & 63;
            float r = (e < cnt) ? rbf[(long)eid_s[e] * 64 + k] : 0.f;
            short hh = f2b(r);
            ah_s[e][k] = hh;
            al_s[e][k] = f2b(r - b2f(hh));
        }
        if (t < cnt * 3) {
            int e = t / 3, d = t % 3;
            ev_s[e][d] = ev[(long)eid_s[e] * 3 + d];
        }
        __syncthreads();
        // A fragments (same data for all 4 waves): row=l16, k=ks*32+quad*8..+7
        bf16x8 afh[2], afl[2];
        #pragma unroll
        for (int ks = 0; ks < 2; ks++) {
            afh[ks] = *(const bf16x8*)(&ah_s[l16][ks * 32 + quad * 8]);
            afl[ks] = *(const bf16x8*)(&al_s[l16][ks * 32 + quad * 8]);
        }

        // ---- section 0: m1 -> dxa ----
        {
            f32x4 acc[4];
            #pragma unroll
            for (int tt = 0; tt < 4; tt++) {
                float bv = bb[0][tt];
                acc[tt] = (f32x4){bv, bv, bv, bv};
                #pragma unroll
                for (int ks = 0; ks < 2; ks++) {
                    long wo = (long)(colb + tt * 16) * 64 + ks * 32 + quad * 8;
                    bf16x8 bh = *(const bf16x8*)(Wrh + wo);
                    bf16x8 bl = *(const bf16x8*)(Wrl + wo);
                    acc[tt] = __builtin_amdgcn_mfma_f32_16x16x32_bf16(afh[ks], bh, acc[tt], 0, 0, 0);
                    acc[tt] = __builtin_amdgcn_mfma_f32_16x16x32_bf16(afl[ks], bh, acc[tt], 0, 0, 0);
                    acc[tt] = __builtin_amdgcn_mfma_f32_16x16x32_bf16(afh[ks], bl, acc[tt], 0, 0, 0);
                }
            }
            #pragma unroll
            for (int r = 0; r < 4; r++) {
                int e = quad * 4 + r;
                if (e < cnt) {
                    long xb = (long)src_s[e] * 768;
                    #pragma unroll
                    for (int tt = 0; tt < 4; tt++)
                        dxa_p[tt] += acc[tt][r] * xh[xb + colb + tt * 16];
                }
            }
        }
        // ---- section 1: m2 -> dv += vec[src]*m2 ----
        {
            f32x4 acc[4];
            #pragma unroll
            for (int tt = 0; tt < 4; tt++) {
                float bv = bb[1][tt];
                acc[tt] = (f32x4){bv, bv, bv, bv};
                #pragma unroll
                for (int ks = 0; ks < 2; ks++) {
                    long wo = (long)(256 + colb + tt * 16) * 64 + ks * 32 + quad * 8;
                    bf16x8 bh = *(const bf16x8*)(Wrh + wo);
                    bf16x8 bl = *(const bf16x8*)(Wrl + wo);
                    acc[tt] = __builtin_amdgcn_mfma_f32_16x16x32_bf16(afh[ks], bh, acc[tt], 0, 0, 0);
                    acc[tt] = __builtin_amdgcn_mfma_f32_16x16x32_bf16(afl[ks], bh, acc[tt], 0, 0, 0);
                    acc[tt] = __builtin_amdgcn_mfma_f32_16x16x32_bf16(afh[ks], bl, acc[tt], 0, 0, 0);
                }
            }
            #pragma unroll
            for (int r = 0; r < 4; r++) {
                int e = quad * 4 + r;
                if (e < cnt) {
                    long xb = (long)src_s[e] * 768;
                    #pragma unroll
                    for (int tt = 0; tt < 4; tt++) {
                        int c = colb + tt * 16;
                        float m2 = acc[tt][r] * (INV_SQRT_3f * INV_SQRT_Hf) *
                                   xh[xb + 256 + c];
                        dv0_p[tt] += vec[xb + c] * m2;
                        dv1_p[tt] += vec[xb + 256 + c] * m2;
                        dv2_p[tt] += vec[xb + 512 + c] * m2;
                    }
                }
            }
        }
        // ---- section 2: m3 -> dv += m3*ev ----
        {
            f32x4 acc[4];
            #pragma unroll
            for (int tt = 0; tt < 4; tt++) {
                float bv = bb[2][tt];
                acc[tt] = (f32x4){bv, bv, bv, bv};
                #pragma unroll
                for (int ks = 0; ks < 2; ks++) {
                    long wo = (long)(512 + colb + tt * 16) * 64 + ks * 32 + quad * 8;
                    bf16x8 bh = *(const bf16x8*)(Wrh + wo);
                    bf16x8 bl = *(const bf16x8*)(Wrl + wo);
                    acc[tt] = __builtin_amdgcn_mfma_f32_16x16x32_bf16(afh[ks], bh, acc[tt], 0, 0, 0);
                    acc[tt] = __builtin_amdgcn_mfma_f32_16x16x32_bf16(afl[ks], bh, acc[tt], 0, 0, 0);
                    acc[tt] = __builtin_amdgcn_mfma_f32_16x16x32_bf16(afh[ks], bl, acc[tt], 0, 0, 0);
                }
            }
            #pragma unroll
            for (int r = 0; r < 4; r++) {
                int e = quad * 4 + r;
                if (e < cnt) {
                    long xb = (long)src_s[e] * 768;
                    #pragma unroll
                    for (int tt = 0; tt < 4; tt++) {
                        int c = colb + tt * 16;
                        float m3 = acc[tt][r] * INV_SQRT_Hf * xh[xb + 512 + c];
                        dv0_p[tt] += m3 * ev_s[e][0];
                        dv1_p[tt] += m3 * ev_s[e][1];
                        dv2_p[tt] += m3 * ev_s[e][2];
                    }
                }
            }
        }
    }

    // ---- epilogue: cross-quad reduce (lanes l16, l16+16, +32, +48 share cols) ----
    #pragma unroll
    for (int tt = 0; tt < 4; tt++) {
        dxa_p[tt] += __shfl_xor(dxa_p[tt], 16);
        dxa_p[tt] += __shfl_xor(dxa_p[tt], 32);
        dv0_p[tt] += __shfl_xor(dv0_p[tt], 16);
        dv0_p[tt] += __shfl_xor(dv0_p[tt], 32);
        dv1_p[tt] += __shfl_xor(dv1_p[tt], 16);
        dv1_p[tt] += __shfl_xor(dv1_p[tt], 32);
        dv2_p[tt] += __shfl_xor(dv2_p[tt], 16);
        dv2_p[tt] += __shfl_xor(dv2_p[tt], 32);
    }
    // all quads now hold the full sums; distribute the writes across quads
    if (quad == 3) {
        #pragma unroll
        for (int tt = 0; tt < 4; tt++) {
            long nb = (long)n * 256 + colb + tt * 16;
            x1[nb] = x[nb] + dxa_p[tt];
        }
    } else {
        #pragma unroll
        for (int tt = 0; tt < 4; tt++) {
            int c = colb + tt * 16;
            long vb;
            float dv;
            if (quad == 0)      { vb = (long)n * 768 + c;       dv = dv0_p[tt]; }
            else if (quad == 1) { vb = (long)n * 768 + 256 + c; dv = dv1_p[tt]; }
            else                { vb = (long)n * 768 + 512 + c; dv = dv2_p[tt]; }
            float vv = vec[vb] + dv;
            vecacc[vb] = vv;
            short h = f2b(vv);
            vah[vb] = h;
            val[vb] = f2b(vv - b2f(h));
        }
    }
}

// ---------------- vec_dot + vnorm + cat(x, vnorm), split out ----------------
__global__ void __launch_bounds__(256) vdot_cat_kernel(const float* __restrict__ vec1,
                                                       const short* __restrict__ vec2,
                                                       const float* __restrict__ x1,
                                                       float* __restrict__ vdot,
                                                       short* __restrict__ cath,
                                                       short* __restrict__ catl) {
    int idx = blockIdx.x * 256 + threadIdx.x;
    int n = idx >> 8, h = idx & 255;
    float dsum = 0.f, s2 = 0.f;
    #pragma unroll
    for (int d = 0; d < 3; d++) {
        long r = (long)(n * 3 + d) * 256 + h;
        float a = vec1[r];
        float b = b2f(vec2[r]);
        dsum += a * b;
        s2 += b * b;
    }
    vdot[idx] = dsum * INV_SQRT_Hf;
    float xv = x1[idx];
    short hh = f2b(xv);
    cath[(long)n * 512 + h] = hh;
    catl[(long)n * 512 + h] = f2b(xv - b2f(hh));
    float vn = sqrtf(s2 + 1e-8f);
    short vh = f2b(vn);
    cath[(long)n * 512 + 256 + h] = vh;
    catl[(long)n * 512 + 256 + h] = f2b(vn - b2f(vh));
}

// ---------------- x/vec update after xv MLP (IN-PLACE) ----------------
__global__ void __launch_bounds__(256) e4_kernel(float* __restrict__ x1,
                                                 float* __restrict__ vecacc,
                                                 const float* __restrict__ vec1,
                                                 const float* __restrict__ vdot,
                                                 const short* __restrict__ xvh_h,
                                                 const short* __restrict__ xvh_l) {
    int idx = blockIdx.x * 256 + threadIdx.x;
    int n = idx >> 8, h = idx & 255;
    long b0 = (long)n * 768 + h;
    float xv1 = b2f(xvh_h[b0])       + b2f(xvh_l[b0]);
    float xv2 = b2f(xvh_h[b0 + 256]) + b2f(xvh_l[b0 + 256]);
    float xv3 = b2f(xvh_h[b0 + 512]) + b2f(xvh_l[b0 + 512]);
    x1[idx] = x1[idx] + (xv1 + xv2 * vdot[idx]) * INV_SQRT_2f;
    #pragma unroll
    for (int d = 0; d < 3; d++) {
        long r = (long)(n * 3 + d) * 256 + h;
        vecacc[r] = vecacc[r] + xv3 * vec1[r];
    }
}

// ---------------- norm over d + concat(x fp32, norm), split out ----------------
__global__ void __launch_bounds__(256) normcat_kernel(const float* __restrict__ xin,
                                                      const short* __restrict__ w,
                                                      short* __restrict__ cath,
                                                      short* __restrict__ catl,
                                                      int Cx, int C, int shift) {
    int idx = blockIdx.x * 256 + threadIdx.x;
    int cols = 1 << shift;
    int n = idx >> shift, c = idx & (cols - 1);
    float v;
    if (c < Cx) {
        v = xin[(long)n * Cx + c];
    } else {
        int cc = c - Cx;
        float s = 0.f;
        #pragma unroll
        for (int d = 0; d < 3; d++) {
            float a = b2f(w[(long)(n * 3 + d) * C + cc]);
            s += a * a;
        }
        v = sqrtf(s);
    }
    short hh = f2b(v);
    cath[idx] = hh;
    catl[idx] = f2b(v - b2f(hh));
}

// ---------------- gated block 1 epilogue ----------------
__global__ void __launch_bounds__(256) gate1_kernel(const float* __restrict__ h1,
                                                    const short* __restrict__ w2h,
                                                    const short* __restrict__ w2l,
                                                    float* __restrict__ x3,
                                                    short* __restrict__ vecCh,
                                                    short* __restrict__ vecCl) {
    int idx = blockIdx.x * 256 + threadIdx.x;
    int n = idx >> 7, c = idx & 127;
    x3[idx] = ssilu_f(h1[(long)n * 256 + c]);
    float vn = h1[(long)n * 256 + 128 + c];
    #pragma unroll
    for (int d = 0; d < 3; d++) {
        long r = (long)(n * 3 + d) * 128 + c;
        float wv = b2f(w2h[r]) + b2f(w2l[r]);
        float v = vn * wv;
        short hh = f2b(v);
        vecCh[r] = hh;
        vecCl[r] = f2b(v - b2f(hh));
    }
}

// ---------------- vecC @ o2_Wv2 (K=128, Nc=1): one wave per row ----------------
__global__ void __launch_bounds__(256) g12_kernel(const short* __restrict__ vecCh,
                                                  const short* __restrict__ vecCl,
                                                  const float* __restrict__ Wv2,
                                                  float* __restrict__ w4) {
    int row = blockIdx.x * 4 + (threadIdx.x >> 6);
    int lane = threadIdx.x & 63;
    long r0 = (long)row * 128 + lane;
    float v0 = b2f(vecCh[r0]) + b2f(vecCl[r0]);
    float v1 = b2f(vecCh[r0 + 64]) + b2f(vecCl[r0 + 64]);
    float s = v0 * Wv2[lane] + v1 * Wv2[64 + lane];
    #pragma unroll
    for (int off = 32; off > 0; off >>= 1) s += __shfl_down(s, off);
    if (lane == 0) w4[row] = s;
}

// ---------------- final: out[n,d] = (t5[n,:]@Wu2[:,1] + b2[1]) * w4[n,d] ----------
__global__ void __launch_bounds__(256) final_kernel(const float* __restrict__ t5,
                                                    const float* __restrict__ Wu2,
                                                    const float* __restrict__ bu2,
                                                    const float* __restrict__ w4,
                                                    float* __restrict__ out) {
    int n = blockIdx.x * 4 + (threadIdx.x >> 6);
    int lane = threadIdx.x & 63;
    float s = t5[(long)n * 128 + lane] * Wu2[lane * 2 + 1] +
              t5[(long)n * 128 + 64 + lane] * Wu2[(64 + lane) * 2 + 1];
    #pragma unroll
    for (int off = 32; off > 0; off >>= 1) s += __shfl_down(s, off);
    float val = __shfl(s, 0) + bu2[1];
    if (lane < 3) out[(long)n * 3 + lane] = val * w4[(long)n * 3 + lane];
}

extern "C" void kernel_launch(void* const* d_in, const int* in_sizes, int n_in,
                              void* d_out, int out_size, void* d_ws, size_t ws_size,
                              hipStream_t stream) {
    const float* x          = (const float*)d_in[0];
    const float* vec        = (const float*)d_in[1];
    const float* edge_rbf   = (const float*)d_in[2];
    const float* edge_vector= (const float*)d_in[3];
    const float* ln_g       = (const float*)d_in[4];
    const float* ln_b       = (const float*)d_in[5];
    const float* W_x1       = (const float*)d_in[6];
    const float* b_x1       = (const float*)d_in[7];
    const float* W_x2       = (const float*)d_in[8];
    const float* b_x2       = (const float*)d_in[9];
    const float* W_rbf      = (const float*)d_in[10];
    const float* b_rbf      = (const float*)d_in[11];
    const float* W_vp       = (const float*)d_in[12];
    const float* W_xv1      = (const float*)d_in[13];
    const float* b_xv1      = (const float*)d_in[14];
    const float* W_xv2      = (const float*)d_in[15];
    const float* b_xv2      = (const float*)d_in[16];
    const float* o1_Wv1     = (const float*)d_in[17];
    const float* o1_Wv2     = (const float*)d_in[18];
    const float* o1_Wu1     = (const float*)d_in[19];
    const float* o1_bu1     = (const float*)d_in[20];
    const float* o1_Wu2     = (const float*)d_in[21];
    const float* o1_bu2     = (const float*)d_in[22];
    const float* o2_Wv1     = (const float*)d_in[23];
    const float* o2_Wv2     = (const float*)d_in[24];
    const float* o2_Wu1     = (const float*)d_in[25];
    const float* o2_bu1     = (const float*)d_in[26];
    const float* o2_Wu2     = (const float*)d_in[27];
    const float* o2_bu2     = (const float*)d_in[28];
    const int*   edge_index = (const int*)d_in[29];
    float* out = (float*)d_out;
    float* ws  = (float*)d_ws;

    const size_t S = (size_t)NN * 256;
    const size_t Q = S / 4;              // 1,048,576 floats = 4 MiB
    // ---- arena in units of Q; peak 52Q = 208 MiB (proven safe) ----
    float* x1      = ws;                     // Q0-3   (fp32 S)
    float* vecacc  = ws + 4 * Q;             // Q4-15  (fp32 3S)
    short* wtb     = (short*)(ws + 16 * Q);  // Q16-17 weights hi + lo
    const long WLO = 1114112;
    // phase 1
    short* xln_h = (short*)(ws + 18 * Q);    // Q18-19 (dead after t1 gemm)
    short* xln_l = (short*)(ws + 20 * Q);    // Q20-21
    short* t1_h  = (short*)(ws + 22 * Q);    // Q22-23 (dead after xh gemm)
    short* t1_l  = (short*)(ws + 24 * Q);    // Q24-25
    float* xh    = ws + 30 * Q;              // Q30-41 (fp32 3S, dead after gather)
    // phase 2 sort scratch (dead before vdot is written)
    int* rowptr    = (int*)(ws + 48 * Q);
    int* cursor    = rowptr + (NN + 1);
    int* dhist     = cursor + NN;
    int* nodeorder = dhist + 64;
    int* perm      = nodeorder + NN;
    // phase 3 (vah/val_ written by node_gather directly)
    short* vah   = (short*)(ws + 18 * Q);    // Q18-23 (3S bf16)
    short* val_  = (short*)(ws + 24 * Q);    // Q24-29
    float* vec1  = ws + 30 * Q;              // Q30-41 (fp32 3S, live till e4)
    short* vec2b = (short*)(ws + 42 * Q);    // Q42-47 (bf16 3S)
    float* vdot  = ws + 48 * Q;              // Q48-51 (fp32 S, live till e4)
    short* catb_h = (short*)(ws + 18 * Q);   // Q18-21 (vah dead after vp gemms)
    short* catb_l = (short*)(ws + 22 * Q);   // Q22-25
    short* t2_h  = (short*)(ws + 26 * Q);    // Q26-27
    short* t2_l  = (short*)(ws + 28 * Q);    // Q28-29
    short* xvh_h = (short*)(ws + 18 * Q);    // Q18-23 (catb dead)
    short* xvh_l = (short*)(ws + 42 * Q);    // Q42-47 (vec2 dead)
    // phase 4
    short* vah2  = (short*)(ws + 18 * Q);    // Q18-23
    short* val2  = (short*)(ws + 24 * Q);    // Q24-29
    short* w1b   = (short*)(ws + 30 * Q);    // Q30-35 (bf16 3S)
    short* w2_h  = (short*)(ws + 36 * Q);    // Q36-38
    short* w2_l  = (short*)(ws + 39 * Q);    // Q39-41
    short* cat2_h = (short*)(ws + 42 * Q);   // Q42-45
    short* cat2_l = (short*)(ws + 46 * Q);   // Q46-49
    short* t4_h  = (short*)(ws + 18 * Q);    // Q18-19
    short* t4_l  = (short*)(ws + 20 * Q);    // Q20-21
    float* h1    = ws + 22 * Q;              // Q22-25 (fp32 S)
    float* x3    = ws + 26 * Q;              // Q26-27 (fp32 S/2)
    short* vecC_h = (short*)(ws + 28 * Q);   // Q28-30
    short* vecC_l = (short*)(ws + 31 * Q);   // Q31-33
    // phase 5
    short* w3b   = (short*)(ws + 34 * Q);    // Q34-36
    float* w4    = ws + 37 * Q;              // Q37
    short* cat3_h = (short*)(ws + 38 * Q);   // Q38-39
    short* cat3_l = (short*)(ws + 40 * Q);   // Q40-41
    float* t5    = ws + 42 * Q;              // Q42-43

    // weight hi/lo offsets (shorts)
    short* WT_x1    = wtb;
    short* WT_x2    = wtb + 65536;
    short* WT_vp    = wtb + 262144;
    short* WT_xv1   = wtb + 393216;
    short* WT_xv2   = wtb + 524288;
    short* WT_o1Wv1 = wtb + 720896;
    short* WT_o1Wv2 = wtb + 786432;
    short* WT_o1Wu1 = wtb + 819200;
    short* WT_o1Wu2 = wtb + 950272;
    short* WT_o2Wv1 = wtb + 1015808;
    short* WT_o2Wu1 = wtb + 1032192;
    short* WT_rbf   = wtb + 1064960;         // 768 x 64

    // Phase 0: all weight transposes + splits in one launch (incl. W_rbf^T)
    WtArgs wa;
    const float* wsrc[12] = {W_x1, W_x2, W_vp, W_xv1, W_xv2, o1_Wv1, o1_Wv2,
                             o1_Wu1, o1_Wu2, o2_Wv1, o2_Wu1, W_rbf};
    int wk[12] = {256, 256, 256, 512, 256, 256, 256, 512, 256, 128, 256, 64};
    int wn[12] = {256, 768, 512, 256, 768, 256, 128, 256, 256, 128, 128, 768};
    int off = 0;
    for (int i = 0; i < 12; i++) {
        wa.W[i] = wsrc[i]; wa.K[i] = wk[i]; wa.N[i] = wn[i];
        wa.off[i] = off; off += wk[i] * wn[i];
    }
    wa.off[12] = off;  // 1,114,112
    wt_split_all<<<off / 256, 256, 0, stream>>>(wa, wtb, wtb + WLO);

    // Phase 1: node MLP
    ln_kernel<<<NN, 256, 0, stream>>>(x, ln_g, ln_b, xln_h, xln_l);
    mfma_gemm<<<dim3(NN / 128, 4), 256, 0, stream>>>(xln_h, xln_l, WT_x1, WT_x1 + WLO,
                                                     b_x1, t1_h, t1_l, NN, 256, 256, 1);
    mfma_gemm<<<dim3(NN / 128, 12), 256, 0, stream>>>(t1_h, t1_l, WT_x2, WT_x2 + WLO,
                                                      b_x2, xh, nullptr, NN, 256, 768, 0);

    // Phase 2: sort edges by dst; node order by desc degree; CSR gather (no atomics)
    zero_kernel<<<(NN + 64 + 255) / 256, 256, 0, stream>>>(cursor, NN + 64);
    hist_kernel<<<EE / 256, 256, 0, stream>>>(edge_index, cursor);
    scan_kernel<<<1, 256, 0, stream>>>(cursor, rowptr);
    scatter_kernel<<<EE / 256, 256, 0, stream>>>(edge_index, cursor, perm);
    deg_hist_kernel<<<NN / 256, 256, 0, stream>>>(rowptr, dhist);
    deg_scan_kernel<<<1, 64, 0, stream>>>(dhist);
    deg_scatter_kernel<<<NN / 256, 256, 0, stream>>>(rowptr, dhist, nodeorder);
    node_gather_kernel<<<NN, 256, 0, stream>>>(edge_rbf, WT_rbf, WT_rbf + WLO,
                                               b_rbf, xh, vec, edge_vector, edge_index,
                                               x, perm, rowptr, nodeorder, x1, vecacc,
                                               vah, val_);

    // Phase 3: vp, vdot/vnorm, xv MLP, in-place updates
    mfma_gemm<<<dim3(3 * NN / 128, 4), 256, 0, stream>>>(vah, val_, WT_vp, WT_vp + WLO,
                                                         nullptr, vec1, nullptr,
                                                         3 * NN, 256, 256, 0);
    mfma_gemm<<<dim3(3 * NN / 128, 4), 256, 0, stream>>>(vah, val_, WT_vp + 65536,
                                                         WT_vp + WLO + 65536,
                                                         nullptr, vec2b, nullptr,
                                                         3 * NN, 256, 256, 2);
    vdot_cat_kernel<<<NN, 256, 0, stream>>>(vec1, vec2b, x1, vdot, catb_h, catb_l);
    mfma_gemm<<<dim3(NN / 128, 4), 256, 0, stream>>>(catb_h, catb_l, WT_xv1, WT_xv1 + WLO,
                                                     b_xv1, t2_h, t2_l, NN, 512, 256, 1);
    mfma_gemm<<<dim3(NN / 128, 12), 256, 0, stream>>>(t2_h, t2_l, WT_xv2, WT_xv2 + WLO,
                                                      b_xv2, xvh_h, xvh_l, NN, 256, 768, 0);
    e4_kernel<<<NN, 256, 0, stream>>>(x1, vecacc, vec1, vdot, xvh_h, xvh_l);

    // Phase 4: gated equivariant block 1
    split4_kernel<<<3 * S / 1024, 256, 0, stream>>>(vecacc, vah2, val2);
    mfma_gemm<<<dim3(3 * NN / 128, 4), 256, 0, stream>>>(vah2, val2, WT_o1Wv1, WT_o1Wv1 + WLO,
                                                         nullptr, w1b, nullptr,
                                                         3 * NN, 256, 256, 2);
    mfma_gemm<<<dim3(3 * NN / 128, 2), 256, 0, stream>>>(vah2, val2, WT_o1Wv2, WT_o1Wv2 + WLO,
                                                         nullptr, w2_h, w2_l,
                                                         3 * NN, 256, 128, 0);
    normcat_kernel<<<NN * 512 / 256, 256, 0, stream>>>(x1, w1b, cat2_h, cat2_l, 256, 256, 9);
    mfma_gemm<<<dim3(NN / 128, 4), 256, 0, stream>>>(cat2_h, cat2_l, WT_o1Wu1, WT_o1Wu1 + WLO,
                                                     o1_bu1, t4_h, t4_l, NN, 512, 256, 1);
    mfma_gemm<<<dim3(NN / 128, 4), 256, 0, stream>>>(t4_h, t4_l, WT_o1Wu2, WT_o1Wu2 + WLO,
                                                     o1_bu2, h1, nullptr, NN, 256, 256, 0);
    gate1_kernel<<<NN * 128 / 256, 256, 0, stream>>>(h1, w2_h, w2_l, x3, vecC_h, vecC_l);

    // Phase 5: gated equivariant block 2 + output
    mfma_gemm<<<dim3(3 * NN / 128, 2), 256, 0, stream>>>(vecC_h, vecC_l, WT_o2Wv1,
                                                         WT_o2Wv1 + WLO, nullptr,
                                                         w3b, nullptr, 3 * NN, 128, 128, 2);
    g12_kernel<<<3 * NN / 4, 256, 0, stream>>>(vecC_h, vecC_l, o2_Wv2, w4);
    normcat_kernel<<<NN * 256 / 256, 256, 0, stream>>>(x3, w3b, cat3_h, cat3_l, 128, 128, 8);
    mfma_gemm<<<dim3(NN / 128, 2), 256, 0, stream>>>(cat3_h, cat3_l, WT_o2Wu1, WT_o2Wu1 + WLO,
                                                     o2_bu1, t5, nullptr, NN, 256, 128, 1);
    final_kernel<<<NN / 4, 256, 0, stream>>>(t5, o2_Wu2, o2_bu2, w4, out);
}

// Round 3
// 1688.783 us; speedup vs baseline: 1.5648x; 1.4388x over previous
//
#include <hip/hip_runtime.h>
#include <math.h>

#define NN 16384
#define EE 262144
#define HH 256

#define INV_SQRT_3f 0.57735026918962576f
#define INV_SQRT_Hf 0.0625f
#define INV_SQRT_2f 0.70710678118654752f
#define SSILU_SCALE 1.6666666666666667f

typedef __attribute__((ext_vector_type(8))) short bf16x8;
typedef __attribute__((ext_vector_type(4))) float f32x4;

__device__ __forceinline__ float ssilu_f(float v) {
    return v * (1.0f / (1.0f + __expf(-v))) * SSILU_SCALE;
}
__device__ __forceinline__ float b2f(short s) {
    unsigned int u = ((unsigned int)(unsigned short)s) << 16;
    return __uint_as_float(u);
}
__device__ __forceinline__ short f2b(float f) {
    unsigned int u = __float_as_uint(f);
    unsigned int r = (u + 0x7fff + ((u >> 16) & 1)) >> 16;
    return (short)r;
}

// ---------------- LayerNorm: one block per row, split-bf16 out ----------------
__global__ void __launch_bounds__(256) ln_kernel(const float* __restrict__ x,
                                                 const float* __restrict__ g,
                                                 const float* __restrict__ b,
                                                 short* __restrict__ oh,
                                                 short* __restrict__ ol) {
    int n = blockIdx.x;
    int t = threadIdx.x;
    float v = x[(long)n * HH + t];
    float s = v, s2 = v * v;
    #pragma unroll
    for (int off = 32; off > 0; off >>= 1) {
        s  += __shfl_down(s, off);
        s2 += __shfl_down(s2, off);
    }
    __shared__ float red[8];
    int wave = t >> 6, lane = t & 63;
    if (lane == 0) { red[wave] = s; red[4 + wave] = s2; }
    __syncthreads();
    __shared__ float mr[2];
    if (t == 0) {
        float ts = red[0] + red[1] + red[2] + red[3];
        float ts2 = red[4] + red[5] + red[6] + red[7];
        float mean = ts * (1.0f / HH);
        float var = ts2 * (1.0f / HH) - mean * mean;
        mr[0] = mean;
        mr[1] = rsqrtf(var + 1e-5f);
    }
    __syncthreads();
    float o = (v - mr[0]) * mr[1] * g[t] + b[t];
    short hh = f2b(o);
    oh[(long)n * HH + t] = hh;
    ol[(long)n * HH + t] = f2b(o - b2f(hh));
}

// ---- ALL weight transposes + hi/lo splits in ONE kernel (incl. W_rbf) ----
struct WtArgs {
    const float* W[12];
    int K[12];
    int N[12];
    int off[13];   // cumulative element offsets; off[12] = total
};

__global__ void __launch_bounds__(256) wt_split_all(WtArgs a,
                                                    short* __restrict__ WTh,
                                                    short* __restrict__ WTl) {
    int idx = blockIdx.x * 256 + threadIdx.x;
    int s = 0;
    #pragma unroll
    for (int i = 1; i < 12; i++) s += (idx >= a.off[i]) ? 1 : 0;
    int local = idx - a.off[s];
    int K = a.K[s], N = a.N[s];
    int k = local / N, n = local - k * N;
    float w = a.W[s][local];
    short hh = f2b(w);
    long o = (long)a.off[s] + (long)n * K + k;
    WTh[o] = hh;
    WTl[o] = f2b(w - b2f(hh));
}

// ---- fp32 -> hi/lo split (count % 1024 == 0) ----
__global__ void __launch_bounds__(256) split4_kernel(const float* __restrict__ in,
                                                     short* __restrict__ h,
                                                     short* __restrict__ l) {
    long i = ((long)blockIdx.x * 256 + threadIdx.x) * 4;
    float4 v = *(const float4*)(in + i);
    short4 oh, ol;
    oh.x = f2b(v.x); ol.x = f2b(v.x - b2f(oh.x));
    oh.y = f2b(v.y); ol.y = f2b(v.y - b2f(oh.y));
    oh.z = f2b(v.z); ol.z = f2b(v.z - b2f(oh.z));
    oh.w = f2b(v.w); ol.w = f2b(v.w - b2f(oh.w));
    *(short4*)(h + i) = oh;
    *(short4*)(l + i) = ol;
}

// ---- split-bf16 MFMA GEMM v2: C = (Ah+Al)(M,K) @ (Wh+Wl)^T(N,K) [+bias][ssilu]
__global__ void __launch_bounds__(256) mfma_gemm(const short* __restrict__ Ah,
                                                 const short* __restrict__ Al,
                                                 const short* __restrict__ Wh,
                                                 const short* __restrict__ Wl,
                                                 const float* __restrict__ bias,
                                                 void* __restrict__ Ch,
                                                 short* __restrict__ Cl,
                                                 int M, int K, int N, int act) {
    int tid = threadIdx.x;
    int wave = tid >> 6, lane = tid & 63;
    int quad = lane >> 4, l16 = lane & 15;
    long bm = (long)blockIdx.x * 128 + wave * 32;
    long bn = (long)blockIdx.y * 64;
    long a0 = (bm + l16) * K + quad * 8;
    long a1 = a0 + (long)16 * K;
    long w0 = (bn + l16) * K + quad * 8;

    f32x4 acc[2][4];
    #pragma unroll
    for (int f = 0; f < 2; f++)
        #pragma unroll
        for (int t = 0; t < 4; t++) acc[f][t] = (f32x4){0.f, 0.f, 0.f, 0.f};

    bf16x8 cah[2], cal[2], cbh[4], cbl[4];
    cah[0] = *(const bf16x8*)(Ah + a0);
    cah[1] = *(const bf16x8*)(Ah + a1);
    cal[0] = *(const bf16x8*)(Al + a0);
    cal[1] = *(const bf16x8*)(Al + a1);
    #pragma unroll
    for (int t = 0; t < 4; t++) {
        long wo = w0 + (long)t * 16 * K;
        cbh[t] = *(const bf16x8*)(Wh + wo);
        cbl[t] = *(const bf16x8*)(Wl + wo);
    }

    for (int k0 = 0; k0 < K; k0 += 32) {
        int k1 = k0 + 32;
        bf16x8 nah[2], nal[2], nbh[4], nbl[4];
        if (k1 < K) {
            nah[0] = *(const bf16x8*)(Ah + a0 + k1);
            nah[1] = *(const bf16x8*)(Ah + a1 + k1);
            nal[0] = *(const bf16x8*)(Al + a0 + k1);
            nal[1] = *(const bf16x8*)(Al + a1 + k1);
            #pragma unroll
            for (int t = 0; t < 4; t++) {
                long wo = w0 + (long)t * 16 * K + k1;
                nbh[t] = *(const bf16x8*)(Wh + wo);
                nbl[t] = *(const bf16x8*)(Wl + wo);
            }
        }
        #pragma unroll
        for (int t = 0; t < 4; t++) {
            #pragma unroll
            for (int f = 0; f < 2; f++) {
                acc[f][t] = __builtin_amdgcn_mfma_f32_16x16x32_bf16(cah[f], cbh[t], acc[f][t], 0, 0, 0);
                acc[f][t] = __builtin_amdgcn_mfma_f32_16x16x32_bf16(cal[f], cbh[t], acc[f][t], 0, 0, 0);
                acc[f][t] = __builtin_amdgcn_mfma_f32_16x16x32_bf16(cah[f], cbl[t], acc[f][t], 0, 0, 0);
            }
        }
        if (k1 < K) {
            cah[0] = nah[0]; cah[1] = nah[1];
            cal[0] = nal[0]; cal[1] = nal[1];
            #pragma unroll
            for (int t = 0; t < 4; t++) { cbh[t] = nbh[t]; cbl[t] = nbl[t]; }
        }
    }

    #pragma unroll
    for (int f = 0; f < 2; f++) {
        long row0 = bm + f * 16 + quad * 4;
        #pragma unroll
        for (int t = 0; t < 4; t++) {
            long col = bn + t * 16 + l16;
            float bv = bias ? bias[col] : 0.f;
            #pragma unroll
            for (int r = 0; r < 4; r++) {
                float v = acc[f][t][r] + bv;
                if (act & 1) v = ssilu_f(v);
                long idx = (row0 + r) * N + col;
                if (Cl) {
                    short hh = f2b(v);
                    ((short*)Ch)[idx] = hh;
                    Cl[idx] = f2b(v - b2f(hh));
                } else if (act & 2) {
                    ((short*)Ch)[idx] = f2b(v);
                } else {
                    ((float*)Ch)[idx] = v;
                }
            }
        }
    }
}

// ---------------- edge sort (counting sort by dst) ----------------
__global__ void __launch_bounds__(256) zero_kernel(int* __restrict__ p, int n) {
    int i = blockIdx.x * 256 + threadIdx.x;
    if (i < n) p[i] = 0;
}

__global__ void __launch_bounds__(256) hist_kernel(const int* __restrict__ eidx,
                                                   int* __restrict__ cnt) {
    int e = blockIdx.x * 256 + threadIdx.x;
    atomicAdd(&cnt[eidx[EE + e]], 1);
}

__global__ void __launch_bounds__(256) scan_kernel(int* __restrict__ cursor,
                                                   int* __restrict__ rowptr) {
    int t = threadIdx.x;
    int base_i = t * 64;
    int tsum = 0;
    for (int i = 0; i < 64; i++) tsum += cursor[base_i + i];
    __shared__ int ls[256];
    ls[t] = tsum;
    __syncthreads();
    for (int off = 1; off < 256; off <<= 1) {
        int v = (t >= off) ? ls[t - off] : 0;
        __syncthreads();
        ls[t] += v;
        __syncthreads();
    }
    int running = ls[t] - tsum;
    for (int i = 0; i < 64; i++) {
        int c = cursor[base_i + i];
        rowptr[base_i + i] = running;
        cursor[base_i + i] = running;
        running += c;
    }
    if (t == 255) rowptr[NN] = running;
}

// scatter: also materialize dst/src/ev in sorted order for the edge kernel
__global__ void __launch_bounds__(256) scatter_kernel(const int* __restrict__ eidx,
                                                      const float* __restrict__ ev,
                                                      int* __restrict__ cursor,
                                                      int* __restrict__ perm,
                                                      int* __restrict__ dsts,
                                                      int* __restrict__ srcs,
                                                      float* __restrict__ evs) {
    int e = blockIdx.x * 256 + threadIdx.x;
    int s_ = eidx[e];
    int d_ = eidx[EE + e];
    int pos = atomicAdd(&cursor[d_], 1);
    perm[pos] = e;
    dsts[pos] = d_;
    srcs[pos] = s_;
    evs[pos * 3 + 0] = ev[e * 3 + 0];
    evs[pos * 3 + 1] = ev[e * 3 + 1];
    evs[pos * 3 + 2] = ev[e * 3 + 2];
}

// ---------------- Edge-parallel fused rbf-GEMM + gather + atomic reduce -------
// Grid (EE/128, 12). Block = 4 waves; rows = 128 consecutive dst-sorted edge
// positions, cols = one 64-wide tile of the 768 rbfh outputs (section = by>>2).
// Phase A: m = (rbf[perm]@W_rbf^T + b) via split-bf16 MFMA (A converted fp32->
// hi/lo in registers, B = WT_rbf, L2-resident). Each wave's 32 rows -> LDS.
// Phase B (after 1 barrier): wave g, 64 lanes = 64 consecutive cols, iterates
// its own 32 rows; gathers xh/vec rows (coalesced 256B per wave) and
// run-accumulates over consecutive same-dst edges (wave-uniform branch),
// atomicAdd per run into x1/vecacc (pre-initialized with x/vec).
__global__ void __launch_bounds__(256) edge_gather_kernel(
        const float* __restrict__ rbf,
        const short* __restrict__ Wrh,
        const short* __restrict__ Wrl,
        const float* __restrict__ b_rbf,
        const float* __restrict__ xh,
        const float* __restrict__ vec,
        const int* __restrict__ perm,
        const int* __restrict__ dsts,
        const int* __restrict__ srcs,
        const float* __restrict__ evs,
        float* __restrict__ x1,
        float* __restrict__ vecacc) {
    int tid = threadIdx.x;
    int wave = tid >> 6, lane = tid & 63;
    int quad = lane >> 4, l16 = lane & 15;
    int bm = blockIdx.x * 128;
    int bn = blockIdx.y * 64;
    int sec = bn >> 8;               // 0: m1, 1: m2, 2: m3
    int cbase = bn & 255;            // col base within section

    __shared__ __align__(16) float mlds[128][66];
    __shared__ int dst_s[128], src_s[128];
    __shared__ float ev_s[128][3];

    // stage dst/src (+ev for sec 2)
    if (tid < 128) {
        dst_s[tid] = dsts[bm + tid];
        src_s[tid] = srcs[bm + tid];
    } else if (sec == 2) {
        int i = tid - 128;
        ev_s[i][0] = evs[(long)(bm + i) * 3 + 0];
        ev_s[i][1] = evs[(long)(bm + i) * 3 + 1];
        ev_s[i][2] = evs[(long)(bm + i) * 3 + 2];
    }

    // ---- A fragments: rbf rows via perm, fp32 -> split hi/lo in registers ----
    int r0 = bm + wave * 32 + l16;
    int e0 = perm[r0];
    int e1 = perm[r0 + 16];
    bf16x8 afh[2][2], afl[2][2];     // [f][ks]
    #pragma unroll
    for (int f = 0; f < 2; f++) {
        long ebase = (long)(f == 0 ? e0 : e1) * 64 + quad * 8;
        #pragma unroll
        for (int ks = 0; ks < 2; ks++) {
            float4 ua = *(const float4*)(rbf + ebase + ks * 32);
            float4 ub = *(const float4*)(rbf + ebase + ks * 32 + 4);
            float vv[8] = {ua.x, ua.y, ua.z, ua.w, ub.x, ub.y, ub.z, ub.w};
            bf16x8 hh, ll;
            #pragma unroll
            for (int j = 0; j < 8; j++) {
                short hb = f2b(vv[j]);
                hh[j] = hb;
                ll[j] = f2b(vv[j] - b2f(hb));
            }
            afh[f][ks] = hh;
            afl[f][ks] = ll;
        }
    }

    f32x4 acc[2][4];
    #pragma unroll
    for (int t = 0; t < 4; t++) {
        float bv = b_rbf[bn + t * 16 + l16];
        acc[0][t] = (f32x4){bv, bv, bv, bv};
        acc[1][t] = (f32x4){bv, bv, bv, bv};
    }
    #pragma unroll
    for (int t = 0; t < 4; t++) {
        #pragma unroll
        for (int ks = 0; ks < 2; ks++) {
            long wo = (long)(bn + t * 16 + l16) * 64 + ks * 32 + quad * 8;
            bf16x8 bh = *(const bf16x8*)(Wrh + wo);
            bf16x8 bl = *(const bf16x8*)(Wrl + wo);
            #pragma unroll
            for (int f = 0; f < 2; f++) {
                acc[f][t] = __builtin_amdgcn_mfma_f32_16x16x32_bf16(afh[f][ks], bh, acc[f][t], 0, 0, 0);
                acc[f][t] = __builtin_amdgcn_mfma_f32_16x16x32_bf16(afl[f][ks], bh, acc[f][t], 0, 0, 0);
                acc[f][t] = __builtin_amdgcn_mfma_f32_16x16x32_bf16(afh[f][ks], bl, acc[f][t], 0, 0, 0);
            }
        }
    }
    #pragma unroll
    for (int f = 0; f < 2; f++)
        #pragma unroll
        for (int t = 0; t < 4; t++)
            #pragma unroll
            for (int r = 0; r < 4; r++)
                mlds[wave * 32 + f * 16 + quad * 4 + r][t * 16 + l16] = acc[f][t][r];
    __syncthreads();

    // ---- consume: wave owns its 32 rows; lane owns one column ----
    int base = wave * 32;
    int colx = cbase + lane;                 // 0..255 within section
    if (sec == 0) {
        float a = 0.f;
        int dprev = dst_s[base];
        #pragma unroll 4
        for (int i = 0; i < 32; i++) {
            int d = dst_s[base + i];
            if (d != dprev) {
                atomicAdd(&x1[(long)dprev * 256 + colx], a);
                a = 0.f;
                dprev = d;
            }
            long xb = (long)src_s[base + i] * 768;
            a += mlds[base + i][lane] * xh[xb + colx];
        }
        atomicAdd(&x1[(long)dprev * 256 + colx], a);
    } else if (sec == 1) {
        float a0 = 0.f, a1 = 0.f, a2 = 0.f;
        int dprev = dst_s[base];
        #pragma unroll 4
        for (int i = 0; i < 32; i++) {
            int d = dst_s[base + i];
            if (d != dprev) {
                long vb = (long)dprev * 768 + colx;
                atomicAdd(&vecacc[vb], a0);
                atomicAdd(&vecacc[vb + 256], a1);
                atomicAdd(&vecacc[vb + 512], a2);
                a0 = a1 = a2 = 0.f;
                dprev = d;
            }
            long xb = (long)src_s[base + i] * 768;
            float m2 = mlds[base + i][lane] * (INV_SQRT_3f * INV_SQRT_Hf) *
                       xh[xb + 256 + colx];
            a0 += vec[xb + colx] * m2;
            a1 += vec[xb + 256 + colx] * m2;
            a2 += vec[xb + 512 + colx] * m2;
        }
        long vb = (long)dprev * 768 + colx;
        atomicAdd(&vecacc[vb], a0);
        atomicAdd(&vecacc[vb + 256], a1);
        atomicAdd(&vecacc[vb + 512], a2);
    } else {
        float a0 = 0.f, a1 = 0.f, a2 = 0.f;
        int dprev = dst_s[base];
        #pragma unroll 4
        for (int i = 0; i < 32; i++) {
            int d = dst_s[base + i];
            if (d != dprev) {
                long vb = (long)dprev * 768 + colx;
                atomicAdd(&vecacc[vb], a0);
                atomicAdd(&vecacc[vb + 256], a1);
                atomicAdd(&vecacc[vb + 512], a2);
                a0 = a1 = a2 = 0.f;
                dprev = d;
            }
            long xb = (long)src_s[base + i] * 768;
            float m3 = mlds[base + i][lane] * INV_SQRT_Hf * xh[xb + 512 + colx];
            a0 += m3 * ev_s[base + i][0];
            a1 += m3 * ev_s[base + i][1];
            a2 += m3 * ev_s[base + i][2];
        }
        long vb = (long)dprev * 768 + colx;
        atomicAdd(&vecacc[vb], a0);
        atomicAdd(&vecacc[vb + 256], a1);
        atomicAdd(&vecacc[vb + 512], a2);
    }
}

// ---------------- vec_dot + vnorm + cat(x, vnorm), split out ----------------
__global__ void __launch_bounds__(256) vdot_cat_kernel(const float* __restrict__ vec1,
                                                       const short* __restrict__ vec2,
                                                       const float* __restrict__ x1,
                                                       float* __restrict__ vdot,
                                                       short* __restrict__ cath,
                                                       short* __restrict__ catl) {
    int idx = blockIdx.x * 256 + threadIdx.x;
    int n = idx >> 8, h = idx & 255;
    float dsum = 0.f, s2 = 0.f;
    #pragma unroll
    for (int d = 0; d < 3; d++) {
        long r = (long)(n * 3 + d) * 256 + h;
        float a = vec1[r];
        float b = b2f(vec2[r]);
        dsum += a * b;
        s2 += b * b;
    }
    vdot[idx] = dsum * INV_SQRT_Hf;
    float xv = x1[idx];
    short hh = f2b(xv);
    cath[(long)n * 512 + h] = hh;
    catl[(long)n * 512 + h] = f2b(xv - b2f(hh));
    float vn = sqrtf(s2 + 1e-8f);
    short vh = f2b(vn);
    cath[(long)n * 512 + 256 + h] = vh;
    catl[(long)n * 512 + 256 + h] = f2b(vn - b2f(vh));
}

// ---------------- x/vec update after xv MLP (IN-PLACE) ----------------
__global__ void __launch_bounds__(256) e4_kernel(float* __restrict__ x1,
                                                 float* __restrict__ vecacc,
                                                 const float* __restrict__ vec1,
                                                 const float* __restrict__ vdot,
                                                 const short* __restrict__ xvh_h,
                                                 const short* __restrict__ xvh_l) {
    int idx = blockIdx.x * 256 + threadIdx.x;
    int n = idx >> 8, h = idx & 255;
    long b0 = (long)n * 768 + h;
    float xv1 = b2f(xvh_h[b0])       + b2f(xvh_l[b0]);
    float xv2 = b2f(xvh_h[b0 + 256]) + b2f(xvh_l[b0 + 256]);
    float xv3 = b2f(xvh_h[b0 + 512]) + b2f(xvh_l[b0 + 512]);
    x1[idx] = x1[idx] + (xv1 + xv2 * vdot[idx]) * INV_SQRT_2f;
    #pragma unroll
    for (int d = 0; d < 3; d++) {
        long r = (long)(n * 3 + d) * 256 + h;
        vecacc[r] = vecacc[r] + xv3 * vec1[r];
    }
}

// ---------------- norm over d + concat(x fp32, norm), split out ----------------
__global__ void __launch_bounds__(256) normcat_kernel(const float* __restrict__ xin,
                                                      const short* __restrict__ w,
                                                      short* __restrict__ cath,
                                                      short* __restrict__ catl,
                                                      int Cx, int C, int shift) {
    int idx = blockIdx.x * 256 + threadIdx.x;
    int cols = 1 << shift;
    int n = idx >> shift, c = idx & (cols - 1);
    float v;
    if (c < Cx) {
        v = xin[(long)n * Cx + c];
    } else {
        int cc = c - Cx;
        float s = 0.f;
        #pragma unroll
        for (int d = 0; d < 3; d++) {
            float a = b2f(w[(long)(n * 3 + d) * C + cc]);
            s += a * a;
        }
        v = sqrtf(s);
    }
    short hh = f2b(v);
    cath[idx] = hh;
    catl[idx] = f2b(v - b2f(hh));
}

// ---------------- gated block 1 epilogue ----------------
__global__ void __launch_bounds__(256) gate1_kernel(const float* __restrict__ h1,
                                                    const short* __restrict__ w2h,
                                                    const short* __restrict__ w2l,
                                                    float* __restrict__ x3,
                                                    short* __restrict__ vecCh,
                                                    short* __restrict__ vecCl) {
    int idx = blockIdx.x * 256 + threadIdx.x;
    int n = idx >> 7, c = idx & 127;
    x3[idx] = ssilu_f(h1[(long)n * 256 + c]);
    float vn = h1[(long)n * 256 + 128 + c];
    #pragma unroll
    for (int d = 0; d < 3; d++) {
        long r = (long)(n * 3 + d) * 128 + c;
        float wv = b2f(w2h[r]) + b2f(w2l[r]);
        float v = vn * wv;
        short hh = f2b(v);
        vecCh[r] = hh;
        vecCl[r] = f2b(v - b2f(hh));
    }
}

// ---------------- vecC @ o2_Wv2 (K=128, Nc=1): one wave per row ----------------
__global__ void __launch_bounds__(256) g12_kernel(const short* __restrict__ vecCh,
                                                  const short* __restrict__ vecCl,
                                                  const float* __restrict__ Wv2,
                                                  float* __restrict__ w4) {
    int row = blockIdx.x * 4 + (threadIdx.x >> 6);
    int lane = threadIdx.x & 63;
    long r0 = (long)row * 128 + lane;
    float v0 = b2f(vecCh[r0]) + b2f(vecCl[r0]);
    float v1 = b2f(vecCh[r0 + 64]) + b2f(vecCl[r0 + 64]);
    float s = v0 * Wv2[lane] + v1 * Wv2[64 + lane];
    #pragma unroll
    for (int off = 32; off > 0; off >>= 1) s += __shfl_down(s, off);
    if (lane == 0) w4[row] = s;
}

// ---------------- final: out[n,d] = (t5[n,:]@Wu2[:,1] + b2[1]) * w4[n,d] ----------
__global__ void __launch_bounds__(256) final_kernel(const float* __restrict__ t5,
                                                    const float* __restrict__ Wu2,
                                                    const float* __restrict__ bu2,
                                                    const float* __restrict__ w4,
                                                    float* __restrict__ out) {
    int n = blockIdx.x * 4 + (threadIdx.x >> 6);
    int lane = threadIdx.x & 63;
    float s = t5[(long)n * 128 + lane] * Wu2[lane * 2 + 1] +
              t5[(long)n * 128 + 64 + lane] * Wu2[(64 + lane) * 2 + 1];
    #pragma unroll
    for (int off = 32; off > 0; off >>= 1) s += __shfl_down(s, off);
    float val = __shfl(s, 0) + bu2[1];
    if (lane < 3) out[(long)n * 3 + lane] = val * w4[(long)n * 3 + lane];
}

extern "C" void kernel_launch(void* const* d_in, const int* in_sizes, int n_in,
                              void* d_out, int out_size, void* d_ws, size_t ws_size,
                              hipStream_t stream) {
    const float* x          = (const float*)d_in[0];
    const float* vec        = (const float*)d_in[1];
    const float* edge_rbf   = (const float*)d_in[2];
    const float* edge_vector= (const float*)d_in[3];
    const float* ln_g       = (const float*)d_in[4];
    const float* ln_b       = (const float*)d_in[5];
    const float* W_x1       = (const float*)d_in[6];
    const float* b_x1       = (const float*)d_in[7];
    const float* W_x2       = (const float*)d_in[8];
    const float* b_x2       = (const float*)d_in[9];
    const float* W_rbf      = (const float*)d_in[10];
    const float* b_rbf      = (const float*)d_in[11];
    const float* W_vp       = (const float*)d_in[12];
    const float* W_xv1      = (const float*)d_in[13];
    const float* b_xv1      = (const float*)d_in[14];
    const float* W_xv2      = (const float*)d_in[15];
    const float* b_xv2      = (const float*)d_in[16];
    const float* o1_Wv1     = (const float*)d_in[17];
    const float* o1_Wv2     = (const float*)d_in[18];
    const float* o1_Wu1     = (const float*)d_in[19];
    const float* o1_bu1     = (const float*)d_in[20];
    const float* o1_Wu2     = (const float*)d_in[21];
    const float* o1_bu2     = (const float*)d_in[22];
    const float* o2_Wv1     = (const float*)d_in[23];
    const float* o2_Wv2     = (const float*)d_in[24];
    const float* o2_Wu1     = (const float*)d_in[25];
    const float* o2_bu1     = (const float*)d_in[26];
    const float* o2_Wu2     = (const float*)d_in[27];
    const float* o2_bu2     = (const float*)d_in[28];
    const int*   edge_index = (const int*)d_in[29];
    float* out = (float*)d_out;
    float* ws  = (float*)d_ws;

    const size_t S = (size_t)NN * 256;
    const size_t Q = S / 4;              // 1,048,576 floats = 4 MiB
    // ---- arena in units of Q; peak 52Q = 208 MiB (proven safe) ----
    float* x1      = ws;                     // Q0-3   (fp32 S)
    float* vecacc  = ws + 4 * Q;             // Q4-15  (fp32 3S)
    short* wtb     = (short*)(ws + 16 * Q);  // Q16-17 weights hi + lo
    const long WLO = 1114112;
    // phase 1
    short* xln_h = (short*)(ws + 18 * Q);    // Q18-19 (dead after t1 gemm)
    short* xln_l = (short*)(ws + 20 * Q);    // Q20-21
    short* t1_h  = (short*)(ws + 22 * Q);    // Q22-23 (dead after xh gemm)
    short* t1_l  = (short*)(ws + 24 * Q);    // Q24-25
    float* xh    = ws + 30 * Q;              // Q30-41 (fp32 3S, dead after gather)
    // phase 2 sort scratch (dead before vdot is written)
    int* rowptr    = (int*)(ws + 48 * Q);    // NN+1
    int* cursor    = rowptr + (NN + 1);      // NN
    int* perm      = cursor + NN;            // EE
    int* dsts      = perm + EE;              // EE
    int* srcs      = dsts + EE;              // EE
    float* evs     = (float*)(srcs + EE);    // 3*EE  (total ~6.4 MB < 16 MB)
    // phase 3 (vah/val_ produced by split4 after edge kernel)
    short* vah   = (short*)(ws + 18 * Q);    // Q18-23 (3S bf16)
    short* val_  = (short*)(ws + 24 * Q);    // Q24-29
    float* vec1  = ws + 30 * Q;              // Q30-41 (fp32 3S, live till e4)
    short* vec2b = (short*)(ws + 42 * Q);    // Q42-47 (bf16 3S)
    float* vdot  = ws + 48 * Q;              // Q48-51 (fp32 S, live till e4)
    short* catb_h = (short*)(ws + 18 * Q);   // Q18-21 (vah dead after vp gemms)
    short* catb_l = (short*)(ws + 22 * Q);   // Q22-25
    short* t2_h  = (short*)(ws + 26 * Q);    // Q26-27
    short* t2_l  = (short*)(ws + 28 * Q);    // Q28-29
    short* xvh_h = (short*)(ws + 18 * Q);    // Q18-23 (catb dead)
    short* xvh_l = (short*)(ws + 42 * Q);    // Q42-47 (vec2 dead)
    // phase 4
    short* vah2  = (short*)(ws + 18 * Q);    // Q18-23
    short* val2  = (short*)(ws + 24 * Q);    // Q24-29
    short* w1b   = (short*)(ws + 30 * Q);    // Q30-35 (bf16 3S)
    short* w2_h  = (short*)(ws + 36 * Q);    // Q36-38
    short* w2_l  = (short*)(ws + 39 * Q);    // Q39-41
    short* cat2_h = (short*)(ws + 42 * Q);   // Q42-45
    short* cat2_l = (short*)(ws + 46 * Q);   // Q46-49
    short* t4_h  = (short*)(ws + 18 * Q);    // Q18-19
    short* t4_l  = (short*)(ws + 20 * Q);    // Q20-21
    float* h1    = ws + 22 * Q;              // Q22-25 (fp32 S)
    float* x3    = ws + 26 * Q;              // Q26-27 (fp32 S/2)
    short* vecC_h = (short*)(ws + 28 * Q);   // Q28-30
    short* vecC_l = (short*)(ws + 31 * Q);   // Q31-33
    // phase 5
    short* w3b   = (short*)(ws + 34 * Q);    // Q34-36
    float* w4    = ws + 37 * Q;              // Q37
    short* cat3_h = (short*)(ws + 38 * Q);   // Q38-39
    short* cat3_l = (short*)(ws + 40 * Q);   // Q40-41
    float* t5    = ws + 42 * Q;              // Q42-43

    // weight hi/lo offsets (shorts)
    short* WT_x1    = wtb;
    short* WT_x2    = wtb + 65536;
    short* WT_vp    = wtb + 262144;
    short* WT_xv1   = wtb + 393216;
    short* WT_xv2   = wtb + 524288;
    short* WT_o1Wv1 = wtb + 720896;
    short* WT_o1Wv2 = wtb + 786432;
    short* WT_o1Wu1 = wtb + 819200;
    short* WT_o1Wu2 = wtb + 950272;
    short* WT_o2Wv1 = wtb + 1015808;
    short* WT_o2Wu1 = wtb + 1032192;
    short* WT_rbf   = wtb + 1064960;         // 768 x 64

    // Phase 0: all weight transposes + splits in one launch (incl. W_rbf^T)
    WtArgs wa;
    const float* wsrc[12] = {W_x1, W_x2, W_vp, W_xv1, W_xv2, o1_Wv1, o1_Wv2,
                             o1_Wu1, o1_Wu2, o2_Wv1, o2_Wu1, W_rbf};
    int wk[12] = {256, 256, 256, 512, 256, 256, 256, 512, 256, 128, 256, 64};
    int wn[12] = {256, 768, 512, 256, 768, 256, 128, 256, 256, 128, 128, 768};
    int off = 0;
    for (int i = 0; i < 12; i++) {
        wa.W[i] = wsrc[i]; wa.K[i] = wk[i]; wa.N[i] = wn[i];
        wa.off[i] = off; off += wk[i] * wn[i];
    }
    wa.off[12] = off;  // 1,114,112
    wt_split_all<<<off / 256, 256, 0, stream>>>(wa, wtb, wtb + WLO);

    // init accumulation targets (x1 = x, vecacc = vec)
    hipMemcpyAsync(x1, x, S * sizeof(float), hipMemcpyDeviceToDevice, stream);
    hipMemcpyAsync(vecacc, vec, 3 * S * sizeof(float), hipMemcpyDeviceToDevice, stream);

    // Phase 1: node MLP
    ln_kernel<<<NN, 256, 0, stream>>>(x, ln_g, ln_b, xln_h, xln_l);
    mfma_gemm<<<dim3(NN / 128, 4), 256, 0, stream>>>(xln_h, xln_l, WT_x1, WT_x1 + WLO,
                                                     b_x1, t1_h, t1_l, NN, 256, 256, 1);
    mfma_gemm<<<dim3(NN / 128, 12), 256, 0, stream>>>(t1_h, t1_l, WT_x2, WT_x2 + WLO,
                                                      b_x2, xh, nullptr, NN, 256, 768, 0);

    // Phase 2: sort edges by dst; edge-parallel fused gather (atomics)
    zero_kernel<<<(NN + 255) / 256, 256, 0, stream>>>(cursor, NN);
    hist_kernel<<<EE / 256, 256, 0, stream>>>(edge_index, cursor);
    scan_kernel<<<1, 256, 0, stream>>>(cursor, rowptr);
    scatter_kernel<<<EE / 256, 256, 0, stream>>>(edge_index, edge_vector, cursor,
                                                 perm, dsts, srcs, evs);
    edge_gather_kernel<<<dim3(EE / 128, 12), 256, 0, stream>>>(
        edge_rbf, WT_rbf, WT_rbf + WLO, b_rbf, xh, vec,
        perm, dsts, srcs, evs, x1, vecacc);
    // hi/lo split of vecacc for the phase-3 GEMMs
    split4_kernel<<<3 * S / 1024, 256, 0, stream>>>(vecacc, vah, val_);

    // Phase 3: vp, vdot/vnorm, xv MLP, in-place updates
    mfma_gemm<<<dim3(3 * NN / 128, 4), 256, 0, stream>>>(vah, val_, WT_vp, WT_vp + WLO,
                                                         nullptr, vec1, nullptr,
                                                         3 * NN, 256, 256, 0);
    mfma_gemm<<<dim3(3 * NN / 128, 4), 256, 0, stream>>>(vah, val_, WT_vp + 65536,
                                                         WT_vp + WLO + 65536,
                                                         nullptr, vec2b, nullptr,
                                                         3 * NN, 256, 256, 2);
    vdot_cat_kernel<<<NN, 256, 0, stream>>>(vec1, vec2b, x1, vdot, catb_h, catb_l);
    mfma_gemm<<<dim3(NN / 128, 4), 256, 0, stream>>>(catb_h, catb_l, WT_xv1, WT_xv1 + WLO,
                                                     b_xv1, t2_h, t2_l, NN, 512, 256, 1);
    mfma_gemm<<<dim3(NN / 128, 12), 256, 0, stream>>>(t2_h, t2_l, WT_xv2, WT_xv2 + WLO,
                                                      b_xv2, xvh_h, xvh_l, NN, 256, 768, 0);
    e4_kernel<<<NN, 256, 0, stream>>>(x1, vecacc, vec1, vdot, xvh_h, xvh_l);

    // Phase 4: gated equivariant block 1
    split4_kernel<<<3 * S / 1024, 256, 0, stream>>>(vecacc, vah2, val2);
    mfma_gemm<<<dim3(3 * NN / 128, 4), 256, 0, stream>>>(vah2, val2, WT_o1Wv1, WT_o1Wv1 + WLO,
                                                         nullptr, w1b, nullptr,
                                                         3 * NN, 256, 256, 2);
    mfma_gemm<<<dim3(3 * NN / 128, 2), 256, 0, stream>>>(vah2, val2, WT_o1Wv2, WT_o1Wv2 + WLO,
                                                         nullptr, w2_h, w2_l,
                                                         3 * NN, 256, 128, 0);
    normcat_kernel<<<NN * 512 / 256, 256, 0, stream>>>(x1, w1b, cat2_h, cat2_l, 256, 256, 9);
    mfma_gemm<<<dim3(NN / 128, 4), 256, 0, stream>>>(cat2_h, cat2_l, WT_o1Wu1, WT_o1Wu1 + WLO,
                                                     o1_bu1, t4_h, t4_l, NN, 512, 256, 1);
    mfma_gemm<<<dim3(NN / 128, 4), 256, 0, stream>>>(t4_h, t4_l, WT_o1Wu2, WT_o1Wu2 + WLO,
                                                     o1_bu2, h1, nullptr, NN, 256, 256, 0);
    gate1_kernel<<<NN * 128 / 256, 256, 0, stream>>>(h1, w2_h, w2_l, x3, vecC_h, vecC_l);

    // Phase 5: gated equivariant block 2 + output
    mfma_gemm<<<dim3(3 * NN / 128, 2), 256, 0, stream>>>(vecC_h, vecC_l, WT_o2Wv1,
                                                         WT_o2Wv1 + WLO, nullptr,
                                                         w3b, nullptr, 3 * NN, 128, 128, 2);
    g12_kernel<<<3 * NN / 4, 256, 0, stream>>>(vecC_h, vecC_l, o2_Wv2, w4);
    normcat_kernel<<<NN * 256 / 256, 256, 0, stream>>>(x3, w3b, cat3_h, cat3_l, 128, 128, 8);
    mfma_gemm<<<dim3(NN / 128, 2), 256, 0, stream>>>(cat3_h, cat3_l, WT_o2Wu1, WT_o2Wu1 + WLO,
                                                     o2_bu1, t5, nullptr, NN, 256, 128, 1);
    final_kernel<<<NN / 4, 256, 0, stream>>>(t5, o2_Wu2, o2_bu2, w4, out);
}

// Round 4
// 1603.084 us; speedup vs baseline: 1.6484x; 1.0535x over previous
//
#include <hip/hip_runtime.h>
#include <math.h>

#define NN 16384
#define EE 262144
#define HH 256

#define INV_SQRT_3f 0.57735026918962576f
#define INV_SQRT_Hf 0.0625f
#define INV_SQRT_2f 0.70710678118654752f
#define SSILU_SCALE 1.6666666666666667f

typedef __attribute__((ext_vector_type(8))) short bf16x8;
typedef __attribute__((ext_vector_type(4))) float f32x4;

__device__ __forceinline__ float ssilu_f(float v) {
    return v * (1.0f / (1.0f + __expf(-v))) * SSILU_SCALE;
}
__device__ __forceinline__ float b2f(short s) {
    unsigned int u = ((unsigned int)(unsigned short)s) << 16;
    return __uint_as_float(u);
}
__device__ __forceinline__ short f2b(float f) {
    unsigned int u = __float_as_uint(f);
    unsigned int r = (u + 0x7fff + ((u >> 16) & 1)) >> 16;
    return (short)r;
}

// ---------------- LayerNorm: one block per row, split-bf16 out ----------------
__global__ void __launch_bounds__(256) ln_kernel(const float* __restrict__ x,
                                                 const float* __restrict__ g,
                                                 const float* __restrict__ b,
                                                 short* __restrict__ oh,
                                                 short* __restrict__ ol) {
    int n = blockIdx.x;
    int t = threadIdx.x;
    float v = x[(long)n * HH + t];
    float s = v, s2 = v * v;
    #pragma unroll
    for (int off = 32; off > 0; off >>= 1) {
        s  += __shfl_down(s, off);
        s2 += __shfl_down(s2, off);
    }
    __shared__ float red[8];
    int wave = t >> 6, lane = t & 63;
    if (lane == 0) { red[wave] = s; red[4 + wave] = s2; }
    __syncthreads();
    __shared__ float mr[2];
    if (t == 0) {
        float ts = red[0] + red[1] + red[2] + red[3];
        float ts2 = red[4] + red[5] + red[6] + red[7];
        float mean = ts * (1.0f / HH);
        float var = ts2 * (1.0f / HH) - mean * mean;
        mr[0] = mean;
        mr[1] = rsqrtf(var + 1e-5f);
    }
    __syncthreads();
    float o = (v - mr[0]) * mr[1] * g[t] + b[t];
    short hh = f2b(o);
    oh[(long)n * HH + t] = hh;
    ol[(long)n * HH + t] = f2b(o - b2f(hh));
}

// ---- ALL weight transposes + hi/lo splits in ONE kernel (incl. W_rbf) ----
struct WtArgs {
    const float* W[12];
    int K[12];
    int N[12];
    int off[13];   // cumulative element offsets; off[12] = total
};

__global__ void __launch_bounds__(256) wt_split_all(WtArgs a,
                                                    short* __restrict__ WTh,
                                                    short* __restrict__ WTl) {
    int idx = blockIdx.x * 256 + threadIdx.x;
    int s = 0;
    #pragma unroll
    for (int i = 1; i < 12; i++) s += (idx >= a.off[i]) ? 1 : 0;
    int local = idx - a.off[s];
    int K = a.K[s], N = a.N[s];
    int k = local / N, n = local - k * N;
    float w = a.W[s][local];
    short hh = f2b(w);
    long o = (long)a.off[s] + (long)n * K + k;
    WTh[o] = hh;
    WTl[o] = f2b(w - b2f(hh));
}

// ---- fp32 -> hi/lo split (count % 1024 == 0) ----
__global__ void __launch_bounds__(256) split4_kernel(const float* __restrict__ in,
                                                     short* __restrict__ h,
                                                     short* __restrict__ l) {
    long i = ((long)blockIdx.x * 256 + threadIdx.x) * 4;
    float4 v = *(const float4*)(in + i);
    short4 oh, ol;
    oh.x = f2b(v.x); ol.x = f2b(v.x - b2f(oh.x));
    oh.y = f2b(v.y); ol.y = f2b(v.y - b2f(oh.y));
    oh.z = f2b(v.z); ol.z = f2b(v.z - b2f(oh.z));
    oh.w = f2b(v.w); ol.w = f2b(v.w - b2f(oh.w));
    *(short4*)(h + i) = oh;
    *(short4*)(l + i) = ol;
}

// ---- split-bf16 MFMA GEMM v2: C = (Ah+Al)(M,K) @ (Wh+Wl)^T(N,K) [+bias][ssilu]
__global__ void __launch_bounds__(256) mfma_gemm(const short* __restrict__ Ah,
                                                 const short* __restrict__ Al,
                                                 const short* __restrict__ Wh,
                                                 const short* __restrict__ Wl,
                                                 const float* __restrict__ bias,
                                                 void* __restrict__ Ch,
                                                 short* __restrict__ Cl,
                                                 int M, int K, int N, int act) {
    int tid = threadIdx.x;
    int wave = tid >> 6, lane = tid & 63;
    int quad = lane >> 4, l16 = lane & 15;
    long bm = (long)blockIdx.x * 128 + wave * 32;
    long bn = (long)blockIdx.y * 64;
    long a0 = (bm + l16) * K + quad * 8;
    long a1 = a0 + (long)16 * K;
    long w0 = (bn + l16) * K + quad * 8;

    f32x4 acc[2][4];
    #pragma unroll
    for (int f = 0; f < 2; f++)
        #pragma unroll
        for (int t = 0; t < 4; t++) acc[f][t] = (f32x4){0.f, 0.f, 0.f, 0.f};

    bf16x8 cah[2], cal[2], cbh[4], cbl[4];
    cah[0] = *(const bf16x8*)(Ah + a0);
    cah[1] = *(const bf16x8*)(Ah + a1);
    cal[0] = *(const bf16x8*)(Al + a0);
    cal[1] = *(const bf16x8*)(Al + a1);
    #pragma unroll
    for (int t = 0; t < 4; t++) {
        long wo = w0 + (long)t * 16 * K;
        cbh[t] = *(const bf16x8*)(Wh + wo);
        cbl[t] = *(const bf16x8*)(Wl + wo);
    }

    for (int k0 = 0; k0 < K; k0 += 32) {
        int k1 = k0 + 32;
        bf16x8 nah[2], nal[2], nbh[4], nbl[4];
        if (k1 < K) {
            nah[0] = *(const bf16x8*)(Ah + a0 + k1);
            nah[1] = *(const bf16x8*)(Ah + a1 + k1);
            nal[0] = *(const bf16x8*)(Al + a0 + k1);
            nal[1] = *(const bf16x8*)(Al + a1 + k1);
            #pragma unroll
            for (int t = 0; t < 4; t++) {
                long wo = w0 + (long)t * 16 * K + k1;
                nbh[t] = *(const bf16x8*)(Wh + wo);
                nbl[t] = *(const bf16x8*)(Wl + wo);
            }
        }
        #pragma unroll
        for (int t = 0; t < 4; t++) {
            #pragma unroll
            for (int f = 0; f < 2; f++) {
                acc[f][t] = __builtin_amdgcn_mfma_f32_16x16x32_bf16(cah[f], cbh[t], acc[f][t], 0, 0, 0);
                acc[f][t] = __builtin_amdgcn_mfma_f32_16x16x32_bf16(cal[f], cbh[t], acc[f][t], 0, 0, 0);
                acc[f][t] = __builtin_amdgcn_mfma_f32_16x16x32_bf16(cah[f], cbl[t], acc[f][t], 0, 0, 0);
            }
        }
        if (k1 < K) {
            cah[0] = nah[0]; cah[1] = nah[1];
            cal[0] = nal[0]; cal[1] = nal[1];
            #pragma unroll
            for (int t = 0; t < 4; t++) { cbh[t] = nbh[t]; cbl[t] = nbl[t]; }
        }
    }

    #pragma unroll
    for (int f = 0; f < 2; f++) {
        long row0 = bm + f * 16 + quad * 4;
        #pragma unroll
        for (int t = 0; t < 4; t++) {
            long col = bn + t * 16 + l16;
            float bv = bias ? bias[col] : 0.f;
            #pragma unroll
            for (int r = 0; r < 4; r++) {
                float v = acc[f][t][r] + bv;
                if (act & 1) v = ssilu_f(v);
                long idx = (row0 + r) * N + col;
                if (Cl) {
                    short hh = f2b(v);
                    ((short*)Ch)[idx] = hh;
                    Cl[idx] = f2b(v - b2f(hh));
                } else if (act & 2) {
                    ((short*)Ch)[idx] = f2b(v);
                } else {
                    ((float*)Ch)[idx] = v;
                }
            }
        }
    }
}

// ---------------- edge sort (counting sort by dst) ----------------
__global__ void __launch_bounds__(256) zero_kernel(int* __restrict__ p, int n) {
    int i = blockIdx.x * 256 + threadIdx.x;
    if (i < n) p[i] = 0;
}

__global__ void __launch_bounds__(256) hist_kernel(const int* __restrict__ eidx,
                                                   int* __restrict__ cnt) {
    int e = blockIdx.x * 256 + threadIdx.x;
    atomicAdd(&cnt[eidx[EE + e]], 1);
}

__global__ void __launch_bounds__(256) scan_kernel(int* __restrict__ cursor,
                                                   int* __restrict__ rowptr) {
    int t = threadIdx.x;
    int base_i = t * 64;
    int tsum = 0;
    for (int i = 0; i < 64; i++) tsum += cursor[base_i + i];
    __shared__ int ls[256];
    ls[t] = tsum;
    __syncthreads();
    for (int off = 1; off < 256; off <<= 1) {
        int v = (t >= off) ? ls[t - off] : 0;
        __syncthreads();
        ls[t] += v;
        __syncthreads();
    }
    int running = ls[t] - tsum;
    for (int i = 0; i < 64; i++) {
        int c = cursor[base_i + i];
        rowptr[base_i + i] = running;
        cursor[base_i + i] = running;
        running += c;
    }
    if (t == 255) rowptr[NN] = running;
}

// scatter: also materialize dst/src/ev in sorted order for the edge kernel
__global__ void __launch_bounds__(256) scatter_kernel(const int* __restrict__ eidx,
                                                      const float* __restrict__ ev,
                                                      int* __restrict__ cursor,
                                                      int* __restrict__ perm,
                                                      int* __restrict__ dsts,
                                                      int* __restrict__ srcs,
                                                      float* __restrict__ evs) {
    int e = blockIdx.x * 256 + threadIdx.x;
    int s_ = eidx[e];
    int d_ = eidx[EE + e];
    int pos = atomicAdd(&cursor[d_], 1);
    perm[pos] = e;
    dsts[pos] = d_;
    srcs[pos] = s_;
    evs[pos * 3 + 0] = ev[e * 3 + 0];
    evs[pos * 3 + 1] = ev[e * 3 + 1];
    evs[pos * 3 + 2] = ev[e * 3 + 2];
}

// ---------------- Edge-parallel fused rbf-GEMM + gather + atomic reduce -------
// v2: grid = EE/128 blocks; each block owns 128 dst-sorted edges and loops the
// 12 col-tiles (3 sections x 4 tiles) INTERNALLY. A-fragments (rbf hi/lo) are
// loaded ONCE into registers and reused across all 12 MFMA rounds — this cuts
// the 12x redundant rbf HBM re-fetch that dominated FETCH_SIZE in v1.
// Per round: MFMA -> mlds (reused) -> barrier -> run-accumulate consume with
// atomicAdd into x1/vecacc (pre-initialized with x/vec) -> barrier.
__global__ void __launch_bounds__(256) edge_gather_kernel(
        const float* __restrict__ rbf,
        const short* __restrict__ Wrh,
        const short* __restrict__ Wrl,
        const float* __restrict__ b_rbf,
        const float* __restrict__ xh,
        const float* __restrict__ vec,
        const int* __restrict__ perm,
        const int* __restrict__ dsts,
        const int* __restrict__ srcs,
        const float* __restrict__ evs,
        float* __restrict__ x1,
        float* __restrict__ vecacc) {
    int tid = threadIdx.x;
    int wave = tid >> 6, lane = tid & 63;
    int quad = lane >> 4, l16 = lane & 15;
    int bm = blockIdx.x * 128;

    __shared__ __align__(16) float mlds[128][66];
    __shared__ int dst_s[128], src_s[128];
    __shared__ float ev_s[128][3];

    // stage dst/src/ev once
    if (tid < 128) {
        dst_s[tid] = dsts[bm + tid];
        src_s[tid] = srcs[bm + tid];
    } else {
        int i = tid - 128;
        ev_s[i][0] = evs[(long)(bm + i) * 3 + 0];
        ev_s[i][1] = evs[(long)(bm + i) * 3 + 1];
        ev_s[i][2] = evs[(long)(bm + i) * 3 + 2];
    }

    // ---- A fragments ONCE: rbf rows via perm, fp32 -> split hi/lo in regs ----
    int r0 = bm + wave * 32 + l16;
    int e0 = perm[r0];
    int e1 = perm[r0 + 16];
    bf16x8 afh[2][2], afl[2][2];     // [f][ks] — 64 VGPRs, pinned for the kernel
    #pragma unroll
    for (int f = 0; f < 2; f++) {
        long ebase = (long)(f == 0 ? e0 : e1) * 64 + quad * 8;
        #pragma unroll
        for (int ks = 0; ks < 2; ks++) {
            float4 ua = *(const float4*)(rbf + ebase + ks * 32);
            float4 ub = *(const float4*)(rbf + ebase + ks * 32 + 4);
            float vv[8] = {ua.x, ua.y, ua.z, ua.w, ub.x, ub.y, ub.z, ub.w};
            bf16x8 hh, ll;
            #pragma unroll
            for (int j = 0; j < 8; j++) {
                short hb = f2b(vv[j]);
                hh[j] = hb;
                ll[j] = f2b(vv[j] - b2f(hb));
            }
            afh[f][ks] = hh;
            afl[f][ks] = ll;
        }
    }

    int base = wave * 32;

    for (int sec = 0; sec < 3; sec++) {
        for (int tile = 0; tile < 4; tile++) {
            int bn = sec * 256 + tile * 64;
            // ---- MFMA round: m[:, bn..bn+63] ----
            f32x4 acc[2][4];
            #pragma unroll
            for (int t = 0; t < 4; t++) {
                float bv = b_rbf[bn + t * 16 + l16];
                acc[0][t] = (f32x4){bv, bv, bv, bv};
                acc[1][t] = (f32x4){bv, bv, bv, bv};
            }
            #pragma unroll
            for (int t = 0; t < 4; t++) {
                #pragma unroll
                for (int ks = 0; ks < 2; ks++) {
                    long wo = (long)(bn + t * 16 + l16) * 64 + ks * 32 + quad * 8;
                    bf16x8 bh = *(const bf16x8*)(Wrh + wo);
                    bf16x8 bl = *(const bf16x8*)(Wrl + wo);
                    #pragma unroll
                    for (int f = 0; f < 2; f++) {
                        acc[f][t] = __builtin_amdgcn_mfma_f32_16x16x32_bf16(afh[f][ks], bh, acc[f][t], 0, 0, 0);
                        acc[f][t] = __builtin_amdgcn_mfma_f32_16x16x32_bf16(afl[f][ks], bh, acc[f][t], 0, 0, 0);
                        acc[f][t] = __builtin_amdgcn_mfma_f32_16x16x32_bf16(afh[f][ks], bl, acc[f][t], 0, 0, 0);
                    }
                }
            }
            __syncthreads();   // previous round's mlds reads complete
            #pragma unroll
            for (int f = 0; f < 2; f++)
                #pragma unroll
                for (int t = 0; t < 4; t++)
                    #pragma unroll
                    for (int r = 0; r < 4; r++)
                        mlds[base + f * 16 + quad * 4 + r][t * 16 + l16] = acc[f][t][r];
            __syncthreads();   // also covers dst_s/src_s/ev_s staging (round 0)

            // ---- consume: wave owns its 32 rows; lane owns one column ----
            int colx = tile * 64 + lane;          // 0..255 within section
            if (sec == 0) {
                float a = 0.f;
                int dprev = dst_s[base];
                #pragma unroll 4
                for (int i = 0; i < 32; i++) {
                    int d = dst_s[base + i];
                    if (d != dprev) {
                        atomicAdd(&x1[(long)dprev * 256 + colx], a);
                        a = 0.f;
                        dprev = d;
                    }
                    long xb = (long)src_s[base + i] * 768;
                    a += mlds[base + i][lane] * xh[xb + colx];
                }
                atomicAdd(&x1[(long)dprev * 256 + colx], a);
            } else if (sec == 1) {
                float a0 = 0.f, a1 = 0.f, a2 = 0.f;
                int dprev = dst_s[base];
                #pragma unroll 4
                for (int i = 0; i < 32; i++) {
                    int d = dst_s[base + i];
                    if (d != dprev) {
                        long vb = (long)dprev * 768 + colx;
                        atomicAdd(&vecacc[vb], a0);
                        atomicAdd(&vecacc[vb + 256], a1);
                        atomicAdd(&vecacc[vb + 512], a2);
                        a0 = a1 = a2 = 0.f;
                        dprev = d;
                    }
                    long xb = (long)src_s[base + i] * 768;
                    float m2 = mlds[base + i][lane] * (INV_SQRT_3f * INV_SQRT_Hf) *
                               xh[xb + 256 + colx];
                    a0 += vec[xb + colx] * m2;
                    a1 += vec[xb + 256 + colx] * m2;
                    a2 += vec[xb + 512 + colx] * m2;
                }
                long vb = (long)dprev * 768 + colx;
                atomicAdd(&vecacc[vb], a0);
                atomicAdd(&vecacc[vb + 256], a1);
                atomicAdd(&vecacc[vb + 512], a2);
            } else {
                float a0 = 0.f, a1 = 0.f, a2 = 0.f;
                int dprev = dst_s[base];
                #pragma unroll 4
                for (int i = 0; i < 32; i++) {
                    int d = dst_s[base + i];
                    if (d != dprev) {
                        long vb = (long)dprev * 768 + colx;
                        atomicAdd(&vecacc[vb], a0);
                        atomicAdd(&vecacc[vb + 256], a1);
                        atomicAdd(&vecacc[vb + 512], a2);
                        a0 = a1 = a2 = 0.f;
                        dprev = d;
                    }
                    long xb = (long)src_s[base + i] * 768;
                    float m3 = mlds[base + i][lane] * INV_SQRT_Hf * xh[xb + 512 + colx];
                    a0 += m3 * ev_s[base + i][0];
                    a1 += m3 * ev_s[base + i][1];
                    a2 += m3 * ev_s[base + i][2];
                }
                long vb = (long)dprev * 768 + colx;
                atomicAdd(&vecacc[vb], a0);
                atomicAdd(&vecacc[vb + 256], a1);
                atomicAdd(&vecacc[vb + 512], a2);
            }
        }
    }
}

// ---------------- vec_dot + vnorm + cat(x, vnorm), split out ----------------
__global__ void __launch_bounds__(256) vdot_cat_kernel(const float* __restrict__ vec1,
                                                       const short* __restrict__ vec2,
                                                       const float* __restrict__ x1,
                                                       float* __restrict__ vdot,
                                                       short* __restrict__ cath,
                                                       short* __restrict__ catl) {
    int idx = blockIdx.x * 256 + threadIdx.x;
    int n = idx >> 8, h = idx & 255;
    float dsum = 0.f, s2 = 0.f;
    #pragma unroll
    for (int d = 0; d < 3; d++) {
        long r = (long)(n * 3 + d) * 256 + h;
        float a = vec1[r];
        float b = b2f(vec2[r]);
        dsum += a * b;
        s2 += b * b;
    }
    vdot[idx] = dsum * INV_SQRT_Hf;
    float xv = x1[idx];
    short hh = f2b(xv);
    cath[(long)n * 512 + h] = hh;
    catl[(long)n * 512 + h] = f2b(xv - b2f(hh));
    float vn = sqrtf(s2 + 1e-8f);
    short vh = f2b(vn);
    cath[(long)n * 512 + 256 + h] = vh;
    catl[(long)n * 512 + 256 + h] = f2b(vn - b2f(vh));
}

// ---------------- x/vec update after xv MLP (IN-PLACE) ----------------
__global__ void __launch_bounds__(256) e4_kernel(float* __restrict__ x1,
                                                 float* __restrict__ vecacc,
                                                 const float* __restrict__ vec1,
                                                 const float* __restrict__ vdot,
                                                 const short* __restrict__ xvh_h,
                                                 const short* __restrict__ xvh_l) {
    int idx = blockIdx.x * 256 + threadIdx.x;
    int n = idx >> 8, h = idx & 255;
    long b0 = (long)n * 768 + h;
    float xv1 = b2f(xvh_h[b0])       + b2f(xvh_l[b0]);
    float xv2 = b2f(xvh_h[b0 + 256]) + b2f(xvh_l[b0 + 256]);
    float xv3 = b2f(xvh_h[b0 + 512]) + b2f(xvh_l[b0 + 512]);
    x1[idx] = x1[idx] + (xv1 + xv2 * vdot[idx]) * INV_SQRT_2f;
    #pragma unroll
    for (int d = 0; d < 3; d++) {
        long r = (long)(n * 3 + d) * 256 + h;
        vecacc[r] = vecacc[r] + xv3 * vec1[r];
    }
}

// ---------------- norm over d + concat(x fp32, norm), split out ----------------
__global__ void __launch_bounds__(256) normcat_kernel(const float* __restrict__ xin,
                                                      const short* __restrict__ w,
                                                      short* __restrict__ cath,
                                                      short* __restrict__ catl,
                                                      int Cx, int C, int shift) {
    int idx = blockIdx.x * 256 + threadIdx.x;
    int cols = 1 << shift;
    int n = idx >> shift, c = idx & (cols - 1);
    float v;
    if (c < Cx) {
        v = xin[(long)n * Cx + c];
    } else {
        int cc = c - Cx;
        float s = 0.f;
        #pragma unroll
        for (int d = 0; d < 3; d++) {
            float a = b2f(w[(long)(n * 3 + d) * C + cc]);
            s += a * a;
        }
        v = sqrtf(s);
    }
    short hh = f2b(v);
    cath[idx] = hh;
    catl[idx] = f2b(v - b2f(hh));
}

// ---------------- gated block 1 epilogue ----------------
__global__ void __launch_bounds__(256) gate1_kernel(const float* __restrict__ h1,
                                                    const short* __restrict__ w2h,
                                                    const short* __restrict__ w2l,
                                                    float* __restrict__ x3,
                                                    short* __restrict__ vecCh,
                                                    short* __restrict__ vecCl) {
    int idx = blockIdx.x * 256 + threadIdx.x;
    int n = idx >> 7, c = idx & 127;
    x3[idx] = ssilu_f(h1[(long)n * 256 + c]);
    float vn = h1[(long)n * 256 + 128 + c];
    #pragma unroll
    for (int d = 0; d < 3; d++) {
        long r = (long)(n * 3 + d) * 128 + c;
        float wv = b2f(w2h[r]) + b2f(w2l[r]);
        float v = vn * wv;
        short hh = f2b(v);
        vecCh[r] = hh;
        vecCl[r] = f2b(v - b2f(hh));
    }
}

// ---------------- vecC @ o2_Wv2 (K=128, Nc=1): one wave per row ----------------
__global__ void __launch_bounds__(256) g12_kernel(const short* __restrict__ vecCh,
                                                  const short* __restrict__ vecCl,
                                                  const float* __restrict__ Wv2,
                                                  float* __restrict__ w4) {
    int row = blockIdx.x * 4 + (threadIdx.x >> 6);
    int lane = threadIdx.x & 63;
    long r0 = (long)row * 128 + lane;
    float v0 = b2f(vecCh[r0]) + b2f(vecCl[r0]);
    float v1 = b2f(vecCh[r0 + 64]) + b2f(vecCl[r0 + 64]);
    float s = v0 * Wv2[lane] + v1 * Wv2[64 + lane];
    #pragma unroll
    for (int off = 32; off > 0; off >>= 1) s += __shfl_down(s, off);
    if (lane == 0) w4[row] = s;
}

// ---------------- final: out[n,d] = (t5[n,:]@Wu2[:,1] + b2[1]) * w4[n,d] ----------
__global__ void __launch_bounds__(256) final_kernel(const float* __restrict__ t5,
                                                    const float* __restrict__ Wu2,
                                                    const float* __restrict__ bu2,
                                                    const float* __restrict__ w4,
                                                    float* __restrict__ out) {
    int n = blockIdx.x * 4 + (threadIdx.x >> 6);
    int lane = threadIdx.x & 63;
    float s = t5[(long)n * 128 + lane] * Wu2[lane * 2 + 1] +
              t5[(long)n * 128 + 64 + lane] * Wu2[(64 + lane) * 2 + 1];
    #pragma unroll
    for (int off = 32; off > 0; off >>= 1) s += __shfl_down(s, off);
    float val = __shfl(s, 0) + bu2[1];
    if (lane < 3) out[(long)n * 3 + lane] = val * w4[(long)n * 3 + lane];
}

extern "C" void kernel_launch(void* const* d_in, const int* in_sizes, int n_in,
                              void* d_out, int out_size, void* d_ws, size_t ws_size,
                              hipStream_t stream) {
    const float* x          = (const float*)d_in[0];
    const float* vec        = (const float*)d_in[1];
    const float* edge_rbf   = (const float*)d_in[2];
    const float* edge_vector= (const float*)d_in[3];
    const float* ln_g       = (const float*)d_in[4];
    const float* ln_b       = (const float*)d_in[5];
    const float* W_x1       = (const float*)d_in[6];
    const float* b_x1       = (const float*)d_in[7];
    const float* W_x2       = (const float*)d_in[8];
    const float* b_x2       = (const float*)d_in[9];
    const float* W_rbf      = (const float*)d_in[10];
    const float* b_rbf      = (const float*)d_in[11];
    const float* W_vp       = (const float*)d_in[12];
    const float* W_xv1      = (const float*)d_in[13];
    const float* b_xv1      = (const float*)d_in[14];
    const float* W_xv2      = (const float*)d_in[15];
    const float* b_xv2      = (const float*)d_in[16];
    const float* o1_Wv1     = (const float*)d_in[17];
    const float* o1_Wv2     = (const float*)d_in[18];
    const float* o1_Wu1     = (const float*)d_in[19];
    const float* o1_bu1     = (const float*)d_in[20];
    const float* o1_Wu2     = (const float*)d_in[21];
    const float* o1_bu2     = (const float*)d_in[22];
    const float* o2_Wv1     = (const float*)d_in[23];
    const float* o2_Wv2     = (const float*)d_in[24];
    const float* o2_Wu1     = (const float*)d_in[25];
    const float* o2_bu1     = (const float*)d_in[26];
    const float* o2_Wu2     = (const float*)d_in[27];
    const float* o2_bu2     = (const float*)d_in[28];
    const int*   edge_index = (const int*)d_in[29];
    float* out = (float*)d_out;
    float* ws  = (float*)d_ws;

    const size_t S = (size_t)NN * 256;
    const size_t Q = S / 4;              // 1,048,576 floats = 4 MiB
    // ---- arena in units of Q; peak 52Q = 208 MiB (proven safe) ----
    float* x1      = ws;                     // Q0-3   (fp32 S)
    float* vecacc  = ws + 4 * Q;             // Q4-15  (fp32 3S)
    short* wtb     = (short*)(ws + 16 * Q);  // Q16-17 weights hi + lo
    const long WLO = 1114112;
    // phase 1
    short* xln_h = (short*)(ws + 18 * Q);    // Q18-19 (dead after t1 gemm)
    short* xln_l = (short*)(ws + 20 * Q);    // Q20-21
    short* t1_h  = (short*)(ws + 22 * Q);    // Q22-23 (dead after xh gemm)
    short* t1_l  = (short*)(ws + 24 * Q);    // Q24-25
    float* xh    = ws + 30 * Q;              // Q30-41 (fp32 3S, dead after gather)
    // phase 2 sort scratch (dead before vdot is written)
    int* rowptr    = (int*)(ws + 48 * Q);    // NN+1
    int* cursor    = rowptr + (NN + 1);      // NN
    int* perm      = cursor + NN;            // EE
    int* dsts      = perm + EE;              // EE
    int* srcs      = dsts + EE;              // EE
    float* evs     = (float*)(srcs + EE);    // 3*EE  (total ~6.4 MB < 16 MB)
    // phase 3 (vah/val_ produced by split4 after edge kernel)
    short* vah   = (short*)(ws + 18 * Q);    // Q18-23 (3S bf16)
    short* val_  = (short*)(ws + 24 * Q);    // Q24-29
    float* vec1  = ws + 30 * Q;              // Q30-41 (fp32 3S, live till e4)
    short* vec2b = (short*)(ws + 42 * Q);    // Q42-47 (bf16 3S)
    float* vdot  = ws + 48 * Q;              // Q48-51 (fp32 S, live till e4)
    short* catb_h = (short*)(ws + 18 * Q);   // Q18-21 (vah dead after vp gemms)
    short* catb_l = (short*)(ws + 22 * Q);   // Q22-25
    short* t2_h  = (short*)(ws + 26 * Q);    // Q26-27
    short* t2_l  = (short*)(ws + 28 * Q);    // Q28-29
    short* xvh_h = (short*)(ws + 18 * Q);    // Q18-23 (catb dead)
    short* xvh_l = (short*)(ws + 42 * Q);    // Q42-47 (vec2 dead)
    // phase 4
    short* vah2  = (short*)(ws + 18 * Q);    // Q18-23
    short* val2  = (short*)(ws + 24 * Q);    // Q24-29
    short* w1b   = (short*)(ws + 30 * Q);    // Q30-35 (bf16 3S)
    short* w2_h  = (short*)(ws + 36 * Q);    // Q36-38
    short* w2_l  = (short*)(ws + 39 * Q);    // Q39-41
    short* cat2_h = (short*)(ws + 42 * Q);   // Q42-45
    short* cat2_l = (short*)(ws + 46 * Q);   // Q46-49
    short* t4_h  = (short*)(ws + 18 * Q);    // Q18-19
    short* t4_l  = (short*)(ws + 20 * Q);    // Q20-21
    float* h1    = ws + 22 * Q;              // Q22-25 (fp32 S)
    float* x3    = ws + 26 * Q;              // Q26-27 (fp32 S/2)
    short* vecC_h = (short*)(ws + 28 * Q);   // Q28-30
    short* vecC_l = (short*)(ws + 31 * Q);   // Q31-33
    // phase 5
    short* w3b   = (short*)(ws + 34 * Q);    // Q34-36
    float* w4    = ws + 37 * Q;              // Q37
    short* cat3_h = (short*)(ws + 38 * Q);   // Q38-39
    short* cat3_l = (short*)(ws + 40 * Q);   // Q40-41
    float* t5    = ws + 42 * Q;              // Q42-43

    // weight hi/lo offsets (shorts)
    short* WT_x1    = wtb;
    short* WT_x2    = wtb + 65536;
    short* WT_vp    = wtb + 262144;
    short* WT_xv1   = wtb + 393216;
    short* WT_xv2   = wtb + 524288;
    short* WT_o1Wv1 = wtb + 720896;
    short* WT_o1Wv2 = wtb + 786432;
    short* WT_o1Wu1 = wtb + 819200;
    short* WT_o1Wu2 = wtb + 950272;
    short* WT_o2Wv1 = wtb + 1015808;
    short* WT_o2Wu1 = wtb + 1032192;
    short* WT_rbf   = wtb + 1064960;         // 768 x 64

    // Phase 0: all weight transposes + splits in one launch (incl. W_rbf^T)
    WtArgs wa;
    const float* wsrc[12] = {W_x1, W_x2, W_vp, W_xv1, W_xv2, o1_Wv1, o1_Wv2,
                             o1_Wu1, o1_Wu2, o2_Wv1, o2_Wu1, W_rbf};
    int wk[12] = {256, 256, 256, 512, 256, 256, 256, 512, 256, 128, 256, 64};
    int wn[12] = {256, 768, 512, 256, 768, 256, 128, 256, 256, 128, 128, 768};
    int off = 0;
    for (int i = 0; i < 12; i++) {
        wa.W[i] = wsrc[i]; wa.K[i] = wk[i]; wa.N[i] = wn[i];
        wa.off[i] = off; off += wk[i] * wn[i];
    }
    wa.off[12] = off;  // 1,114,112
    wt_split_all<<<off / 256, 256, 0, stream>>>(wa, wtb, wtb + WLO);

    // init accumulation targets (x1 = x, vecacc = vec)
    hipMemcpyAsync(x1, x, S * sizeof(float), hipMemcpyDeviceToDevice, stream);
    hipMemcpyAsync(vecacc, vec, 3 * S * sizeof(float), hipMemcpyDeviceToDevice, stream);

    // Phase 1: node MLP
    ln_kernel<<<NN, 256, 0, stream>>>(x, ln_g, ln_b, xln_h, xln_l);
    mfma_gemm<<<dim3(NN / 128, 4), 256, 0, stream>>>(xln_h, xln_l, WT_x1, WT_x1 + WLO,
                                                     b_x1, t1_h, t1_l, NN, 256, 256, 1);
    mfma_gemm<<<dim3(NN / 128, 12), 256, 0, stream>>>(t1_h, t1_l, WT_x2, WT_x2 + WLO,
                                                      b_x2, xh, nullptr, NN, 256, 768, 0);

    // Phase 2: sort edges by dst; edge-parallel fused gather (atomics)
    zero_kernel<<<(NN + 255) / 256, 256, 0, stream>>>(cursor, NN);
    hist_kernel<<<EE / 256, 256, 0, stream>>>(edge_index, cursor);
    scan_kernel<<<1, 256, 0, stream>>>(cursor, rowptr);
    scatter_kernel<<<EE / 256, 256, 0, stream>>>(edge_index, edge_vector, cursor,
                                                 perm, dsts, srcs, evs);
    edge_gather_kernel<<<EE / 128, 256, 0, stream>>>(
        edge_rbf, WT_rbf, WT_rbf + WLO, b_rbf, xh, vec,
        perm, dsts, srcs, evs, x1, vecacc);
    // hi/lo split of vecacc for the phase-3 GEMMs
    split4_kernel<<<3 * S / 1024, 256, 0, stream>>>(vecacc, vah, val_);

    // Phase 3: vp, vdot/vnorm, xv MLP, in-place updates
    mfma_gemm<<<dim3(3 * NN / 128, 4), 256, 0, stream>>>(vah, val_, WT_vp, WT_vp + WLO,
                                                         nullptr, vec1, nullptr,
                                                         3 * NN, 256, 256, 0);
    mfma_gemm<<<dim3(3 * NN / 128, 4), 256, 0, stream>>>(vah, val_, WT_vp + 65536,
                                                         WT_vp + WLO + 65536,
                                                         nullptr, vec2b, nullptr,
                                                         3 * NN, 256, 256, 2);
    vdot_cat_kernel<<<NN, 256, 0, stream>>>(vec1, vec2b, x1, vdot, catb_h, catb_l);
    mfma_gemm<<<dim3(NN / 128, 4), 256, 0, stream>>>(catb_h, catb_l, WT_xv1, WT_xv1 + WLO,
                                                     b_xv1, t2_h, t2_l, NN, 512, 256, 1);
    mfma_gemm<<<dim3(NN / 128, 12), 256, 0, stream>>>(t2_h, t2_l, WT_xv2, WT_xv2 + WLO,
                                                      b_xv2, xvh_h, xvh_l, NN, 256, 768, 0);
    e4_kernel<<<NN, 256, 0, stream>>>(x1, vecacc, vec1, vdot, xvh_h, xvh_l);

    // Phase 4: gated equivariant block 1
    split4_kernel<<<3 * S / 1024, 256, 0, stream>>>(vecacc, vah2, val2);
    mfma_gemm<<<dim3(3 * NN / 128, 4), 256, 0, stream>>>(vah2, val2, WT_o1Wv1, WT_o1Wv1 + WLO,
                                                         nullptr, w1b, nullptr,
                                                         3 * NN, 256, 256, 2);
    mfma_gemm<<<dim3(3 * NN / 128, 2), 256, 0, stream>>>(vah2, val2, WT_o1Wv2, WT_o1Wv2 + WLO,
                                                         nullptr, w2_h, w2_l,
                                                         3 * NN, 256, 128, 0);
    normcat_kernel<<<NN * 512 / 256, 256, 0, stream>>>(x1, w1b, cat2_h, cat2_l, 256, 256, 9);
    mfma_gemm<<<dim3(NN / 128, 4), 256, 0, stream>>>(cat2_h, cat2_l, WT_o1Wu1, WT_o1Wu1 + WLO,
                                                     o1_bu1, t4_h, t4_l, NN, 512, 256, 1);
    mfma_gemm<<<dim3(NN / 128, 4), 256, 0, stream>>>(t4_h, t4_l, WT_o1Wu2, WT_o1Wu2 + WLO,
                                                     o1_bu2, h1, nullptr, NN, 256, 256, 0);
    gate1_kernel<<<NN * 128 / 256, 256, 0, stream>>>(h1, w2_h, w2_l, x3, vecC_h, vecC_l);

    // Phase 5: gated equivariant block 2 + output
    mfma_gemm<<<dim3(3 * NN / 128, 2), 256, 0, stream>>>(vecC_h, vecC_l, WT_o2Wv1,
                                                         WT_o2Wv1 + WLO, nullptr,
                                                         w3b, nullptr, 3 * NN, 128, 128, 2);
    g12_kernel<<<3 * NN / 4, 256, 0, stream>>>(vecC_h, vecC_l, o2_Wv2, w4);
    normcat_kernel<<<NN * 256 / 256, 256, 0, stream>>>(x3, w3b, cat3_h, cat3_l, 128, 128, 8);
    mfma_gemm<<<dim3(NN / 128, 2), 256, 0, stream>>>(cat3_h, cat3_l, WT_o2Wu1, WT_o2Wu1 + WLO,
                                                     o2_bu1, t5, nullptr, NN, 256, 128, 1);
    final_kernel<<<NN / 4, 256, 0, stream>>>(t5, o2_Wu2, o2_bu2, w4, out);
}

// Round 5
// 1578.692 us; speedup vs baseline: 1.6739x; 1.0155x over previous
//
#include <hip/hip_runtime.h>
#include <math.h>

#define NN 16384
#define EE 262144
#define HH 256

#define INV_SQRT_3f 0.57735026918962576f
#define INV_SQRT_Hf 0.0625f
#define INV_SQRT_2f 0.70710678118654752f
#define SSILU_SCALE 1.6666666666666667f

typedef __attribute__((ext_vector_type(8))) short bf16x8;
typedef __attribute__((ext_vector_type(4))) float f32x4;

__device__ __forceinline__ float ssilu_f(float v) {
    return v * (1.0f / (1.0f + __expf(-v))) * SSILU_SCALE;
}
__device__ __forceinline__ float b2f(short s) {
    unsigned int u = ((unsigned int)(unsigned short)s) << 16;
    return __uint_as_float(u);
}
__device__ __forceinline__ short f2b(float f) {
    unsigned int u = __float_as_uint(f);
    unsigned int r = (u + 0x7fff + ((u >> 16) & 1)) >> 16;
    return (short)r;
}

// ---------------- LayerNorm: one block per row, split-bf16 out ----------------
__global__ void __launch_bounds__(256) ln_kernel(const float* __restrict__ x,
                                                 const float* __restrict__ g,
                                                 const float* __restrict__ b,
                                                 short* __restrict__ oh,
                                                 short* __restrict__ ol) {
    int n = blockIdx.x;
    int t = threadIdx.x;
    float v = x[(long)n * HH + t];
    float s = v, s2 = v * v;
    #pragma unroll
    for (int off = 32; off > 0; off >>= 1) {
        s  += __shfl_down(s, off);
        s2 += __shfl_down(s2, off);
    }
    __shared__ float red[8];
    int wave = t >> 6, lane = t & 63;
    if (lane == 0) { red[wave] = s; red[4 + wave] = s2; }
    __syncthreads();
    __shared__ float mr[2];
    if (t == 0) {
        float ts = red[0] + red[1] + red[2] + red[3];
        float ts2 = red[4] + red[5] + red[6] + red[7];
        float mean = ts * (1.0f / HH);
        float var = ts2 * (1.0f / HH) - mean * mean;
        mr[0] = mean;
        mr[1] = rsqrtf(var + 1e-5f);
    }
    __syncthreads();
    float o = (v - mr[0]) * mr[1] * g[t] + b[t];
    short hh = f2b(o);
    oh[(long)n * HH + t] = hh;
    ol[(long)n * HH + t] = f2b(o - b2f(hh));
}

// ---- ALL weight transposes + hi/lo splits in ONE kernel (incl. W_rbf) ----
struct WtArgs {
    const float* W[12];
    int K[12];
    int N[12];
    int off[13];   // cumulative element offsets; off[12] = total
};

__global__ void __launch_bounds__(256) wt_split_all(WtArgs a,
                                                    short* __restrict__ WTh,
                                                    short* __restrict__ WTl) {
    int idx = blockIdx.x * 256 + threadIdx.x;
    int s = 0;
    #pragma unroll
    for (int i = 1; i < 12; i++) s += (idx >= a.off[i]) ? 1 : 0;
    int local = idx - a.off[s];
    int K = a.K[s], N = a.N[s];
    int k = local / N, n = local - k * N;
    float w = a.W[s][local];
    short hh = f2b(w);
    long o = (long)a.off[s] + (long)n * K + k;
    WTh[o] = hh;
    WTl[o] = f2b(w - b2f(hh));
}

// ---- fp32 -> hi/lo split (count % 1024 == 0) ----
__global__ void __launch_bounds__(256) split4_kernel(const float* __restrict__ in,
                                                     short* __restrict__ h,
                                                     short* __restrict__ l) {
    long i = ((long)blockIdx.x * 256 + threadIdx.x) * 4;
    float4 v = *(const float4*)(in + i);
    short4 oh, ol;
    oh.x = f2b(v.x); ol.x = f2b(v.x - b2f(oh.x));
    oh.y = f2b(v.y); ol.y = f2b(v.y - b2f(oh.y));
    oh.z = f2b(v.z); ol.z = f2b(v.z - b2f(oh.z));
    oh.w = f2b(v.w); ol.w = f2b(v.w - b2f(oh.w));
    *(short4*)(h + i) = oh;
    *(short4*)(l + i) = ol;
}

// ---- split-bf16 MFMA GEMM v2: C = (Ah+Al)(M,K) @ (Wh+Wl)^T(N,K) [+bias][ssilu]
__global__ void __launch_bounds__(256) mfma_gemm(const short* __restrict__ Ah,
                                                 const short* __restrict__ Al,
                                                 const short* __restrict__ Wh,
                                                 const short* __restrict__ Wl,
                                                 const float* __restrict__ bias,
                                                 void* __restrict__ Ch,
                                                 short* __restrict__ Cl,
                                                 int M, int K, int N, int act) {
    int tid = threadIdx.x;
    int wave = tid >> 6, lane = tid & 63;
    int quad = lane >> 4, l16 = lane & 15;
    long bm = (long)blockIdx.x * 128 + wave * 32;
    long bn = (long)blockIdx.y * 64;
    long a0 = (bm + l16) * K + quad * 8;
    long a1 = a0 + (long)16 * K;
    long w0 = (bn + l16) * K + quad * 8;

    f32x4 acc[2][4];
    #pragma unroll
    for (int f = 0; f < 2; f++)
        #pragma unroll
        for (int t = 0; t < 4; t++) acc[f][t] = (f32x4){0.f, 0.f, 0.f, 0.f};

    bf16x8 cah[2], cal[2], cbh[4], cbl[4];
    cah[0] = *(const bf16x8*)(Ah + a0);
    cah[1] = *(const bf16x8*)(Ah + a1);
    cal[0] = *(const bf16x8*)(Al + a0);
    cal[1] = *(const bf16x8*)(Al + a1);
    #pragma unroll
    for (int t = 0; t < 4; t++) {
        long wo = w0 + (long)t * 16 * K;
        cbh[t] = *(const bf16x8*)(Wh + wo);
        cbl[t] = *(const bf16x8*)(Wl + wo);
    }

    for (int k0 = 0; k0 < K; k0 += 32) {
        int k1 = k0 + 32;
        bf16x8 nah[2], nal[2], nbh[4], nbl[4];
        if (k1 < K) {
            nah[0] = *(const bf16x8*)(Ah + a0 + k1);
            nah[1] = *(const bf16x8*)(Ah + a1 + k1);
            nal[0] = *(const bf16x8*)(Al + a0 + k1);
            nal[1] = *(const bf16x8*)(Al + a1 + k1);
            #pragma unroll
            for (int t = 0; t < 4; t++) {
                long wo = w0 + (long)t * 16 * K + k1;
                nbh[t] = *(const bf16x8*)(Wh + wo);
                nbl[t] = *(const bf16x8*)(Wl + wo);
            }
        }
        #pragma unroll
        for (int t = 0; t < 4; t++) {
            #pragma unroll
            for (int f = 0; f < 2; f++) {
                acc[f][t] = __builtin_amdgcn_mfma_f32_16x16x32_bf16(cah[f], cbh[t], acc[f][t], 0, 0, 0);
                acc[f][t] = __builtin_amdgcn_mfma_f32_16x16x32_bf16(cal[f], cbh[t], acc[f][t], 0, 0, 0);
                acc[f][t] = __builtin_amdgcn_mfma_f32_16x16x32_bf16(cah[f], cbl[t], acc[f][t], 0, 0, 0);
            }
        }
        if (k1 < K) {
            cah[0] = nah[0]; cah[1] = nah[1];
            cal[0] = nal[0]; cal[1] = nal[1];
            #pragma unroll
            for (int t = 0; t < 4; t++) { cbh[t] = nbh[t]; cbl[t] = nbl[t]; }
        }
    }

    #pragma unroll
    for (int f = 0; f < 2; f++) {
        long row0 = bm + f * 16 + quad * 4;
        #pragma unroll
        for (int t = 0; t < 4; t++) {
            long col = bn + t * 16 + l16;
            float bv = bias ? bias[col] : 0.f;
            #pragma unroll
            for (int r = 0; r < 4; r++) {
                float v = acc[f][t][r] + bv;
                if (act & 1) v = ssilu_f(v);
                long idx = (row0 + r) * N + col;
                if (Cl) {
                    short hh = f2b(v);
                    ((short*)Ch)[idx] = hh;
                    Cl[idx] = f2b(v - b2f(hh));
                } else if (act & 2) {
                    ((short*)Ch)[idx] = f2b(v);
                } else {
                    ((float*)Ch)[idx] = v;
                }
            }
        }
    }
}

// ---------------- edge sort (counting sort by dst) ----------------
__global__ void __launch_bounds__(256) zero_kernel(int* __restrict__ p, int n) {
    int i = blockIdx.x * 256 + threadIdx.x;
    if (i < n) p[i] = 0;
}

__global__ void __launch_bounds__(256) hist_kernel(const int* __restrict__ eidx,
                                                   int* __restrict__ cnt) {
    int e = blockIdx.x * 256 + threadIdx.x;
    atomicAdd(&cnt[eidx[EE + e]], 1);
}

__global__ void __launch_bounds__(256) scan_kernel(int* __restrict__ cursor,
                                                   int* __restrict__ rowptr) {
    int t = threadIdx.x;
    int base_i = t * 64;
    int tsum = 0;
    for (int i = 0; i < 64; i++) tsum += cursor[base_i + i];
    __shared__ int ls[256];
    ls[t] = tsum;
    __syncthreads();
    for (int off = 1; off < 256; off <<= 1) {
        int v = (t >= off) ? ls[t - off] : 0;
        __syncthreads();
        ls[t] += v;
        __syncthreads();
    }
    int running = ls[t] - tsum;
    for (int i = 0; i < 64; i++) {
        int c = cursor[base_i + i];
        rowptr[base_i + i] = running;
        cursor[base_i + i] = running;
        running += c;
    }
    if (t == 255) rowptr[NN] = running;
}

// scatter: also materialize dst/src/ev in sorted order for the edge kernel
__global__ void __launch_bounds__(256) scatter_kernel(const int* __restrict__ eidx,
                                                      const float* __restrict__ ev,
                                                      int* __restrict__ cursor,
                                                      int* __restrict__ perm,
                                                      int* __restrict__ dsts,
                                                      int* __restrict__ srcs,
                                                      float* __restrict__ evs) {
    int e = blockIdx.x * 256 + threadIdx.x;
    int s_ = eidx[e];
    int d_ = eidx[EE + e];
    int pos = atomicAdd(&cursor[d_], 1);
    perm[pos] = e;
    dsts[pos] = d_;
    srcs[pos] = s_;
    evs[pos * 3 + 0] = ev[e * 3 + 0];
    evs[pos * 3 + 1] = ev[e * 3 + 1];
    evs[pos * 3 + 2] = ev[e * 3 + 2];
}

// ---------------- Edge-parallel fused rbf-GEMM + gather + atomic reduce -------
// v3: BARRIER-FREE. Key fact: each wave writes mlds[wave*32..+31][*] and reads
// back ONLY those rows — no cross-wave LDS sharing anywhere (dst/src/ev staged
// per-wave by lanes 0-31 of the owning wave). DS ops are in-order per wave and
// the compiler inserts lgkmcnt waits for same-array RAW, so ALL __syncthreads()
// are deleted. The 4 waves run as independent streams: gather latency of one
// wave no longer stalls the other three, and MFMA/VALU/memory phases of
// different waves overlap on the CU.
__global__ void __launch_bounds__(256) edge_gather_kernel(
        const float* __restrict__ rbf,
        const short* __restrict__ Wrh,
        const short* __restrict__ Wrl,
        const float* __restrict__ b_rbf,
        const float* __restrict__ xh,
        const float* __restrict__ vec,
        const int* __restrict__ perm,
        const int* __restrict__ dsts,
        const int* __restrict__ srcs,
        const float* __restrict__ evs,
        float* __restrict__ x1,
        float* __restrict__ vecacc) {
    int tid = threadIdx.x;
    int wave = tid >> 6, lane = tid & 63;
    int quad = lane >> 4, l16 = lane & 15;
    int bm = blockIdx.x * 128;
    int base = wave * 32;

    __shared__ __align__(16) float mlds[128][66];
    __shared__ int dst_s[128], src_s[128];
    __shared__ float ev_s[128][3];

    // per-wave staging: lanes 0-31 stage this wave's 32 rows (same-wave
    // in-order DS => no barrier needed before reads later in this wave)
    if (lane < 32) {
        int i = base + lane;
        dst_s[i] = dsts[bm + i];
        src_s[i] = srcs[bm + i];
        ev_s[i][0] = evs[(long)(bm + i) * 3 + 0];
        ev_s[i][1] = evs[(long)(bm + i) * 3 + 1];
        ev_s[i][2] = evs[(long)(bm + i) * 3 + 2];
    }

    // ---- A fragments ONCE: rbf rows via perm, fp32 -> split hi/lo in regs ----
    int r0 = bm + wave * 32 + l16;
    int e0 = perm[r0];
    int e1 = perm[r0 + 16];
    bf16x8 afh[2][2], afl[2][2];     // [f][ks] — pinned for the kernel
    #pragma unroll
    for (int f = 0; f < 2; f++) {
        long ebase = (long)(f == 0 ? e0 : e1) * 64 + quad * 8;
        #pragma unroll
        for (int ks = 0; ks < 2; ks++) {
            float4 ua = *(const float4*)(rbf + ebase + ks * 32);
            float4 ub = *(const float4*)(rbf + ebase + ks * 32 + 4);
            float vv[8] = {ua.x, ua.y, ua.z, ua.w, ub.x, ub.y, ub.z, ub.w};
            bf16x8 hh, ll;
            #pragma unroll
            for (int j = 0; j < 8; j++) {
                short hb = f2b(vv[j]);
                hh[j] = hb;
                ll[j] = f2b(vv[j] - b2f(hb));
            }
            afh[f][ks] = hh;
            afl[f][ks] = ll;
        }
    }

    for (int sec = 0; sec < 3; sec++) {
        for (int tile = 0; tile < 4; tile++) {
            int bn = sec * 256 + tile * 64;
            // ---- MFMA round: m[:, bn..bn+63] ----
            f32x4 acc[2][4];
            #pragma unroll
            for (int t = 0; t < 4; t++) {
                float bv = b_rbf[bn + t * 16 + l16];
                acc[0][t] = (f32x4){bv, bv, bv, bv};
                acc[1][t] = (f32x4){bv, bv, bv, bv};
            }
            #pragma unroll
            for (int t = 0; t < 4; t++) {
                #pragma unroll
                for (int ks = 0; ks < 2; ks++) {
                    long wo = (long)(bn + t * 16 + l16) * 64 + ks * 32 + quad * 8;
                    bf16x8 bh = *(const bf16x8*)(Wrh + wo);
                    bf16x8 bl = *(const bf16x8*)(Wrl + wo);
                    #pragma unroll
                    for (int f = 0; f < 2; f++) {
                        acc[f][t] = __builtin_amdgcn_mfma_f32_16x16x32_bf16(afh[f][ks], bh, acc[f][t], 0, 0, 0);
                        acc[f][t] = __builtin_amdgcn_mfma_f32_16x16x32_bf16(afl[f][ks], bh, acc[f][t], 0, 0, 0);
                        acc[f][t] = __builtin_amdgcn_mfma_f32_16x16x32_bf16(afh[f][ks], bl, acc[f][t], 0, 0, 0);
                    }
                }
            }
            // write this wave's 32 rows (only this wave reads them back)
            #pragma unroll
            for (int f = 0; f < 2; f++)
                #pragma unroll
                for (int t = 0; t < 4; t++)
                    #pragma unroll
                    for (int r = 0; r < 4; r++)
                        mlds[base + f * 16 + quad * 4 + r][t * 16 + l16] = acc[f][t][r];

            // ---- consume: wave owns its 32 rows; lane owns one column ----
            int colx = tile * 64 + lane;          // 0..255 within section
            if (sec == 0) {
                float a = 0.f;
                int dprev = dst_s[base];
                #pragma unroll 4
                for (int i = 0; i < 32; i++) {
                    int d = dst_s[base + i];
                    if (d != dprev) {
                        atomicAdd(&x1[(long)dprev * 256 + colx], a);
                        a = 0.f;
                        dprev = d;
                    }
                    long xb = (long)src_s[base + i] * 768;
                    a += mlds[base + i][lane] * xh[xb + colx];
                }
                atomicAdd(&x1[(long)dprev * 256 + colx], a);
            } else if (sec == 1) {
                float a0 = 0.f, a1 = 0.f, a2 = 0.f;
                int dprev = dst_s[base];
                #pragma unroll 4
                for (int i = 0; i < 32; i++) {
                    int d = dst_s[base + i];
                    if (d != dprev) {
                        long vb = (long)dprev * 768 + colx;
                        atomicAdd(&vecacc[vb], a0);
                        atomicAdd(&vecacc[vb + 256], a1);
                        atomicAdd(&vecacc[vb + 512], a2);
                        a0 = a1 = a2 = 0.f;
                        dprev = d;
                    }
                    long xb = (long)src_s[base + i] * 768;
                    float m2 = mlds[base + i][lane] * (INV_SQRT_3f * INV_SQRT_Hf) *
                               xh[xb + 256 + colx];
                    a0 += vec[xb + colx] * m2;
                    a1 += vec[xb + 256 + colx] * m2;
                    a2 += vec[xb + 512 + colx] * m2;
                }
                long vb = (long)dprev * 768 + colx;
                atomicAdd(&vecacc[vb], a0);
                atomicAdd(&vecacc[vb + 256], a1);
                atomicAdd(&vecacc[vb + 512], a2);
            } else {
                float a0 = 0.f, a1 = 0.f, a2 = 0.f;
                int dprev = dst_s[base];
                #pragma unroll 4
                for (int i = 0; i < 32; i++) {
                    int d = dst_s[base + i];
                    if (d != dprev) {
                        long vb = (long)dprev * 768 + colx;
                        atomicAdd(&vecacc[vb], a0);
                        atomicAdd(&vecacc[vb + 256], a1);
                        atomicAdd(&vecacc[vb + 512], a2);
                        a0 = a1 = a2 = 0.f;
                        dprev = d;
                    }
                    long xb = (long)src_s[base + i] * 768;
                    float m3 = mlds[base + i][lane] * INV_SQRT_Hf * xh[xb + 512 + colx];
                    a0 += m3 * ev_s[base + i][0];
                    a1 += m3 * ev_s[base + i][1];
                    a2 += m3 * ev_s[base + i][2];
                }
                long vb = (long)dprev * 768 + colx;
                atomicAdd(&vecacc[vb], a0);
                atomicAdd(&vecacc[vb + 256], a1);
                atomicAdd(&vecacc[vb + 512], a2);
            }
        }
    }
}

// ---------------- vec_dot + vnorm + cat(x, vnorm), split out ----------------
__global__ void __launch_bounds__(256) vdot_cat_kernel(const float* __restrict__ vec1,
                                                       const short* __restrict__ vec2,
                                                       const float* __restrict__ x1,
                                                       float* __restrict__ vdot,
                                                       short* __restrict__ cath,
                                                       short* __restrict__ catl) {
    int idx = blockIdx.x * 256 + threadIdx.x;
    int n = idx >> 8, h = idx & 255;
    float dsum = 0.f, s2 = 0.f;
    #pragma unroll
    for (int d = 0; d < 3; d++) {
        long r = (long)(n * 3 + d) * 256 + h;
        float a = vec1[r];
        float b = b2f(vec2[r]);
        dsum += a * b;
        s2 += b * b;
    }
    vdot[idx] = dsum * INV_SQRT_Hf;
    float xv = x1[idx];
    short hh = f2b(xv);
    cath[(long)n * 512 + h] = hh;
    catl[(long)n * 512 + h] = f2b(xv - b2f(hh));
    float vn = sqrtf(s2 + 1e-8f);
    short vh = f2b(vn);
    cath[(long)n * 512 + 256 + h] = vh;
    catl[(long)n * 512 + 256 + h] = f2b(vn - b2f(vh));
}

// ---------------- x/vec update after xv MLP (IN-PLACE) ----------------
__global__ void __launch_bounds__(256) e4_kernel(float* __restrict__ x1,
                                                 float* __restrict__ vecacc,
                                                 const float* __restrict__ vec1,
                                                 const float* __restrict__ vdot,
                                                 const short* __restrict__ xvh_h,
                                                 const short* __restrict__ xvh_l) {
    int idx = blockIdx.x * 256 + threadIdx.x;
    int n = idx >> 8, h = idx & 255;
    long b0 = (long)n * 768 + h;
    float xv1 = b2f(xvh_h[b0])       + b2f(xvh_l[b0]);
    float xv2 = b2f(xvh_h[b0 + 256]) + b2f(xvh_l[b0 + 256]);
    float xv3 = b2f(xvh_h[b0 + 512]) + b2f(xvh_l[b0 + 512]);
    x1[idx] = x1[idx] + (xv1 + xv2 * vdot[idx]) * INV_SQRT_2f;
    #pragma unroll
    for (int d = 0; d < 3; d++) {
        long r = (long)(n * 3 + d) * 256 + h;
        vecacc[r] = vecacc[r] + xv3 * vec1[r];
    }
}

// ---------------- norm over d + concat(x fp32, norm), split out ----------------
__global__ void __launch_bounds__(256) normcat_kernel(const float* __restrict__ xin,
                                                      const short* __restrict__ w,
                                                      short* __restrict__ cath,
                                                      short* __restrict__ catl,
                                                      int Cx, int C, int shift) {
    int idx = blockIdx.x * 256 + threadIdx.x;
    int cols = 1 << shift;
    int n = idx >> shift, c = idx & (cols - 1);
    float v;
    if (c < Cx) {
        v = xin[(long)n * Cx + c];
    } else {
        int cc = c - Cx;
        float s = 0.f;
        #pragma unroll
        for (int d = 0; d < 3; d++) {
            float a = b2f(w[(long)(n * 3 + d) * C + cc]);
            s += a * a;
        }
        v = sqrtf(s);
    }
    short hh = f2b(v);
    cath[idx] = hh;
    catl[idx] = f2b(v - b2f(hh));
}

// ---------------- gated block 1 epilogue ----------------
__global__ void __launch_bounds__(256) gate1_kernel(const float* __restrict__ h1,
                                                    const short* __restrict__ w2h,
                                                    const short* __restrict__ w2l,
                                                    float* __restrict__ x3,
                                                    short* __restrict__ vecCh,
                                                    short* __restrict__ vecCl) {
    int idx = blockIdx.x * 256 + threadIdx.x;
    int n = idx >> 7, c = idx & 127;
    x3[idx] = ssilu_f(h1[(long)n * 256 + c]);
    float vn = h1[(long)n * 256 + 128 + c];
    #pragma unroll
    for (int d = 0; d < 3; d++) {
        long r = (long)(n * 3 + d) * 128 + c;
        float wv = b2f(w2h[r]) + b2f(w2l[r]);
        float v = vn * wv;
        short hh = f2b(v);
        vecCh[r] = hh;
        vecCl[r] = f2b(v - b2f(hh));
    }
}

// ---------------- vecC @ o2_Wv2 (K=128, Nc=1): one wave per row ----------------
__global__ void __launch_bounds__(256) g12_kernel(const short* __restrict__ vecCh,
                                                  const short* __restrict__ vecCl,
                                                  const float* __restrict__ Wv2,
                                                  float* __restrict__ w4) {
    int row = blockIdx.x * 4 + (threadIdx.x >> 6);
    int lane = threadIdx.x & 63;
    long r0 = (long)row * 128 + lane;
    float v0 = b2f(vecCh[r0]) + b2f(vecCl[r0]);
    float v1 = b2f(vecCh[r0 + 64]) + b2f(vecCl[r0 + 64]);
    float s = v0 * Wv2[lane] + v1 * Wv2[64 + lane];
    #pragma unroll
    for (int off = 32; off > 0; off >>= 1) s += __shfl_down(s, off);
    if (lane == 0) w4[row] = s;
}

// ---------------- final: out[n,d] = (t5[n,:]@Wu2[:,1] + b2[1]) * w4[n,d] ----------
__global__ void __launch_bounds__(256) final_kernel(const float* __restrict__ t5,
                                                    const float* __restrict__ Wu2,
                                                    const float* __restrict__ bu2,
                                                    const float* __restrict__ w4,
                                                    float* __restrict__ out) {
    int n = blockIdx.x * 4 + (threadIdx.x >> 6);
    int lane = threadIdx.x & 63;
    float s = t5[(long)n * 128 + lane] * Wu2[lane * 2 + 1] +
              t5[(long)n * 128 + 64 + lane] * Wu2[(64 + lane) * 2 + 1];
    #pragma unroll
    for (int off = 32; off > 0; off >>= 1) s += __shfl_down(s, off);
    float val = __shfl(s, 0) + bu2[1];
    if (lane < 3) out[(long)n * 3 + lane] = val * w4[(long)n * 3 + lane];
}

extern "C" void kernel_launch(void* const* d_in, const int* in_sizes, int n_in,
                              void* d_out, int out_size, void* d_ws, size_t ws_size,
                              hipStream_t stream) {
    const float* x          = (const float*)d_in[0];
    const float* vec        = (const float*)d_in[1];
    const float* edge_rbf   = (const float*)d_in[2];
    const float* edge_vector= (const float*)d_in[3];
    const float* ln_g       = (const float*)d_in[4];
    const float* ln_b       = (const float*)d_in[5];
    const float* W_x1       = (const float*)d_in[6];
    const float* b_x1       = (const float*)d_in[7];
    const float* W_x2       = (const float*)d_in[8];
    const float* b_x2       = (const float*)d_in[9];
    const float* W_rbf      = (const float*)d_in[10];
    const float* b_rbf      = (const float*)d_in[11];
    const float* W_vp       = (const float*)d_in[12];
    const float* W_xv1      = (const float*)d_in[13];
    const float* b_xv1      = (const float*)d_in[14];
    const float* W_xv2      = (const float*)d_in[15];
    const float* b_xv2      = (const float*)d_in[16];
    const float* o1_Wv1     = (const float*)d_in[17];
    const float* o1_Wv2     = (const float*)d_in[18];
    const float* o1_Wu1     = (const float*)d_in[19];
    const float* o1_bu1     = (const float*)d_in[20];
    const float* o1_Wu2     = (const float*)d_in[21];
    const float* o1_bu2     = (const float*)d_in[22];
    const float* o2_Wv1     = (const float*)d_in[23];
    const float* o2_Wv2     = (const float*)d_in[24];
    const float* o2_Wu1     = (const float*)d_in[25];
    const float* o2_bu1     = (const float*)d_in[26];
    const float* o2_Wu2     = (const float*)d_in[27];
    const float* o2_bu2     = (const float*)d_in[28];
    const int*   edge_index = (const int*)d_in[29];
    float* out = (float*)d_out;
    float* ws  = (float*)d_ws;

    const size_t S = (size_t)NN * 256;
    const size_t Q = S / 4;              // 1,048,576 floats = 4 MiB
    // ---- arena in units of Q; peak 52Q = 208 MiB (proven safe) ----
    float* x1      = ws;                     // Q0-3   (fp32 S)
    float* vecacc  = ws + 4 * Q;             // Q4-15  (fp32 3S)
    short* wtb     = (short*)(ws + 16 * Q);  // Q16-17 weights hi + lo
    const long WLO = 1114112;
    // phase 1
    short* xln_h = (short*)(ws + 18 * Q);    // Q18-19 (dead after t1 gemm)
    short* xln_l = (short*)(ws + 20 * Q);    // Q20-21
    short* t1_h  = (short*)(ws + 22 * Q);    // Q22-23 (dead after xh gemm)
    short* t1_l  = (short*)(ws + 24 * Q);    // Q24-25
    float* xh    = ws + 30 * Q;              // Q30-41 (fp32 3S, dead after gather)
    // phase 2 sort scratch (dead before vdot is written)
    int* rowptr    = (int*)(ws + 48 * Q);    // NN+1
    int* cursor    = rowptr + (NN + 1);      // NN
    int* perm      = cursor + NN;            // EE
    int* dsts      = perm + EE;              // EE
    int* srcs      = dsts + EE;              // EE
    float* evs     = (float*)(srcs + EE);    // 3*EE  (total ~6.4 MB < 16 MB)
    // phase 3 (vah/val_ produced by split4 after edge kernel)
    short* vah   = (short*)(ws + 18 * Q);    // Q18-23 (3S bf16)
    short* val_  = (short*)(ws + 24 * Q);    // Q24-29
    float* vec1  = ws + 30 * Q;              // Q30-41 (fp32 3S, live till e4)
    short* vec2b = (short*)(ws + 42 * Q);    // Q42-47 (bf16 3S)
    float* vdot  = ws + 48 * Q;              // Q48-51 (fp32 S, live till e4)
    short* catb_h = (short*)(ws + 18 * Q);   // Q18-21 (vah dead after vp gemms)
    short* catb_l = (short*)(ws + 22 * Q);   // Q22-25
    short* t2_h  = (short*)(ws + 26 * Q);    // Q26-27
    short* t2_l  = (short*)(ws + 28 * Q);    // Q28-29
    short* xvh_h = (short*)(ws + 18 * Q);    // Q18-23 (catb dead)
    short* xvh_l = (short*)(ws + 42 * Q);    // Q42-47 (vec2 dead)
    // phase 4
    short* vah2  = (short*)(ws + 18 * Q);    // Q18-23
    short* val2  = (short*)(ws + 24 * Q);    // Q24-29
    short* w1b   = (short*)(ws + 30 * Q);    // Q30-35 (bf16 3S)
    short* w2_h  = (short*)(ws + 36 * Q);    // Q36-38
    short* w2_l  = (short*)(ws + 39 * Q);    // Q39-41
    short* cat2_h = (short*)(ws + 42 * Q);   // Q42-45
    short* cat2_l = (short*)(ws + 46 * Q);   // Q46-49
    short* t4_h  = (short*)(ws + 18 * Q);    // Q18-19
    short* t4_l  = (short*)(ws + 20 * Q);    // Q20-21
    float* h1    = ws + 22 * Q;              // Q22-25 (fp32 S)
    float* x3    = ws + 26 * Q;              // Q26-27 (fp32 S/2)
    short* vecC_h = (short*)(ws + 28 * Q);   // Q28-30
    short* vecC_l = (short*)(ws + 31 * Q);   // Q31-33
    // phase 5
    short* w3b   = (short*)(ws + 34 * Q);    // Q34-36
    float* w4    = ws + 37 * Q;              // Q37
    short* cat3_h = (short*)(ws + 38 * Q);   // Q38-39
    short* cat3_l = (short*)(ws + 40 * Q);   // Q40-41
    float* t5    = ws + 42 * Q;              // Q42-43

    // weight hi/lo offsets (shorts)
    short* WT_x1    = wtb;
    short* WT_x2    = wtb + 65536;
    short* WT_vp    = wtb + 262144;
    short* WT_xv1   = wtb + 393216;
    short* WT_xv2   = wtb + 524288;
    short* WT_o1Wv1 = wtb + 720896;
    short* WT_o1Wv2 = wtb + 786432;
    short* WT_o1Wu1 = wtb + 819200;
    short* WT_o1Wu2 = wtb + 950272;
    short* WT_o2Wv1 = wtb + 1015808;
    short* WT_o2Wu1 = wtb + 1032192;
    short* WT_rbf   = wtb + 1064960;         // 768 x 64

    // Phase 0: all weight transposes + splits in one launch (incl. W_rbf^T)
    WtArgs wa;
    const float* wsrc[12] = {W_x1, W_x2, W_vp, W_xv1, W_xv2, o1_Wv1, o1_Wv2,
                             o1_Wu1, o1_Wu2, o2_Wv1, o2_Wu1, W_rbf};
    int wk[12] = {256, 256, 256, 512, 256, 256, 256, 512, 256, 128, 256, 64};
    int wn[12] = {256, 768, 512, 256, 768, 256, 128, 256, 256, 128, 128, 768};
    int off = 0;
    for (int i = 0; i < 12; i++) {
        wa.W[i] = wsrc[i]; wa.K[i] = wk[i]; wa.N[i] = wn[i];
        wa.off[i] = off; off += wk[i] * wn[i];
    }
    wa.off[12] = off;  // 1,114,112
    wt_split_all<<<off / 256, 256, 0, stream>>>(wa, wtb, wtb + WLO);

    // init accumulation targets (x1 = x, vecacc = vec)
    hipMemcpyAsync(x1, x, S * sizeof(float), hipMemcpyDeviceToDevice, stream);
    hipMemcpyAsync(vecacc, vec, 3 * S * sizeof(float), hipMemcpyDeviceToDevice, stream);

    // Phase 1: node MLP
    ln_kernel<<<NN, 256, 0, stream>>>(x, ln_g, ln_b, xln_h, xln_l);
    mfma_gemm<<<dim3(NN / 128, 4), 256, 0, stream>>>(xln_h, xln_l, WT_x1, WT_x1 + WLO,
                                                     b_x1, t1_h, t1_l, NN, 256, 256, 1);
    mfma_gemm<<<dim3(NN / 128, 12), 256, 0, stream>>>(t1_h, t1_l, WT_x2, WT_x2 + WLO,
                                                      b_x2, xh, nullptr, NN, 256, 768, 0);

    // Phase 2: sort edges by dst; edge-parallel fused gather (atomics)
    zero_kernel<<<(NN + 255) / 256, 256, 0, stream>>>(cursor, NN);
    hist_kernel<<<EE / 256, 256, 0, stream>>>(edge_index, cursor);
    scan_kernel<<<1, 256, 0, stream>>>(cursor, rowptr);
    scatter_kernel<<<EE / 256, 256, 0, stream>>>(edge_index, edge_vector, cursor,
                                                 perm, dsts, srcs, evs);
    edge_gather_kernel<<<EE / 128, 256, 0, stream>>>(
        edge_rbf, WT_rbf, WT_rbf + WLO, b_rbf, xh, vec,
        perm, dsts, srcs, evs, x1, vecacc);
    // hi/lo split of vecacc for the phase-3 GEMMs
    split4_kernel<<<3 * S / 1024, 256, 0, stream>>>(vecacc, vah, val_);

    // Phase 3: vp, vdot/vnorm, xv MLP, in-place updates
    mfma_gemm<<<dim3(3 * NN / 128, 4), 256, 0, stream>>>(vah, val_, WT_vp, WT_vp + WLO,
                                                         nullptr, vec1, nullptr,
                                                         3 * NN, 256, 256, 0);
    mfma_gemm<<<dim3(3 * NN / 128, 4), 256, 0, stream>>>(vah, val_, WT_vp + 65536,
                                                         WT_vp + WLO + 65536,
                                                         nullptr, vec2b, nullptr,
                                                         3 * NN, 256, 256, 2);
    vdot_cat_kernel<<<NN, 256, 0, stream>>>(vec1, vec2b, x1, vdot, catb_h, catb_l);
    mfma_gemm<<<dim3(NN / 128, 4), 256, 0, stream>>>(catb_h, catb_l, WT_xv1, WT_xv1 + WLO,
                                                     b_xv1, t2_h, t2_l, NN, 512, 256, 1);
    mfma_gemm<<<dim3(NN / 128, 12), 256, 0, stream>>>(t2_h, t2_l, WT_xv2, WT_xv2 + WLO,
                                                      b_xv2, xvh_h, xvh_l, NN, 256, 768, 0);
    e4_kernel<<<NN, 256, 0, stream>>>(x1, vecacc, vec1, vdot, xvh_h, xvh_l);

    // Phase 4: gated equivariant block 1
    split4_kernel<<<3 * S / 1024, 256, 0, stream>>>(vecacc, vah2, val2);
    mfma_gemm<<<dim3(3 * NN / 128, 4), 256, 0, stream>>>(vah2, val2, WT_o1Wv1, WT_o1Wv1 + WLO,
                                                         nullptr, w1b, nullptr,
                                                         3 * NN, 256, 256, 2);
    mfma_gemm<<<dim3(3 * NN / 128, 2), 256, 0, stream>>>(vah2, val2, WT_o1Wv2, WT_o1Wv2 + WLO,
                                                         nullptr, w2_h, w2_l,
                                                         3 * NN, 256, 128, 0);
    normcat_kernel<<<NN * 512 / 256, 256, 0, stream>>>(x1, w1b, cat2_h, cat2_l, 256, 256, 9);
    mfma_gemm<<<dim3(NN / 128, 4), 256, 0, stream>>>(cat2_h, cat2_l, WT_o1Wu1, WT_o1Wu1 + WLO,
                                                     o1_bu1, t4_h, t4_l, NN, 512, 256, 1);
    mfma_gemm<<<dim3(NN / 128, 4), 256, 0, stream>>>(t4_h, t4_l, WT_o1Wu2, WT_o1Wu2 + WLO,
                                                     o1_bu2, h1, nullptr, NN, 256, 256, 0);
    gate1_kernel<<<NN * 128 / 256, 256, 0, stream>>>(h1, w2_h, w2_l, x3, vecC_h, vecC_l);

    // Phase 5: gated equivariant block 2 + output
    mfma_gemm<<<dim3(3 * NN / 128, 2), 256, 0, stream>>>(vecC_h, vecC_l, WT_o2Wv1,
                                                         WT_o2Wv1 + WLO, nullptr,
                                                         w3b, nullptr, 3 * NN, 128, 128, 2);
    g12_kernel<<<3 * NN / 4, 256, 0, stream>>>(vecC_h, vecC_l, o2_Wv2, w4);
    normcat_kernel<<<NN * 256 / 256, 256, 0, stream>>>(x3, w3b, cat3_h, cat3_l, 128, 128, 8);
    mfma_gemm<<<dim3(NN / 128, 2), 256, 0, stream>>>(cat3_h, cat3_l, WT_o2Wu1, WT_o2Wu1 + WLO,
                                                     o2_bu1, t5, nullptr, NN, 256, 128, 1);
    final_kernel<<<NN / 4, 256, 0, stream>>>(t5, o2_Wu2, o2_bu2, w4, out);
}

// Round 6
// 1479.291 us; speedup vs baseline: 1.7864x; 1.0672x over previous
//
#include <hip/hip_runtime.h>
#include <math.h>

#define NN 16384
#define EE 262144
#define HH 256

#define INV_SQRT_3f 0.57735026918962576f
#define INV_SQRT_Hf 0.0625f
#define INV_SQRT_2f 0.70710678118654752f
#define SSILU_SCALE 1.6666666666666667f

typedef __attribute__((ext_vector_type(8))) short bf16x8;
typedef __attribute__((ext_vector_type(4))) float f32x4;

__device__ __forceinline__ float ssilu_f(float v) {
    return v * (1.0f / (1.0f + __expf(-v))) * SSILU_SCALE;
}
__device__ __forceinline__ float b2f(short s) {
    unsigned int u = ((unsigned int)(unsigned short)s) << 16;
    return __uint_as_float(u);
}
__device__ __forceinline__ short f2b(float f) {
    unsigned int u = __float_as_uint(f);
    unsigned int r = (u + 0x7fff + ((u >> 16) & 1)) >> 16;
    return (short)r;
}

// ---------------- LayerNorm: one block per row, split-bf16 out ----------------
// also initializes x1 = x (folds away the 128MB-traffic D2D memcpy)
__global__ void __launch_bounds__(256) ln_kernel(const float* __restrict__ x,
                                                 const float* __restrict__ g,
                                                 const float* __restrict__ b,
                                                 short* __restrict__ oh,
                                                 short* __restrict__ ol,
                                                 float* __restrict__ x1) {
    int n = blockIdx.x;
    int t = threadIdx.x;
    float v = x[(long)n * HH + t];
    x1[(long)n * HH + t] = v;
    float s = v, s2 = v * v;
    #pragma unroll
    for (int off = 32; off > 0; off >>= 1) {
        s  += __shfl_down(s, off);
        s2 += __shfl_down(s2, off);
    }
    __shared__ float red[8];
    int wave = t >> 6, lane = t & 63;
    if (lane == 0) { red[wave] = s; red[4 + wave] = s2; }
    __syncthreads();
    __shared__ float mr[2];
    if (t == 0) {
        float ts = red[0] + red[1] + red[2] + red[3];
        float ts2 = red[4] + red[5] + red[6] + red[7];
        float mean = ts * (1.0f / HH);
        float var = ts2 * (1.0f / HH) - mean * mean;
        mr[0] = mean;
        mr[1] = rsqrtf(var + 1e-5f);
    }
    __syncthreads();
    float o = (v - mr[0]) * mr[1] * g[t] + b[t];
    short hh = f2b(o);
    oh[(long)n * HH + t] = hh;
    ol[(long)n * HH + t] = f2b(o - b2f(hh));
}

// ---- ALL weight transposes + hi/lo splits in ONE kernel (incl. W_rbf) ----
struct WtArgs {
    const float* W[12];
    int K[12];
    int N[12];
    int off[13];   // cumulative element offsets; off[12] = total
};

__global__ void __launch_bounds__(256) wt_split_all(WtArgs a,
                                                    short* __restrict__ WTh,
                                                    short* __restrict__ WTl) {
    int idx = blockIdx.x * 256 + threadIdx.x;
    int s = 0;
    #pragma unroll
    for (int i = 1; i < 12; i++) s += (idx >= a.off[i]) ? 1 : 0;
    int local = idx - a.off[s];
    int K = a.K[s], N = a.N[s];
    int k = local / N, n = local - k * N;
    float w = a.W[s][local];
    short hh = f2b(w);
    long o = (long)a.off[s] + (long)n * K + k;
    WTh[o] = hh;
    WTl[o] = f2b(w - b2f(hh));
}

// ---- fp32 -> hi/lo split (count % 1024 == 0) ----
__global__ void __launch_bounds__(256) split4_kernel(const float* __restrict__ in,
                                                     short* __restrict__ h,
                                                     short* __restrict__ l) {
    long i = ((long)blockIdx.x * 256 + threadIdx.x) * 4;
    float4 v = *(const float4*)(in + i);
    short4 oh, ol;
    oh.x = f2b(v.x); ol.x = f2b(v.x - b2f(oh.x));
    oh.y = f2b(v.y); ol.y = f2b(v.y - b2f(oh.y));
    oh.z = f2b(v.z); ol.z = f2b(v.z - b2f(oh.z));
    oh.w = f2b(v.w); ol.w = f2b(v.w - b2f(oh.w));
    *(short4*)(h + i) = oh;
    *(short4*)(l + i) = ol;
}

// ---- split-bf16 MFMA GEMM v2: C = (Ah+Al)(M,K) @ (Wh+Wl)^T(N,K) [+bias][ssilu]
__global__ void __launch_bounds__(256) mfma_gemm(const short* __restrict__ Ah,
                                                 const short* __restrict__ Al,
                                                 const short* __restrict__ Wh,
                                                 const short* __restrict__ Wl,
                                                 const float* __restrict__ bias,
                                                 void* __restrict__ Ch,
                                                 short* __restrict__ Cl,
                                                 int M, int K, int N, int act) {
    int tid = threadIdx.x;
    int wave = tid >> 6, lane = tid & 63;
    int quad = lane >> 4, l16 = lane & 15;
    long bm = (long)blockIdx.x * 128 + wave * 32;
    long bn = (long)blockIdx.y * 64;
    long a0 = (bm + l16) * K + quad * 8;
    long a1 = a0 + (long)16 * K;
    long w0 = (bn + l16) * K + quad * 8;

    f32x4 acc[2][4];
    #pragma unroll
    for (int f = 0; f < 2; f++)
        #pragma unroll
        for (int t = 0; t < 4; t++) acc[f][t] = (f32x4){0.f, 0.f, 0.f, 0.f};

    bf16x8 cah[2], cal[2], cbh[4], cbl[4];
    cah[0] = *(const bf16x8*)(Ah + a0);
    cah[1] = *(const bf16x8*)(Ah + a1);
    cal[0] = *(const bf16x8*)(Al + a0);
    cal[1] = *(const bf16x8*)(Al + a1);
    #pragma unroll
    for (int t = 0; t < 4; t++) {
        long wo = w0 + (long)t * 16 * K;
        cbh[t] = *(const bf16x8*)(Wh + wo);
        cbl[t] = *(const bf16x8*)(Wl + wo);
    }

    for (int k0 = 0; k0 < K; k0 += 32) {
        int k1 = k0 + 32;
        bf16x8 nah[2], nal[2], nbh[4], nbl[4];
        if (k1 < K) {
            nah[0] = *(const bf16x8*)(Ah + a0 + k1);
            nah[1] = *(const bf16x8*)(Ah + a1 + k1);
            nal[0] = *(const bf16x8*)(Al + a0 + k1);
            nal[1] = *(const bf16x8*)(Al + a1 + k1);
            #pragma unroll
            for (int t = 0; t < 4; t++) {
                long wo = w0 + (long)t * 16 * K + k1;
                nbh[t] = *(const bf16x8*)(Wh + wo);
                nbl[t] = *(const bf16x8*)(Wl + wo);
            }
        }
        #pragma unroll
        for (int t = 0; t < 4; t++) {
            #pragma unroll
            for (int f = 0; f < 2; f++) {
                acc[f][t] = __builtin_amdgcn_mfma_f32_16x16x32_bf16(cah[f], cbh[t], acc[f][t], 0, 0, 0);
                acc[f][t] = __builtin_amdgcn_mfma_f32_16x16x32_bf16(cal[f], cbh[t], acc[f][t], 0, 0, 0);
                acc[f][t] = __builtin_amdgcn_mfma_f32_16x16x32_bf16(cah[f], cbl[t], acc[f][t], 0, 0, 0);
            }
        }
        if (k1 < K) {
            cah[0] = nah[0]; cah[1] = nah[1];
            cal[0] = nal[0]; cal[1] = nal[1];
            #pragma unroll
            for (int t = 0; t < 4; t++) { cbh[t] = nbh[t]; cbl[t] = nbl[t]; }
        }
    }

    #pragma unroll
    for (int f = 0; f < 2; f++) {
        long row0 = bm + f * 16 + quad * 4;
        #pragma unroll
        for (int t = 0; t < 4; t++) {
            long col = bn + t * 16 + l16;
            float bv = bias ? bias[col] : 0.f;
            #pragma unroll
            for (int r = 0; r < 4; r++) {
                float v = acc[f][t][r] + bv;
                if (act & 1) v = ssilu_f(v);
                long idx = (row0 + r) * N + col;
                if (Cl) {
                    short hh = f2b(v);
                    ((short*)Ch)[idx] = hh;
                    Cl[idx] = f2b(v - b2f(hh));
                } else if (act & 2) {
                    ((short*)Ch)[idx] = f2b(v);
                } else {
                    ((float*)Ch)[idx] = v;
                }
            }
        }
    }
}

// ---------------- edge sort (counting sort by dst) ----------------
__global__ void __launch_bounds__(256) zero_kernel(int* __restrict__ p, int n) {
    int i = blockIdx.x * 256 + threadIdx.x;
    if (i < n) p[i] = 0;
}

__global__ void __launch_bounds__(256) hist_kernel(const int* __restrict__ eidx,
                                                   int* __restrict__ cnt) {
    int e = blockIdx.x * 256 + threadIdx.x;
    atomicAdd(&cnt[eidx[EE + e]], 1);
}

__global__ void __launch_bounds__(256) scan_kernel(int* __restrict__ cursor,
                                                   int* __restrict__ rowptr) {
    int t = threadIdx.x;
    int base_i = t * 64;
    int tsum = 0;
    for (int i = 0; i < 64; i++) tsum += cursor[base_i + i];
    __shared__ int ls[256];
    ls[t] = tsum;
    __syncthreads();
    for (int off = 1; off < 256; off <<= 1) {
        int v = (t >= off) ? ls[t - off] : 0;
        __syncthreads();
        ls[t] += v;
        __syncthreads();
    }
    int running = ls[t] - tsum;
    for (int i = 0; i < 64; i++) {
        int c = cursor[base_i + i];
        rowptr[base_i + i] = running;
        cursor[base_i + i] = running;
        running += c;
    }
    if (t == 255) rowptr[NN] = running;
}

// scatter: also materialize dst/src/ev in sorted order for the edge kernel
__global__ void __launch_bounds__(256) scatter_kernel(const int* __restrict__ eidx,
                                                      const float* __restrict__ ev,
                                                      int* __restrict__ cursor,
                                                      int* __restrict__ perm,
                                                      int* __restrict__ dsts,
                                                      int* __restrict__ srcs,
                                                      float* __restrict__ evs) {
    int e = blockIdx.x * 256 + threadIdx.x;
    int s_ = eidx[e];
    int d_ = eidx[EE + e];
    int pos = atomicAdd(&cursor[d_], 1);
    perm[pos] = e;
    dsts[pos] = d_;
    srcs[pos] = s_;
    evs[pos * 3 + 0] = ev[e * 3 + 0];
    evs[pos * 3 + 1] = ev[e * 3 + 1];
    evs[pos * 3 + 2] = ev[e * 3 + 2];
}

// ---------------- Edge-parallel fused rbf-GEMM + gather + atomic reduce -------
// v4: 8 waves x 16 edges/wave (512-thread block, still 128 edges/block).
// Halves the per-wave serial chain and doubles waves/CU (LDS 36.4KB -> 4
// blocks/CU x 8 waves = 32 waves/CU target) — attacks the round-5 diagnosis
// of "latency-bound at ~10 resident waves/CU". A-fragment is 1 row-frag
// (16 VGPR) instead of 2; barrier-free per-wave mlds ownership unchanged.
__global__ void __launch_bounds__(512, 8) edge_gather_kernel(
        const float* __restrict__ rbf,
        const short* __restrict__ Wrh,
        const short* __restrict__ Wrl,
        const float* __restrict__ b_rbf,
        const float* __restrict__ xh,
        const float* __restrict__ vec,
        const int* __restrict__ perm,
        const int* __restrict__ dsts,
        const int* __restrict__ srcs,
        const float* __restrict__ evs,
        float* __restrict__ x1,
        float* __restrict__ vecacc) {
    int tid = threadIdx.x;
    int wave = tid >> 6, lane = tid & 63;
    int quad = lane >> 4, l16 = lane & 15;
    int bm = blockIdx.x * 128;
    int base = wave * 16;              // this wave's 16 rows

    __shared__ __align__(16) float mlds[128][66];
    __shared__ int dst_s[128], src_s[128];
    __shared__ float ev_s[128][3];

    // per-wave staging: lanes 0-15 stage this wave's 16 rows (same-wave
    // in-order DS => no barrier needed before this wave reads them)
    if (lane < 16) {
        int i = base + lane;
        dst_s[i] = dsts[bm + i];
        src_s[i] = srcs[bm + i];
        ev_s[i][0] = evs[(long)(bm + i) * 3 + 0];
        ev_s[i][1] = evs[(long)(bm + i) * 3 + 1];
        ev_s[i][2] = evs[(long)(bm + i) * 3 + 2];
    }

    // ---- A fragment ONCE: 16 rbf rows via perm, fp32 -> split hi/lo in regs --
    int e0 = perm[bm + base + l16];
    bf16x8 afh[2], afl[2];             // [ks] — 16 VGPR, pinned
    {
        long ebase = (long)e0 * 64 + quad * 8;
        #pragma unroll
        for (int ks = 0; ks < 2; ks++) {
            float4 ua = *(const float4*)(rbf + ebase + ks * 32);
            float4 ub = *(const float4*)(rbf + ebase + ks * 32 + 4);
            float vv[8] = {ua.x, ua.y, ua.z, ua.w, ub.x, ub.y, ub.z, ub.w};
            bf16x8 hh, ll;
            #pragma unroll
            for (int j = 0; j < 8; j++) {
                short hb = f2b(vv[j]);
                hh[j] = hb;
                ll[j] = f2b(vv[j] - b2f(hb));
            }
            afh[ks] = hh;
            afl[ks] = ll;
        }
    }

    for (int sec = 0; sec < 3; sec++) {
        for (int tile = 0; tile < 4; tile++) {
            int bn = sec * 256 + tile * 64;
            // ---- MFMA round: m[base..base+15, bn..bn+63] ----
            f32x4 acc[4];
            #pragma unroll
            for (int t = 0; t < 4; t++) {
                float bv = b_rbf[bn + t * 16 + l16];
                acc[t] = (f32x4){bv, bv, bv, bv};
                #pragma unroll
                for (int ks = 0; ks < 2; ks++) {
                    long wo = (long)(bn + t * 16 + l16) * 64 + ks * 32 + quad * 8;
                    bf16x8 bh = *(const bf16x8*)(Wrh + wo);
                    bf16x8 bl = *(const bf16x8*)(Wrl + wo);
                    acc[t] = __builtin_amdgcn_mfma_f32_16x16x32_bf16(afh[ks], bh, acc[t], 0, 0, 0);
                    acc[t] = __builtin_amdgcn_mfma_f32_16x16x32_bf16(afl[ks], bh, acc[t], 0, 0, 0);
                    acc[t] = __builtin_amdgcn_mfma_f32_16x16x32_bf16(afh[ks], bl, acc[t], 0, 0, 0);
                }
            }
            // write this wave's 16 rows (only this wave reads them back)
            #pragma unroll
            for (int t = 0; t < 4; t++)
                #pragma unroll
                for (int r = 0; r < 4; r++)
                    mlds[base + quad * 4 + r][t * 16 + l16] = acc[t][r];

            // ---- consume: wave owns its 16 rows; lane owns one column ----
            int colx = tile * 64 + lane;          // 0..255 within section
            if (sec == 0) {
                float a = 0.f;
                int dprev = dst_s[base];
                #pragma unroll 4
                for (int i = 0; i < 16; i++) {
                    int d = dst_s[base + i];
                    if (d != dprev) {
                        atomicAdd(&x1[(long)dprev * 256 + colx], a);
                        a = 0.f;
                        dprev = d;
                    }
                    long xb = (long)src_s[base + i] * 768;
                    a += mlds[base + i][lane] * xh[xb + colx];
                }
                atomicAdd(&x1[(long)dprev * 256 + colx], a);
            } else if (sec == 1) {
                float a0 = 0.f, a1 = 0.f, a2 = 0.f;
                int dprev = dst_s[base];
                #pragma unroll 4
                for (int i = 0; i < 16; i++) {
                    int d = dst_s[base + i];
                    if (d != dprev) {
                        long vb = (long)dprev * 768 + colx;
                        atomicAdd(&vecacc[vb], a0);
                        atomicAdd(&vecacc[vb + 256], a1);
                        atomicAdd(&vecacc[vb + 512], a2);
                        a0 = a1 = a2 = 0.f;
                        dprev = d;
                    }
                    long xb = (long)src_s[base + i] * 768;
                    float m2 = mlds[base + i][lane] * (INV_SQRT_3f * INV_SQRT_Hf) *
                               xh[xb + 256 + colx];
                    a0 += vec[xb + colx] * m2;
                    a1 += vec[xb + 256 + colx] * m2;
                    a2 += vec[xb + 512 + colx] * m2;
                }
                long vb = (long)dprev * 768 + colx;
                atomicAdd(&vecacc[vb], a0);
                atomicAdd(&vecacc[vb + 256], a1);
                atomicAdd(&vecacc[vb + 512], a2);
            } else {
                float a0 = 0.f, a1 = 0.f, a2 = 0.f;
                int dprev = dst_s[base];
                #pragma unroll 4
                for (int i = 0; i < 16; i++) {
                    int d = dst_s[base + i];
                    if (d != dprev) {
                        long vb = (long)dprev * 768 + colx;
                        atomicAdd(&vecacc[vb], a0);
                        atomicAdd(&vecacc[vb + 256], a1);
                        atomicAdd(&vecacc[vb + 512], a2);
                        a0 = a1 = a2 = 0.f;
                        dprev = d;
                    }
                    long xb = (long)src_s[base + i] * 768;
                    float m3 = mlds[base + i][lane] * INV_SQRT_Hf * xh[xb + 512 + colx];
                    a0 += m3 * ev_s[base + i][0];
                    a1 += m3 * ev_s[base + i][1];
                    a2 += m3 * ev_s[base + i][2];
                }
                long vb = (long)dprev * 768 + colx;
                atomicAdd(&vecacc[vb], a0);
                atomicAdd(&vecacc[vb + 256], a1);
                atomicAdd(&vecacc[vb + 512], a2);
            }
        }
    }
}

// ---------------- vec_dot + vnorm + cat(x, vnorm), split out ----------------
__global__ void __launch_bounds__(256) vdot_cat_kernel(const float* __restrict__ vec1,
                                                       const short* __restrict__ vec2,
                                                       const float* __restrict__ x1,
                                                       float* __restrict__ vdot,
                                                       short* __restrict__ cath,
                                                       short* __restrict__ catl) {
    int idx = blockIdx.x * 256 + threadIdx.x;
    int n = idx >> 8, h = idx & 255;
    float dsum = 0.f, s2 = 0.f;
    #pragma unroll
    for (int d = 0; d < 3; d++) {
        long r = (long)(n * 3 + d) * 256 + h;
        float a = vec1[r];
        float b = b2f(vec2[r]);
        dsum += a * b;
        s2 += b * b;
    }
    vdot[idx] = dsum * INV_SQRT_Hf;
    float xv = x1[idx];
    short hh = f2b(xv);
    cath[(long)n * 512 + h] = hh;
    catl[(long)n * 512 + h] = f2b(xv - b2f(hh));
    float vn = sqrtf(s2 + 1e-8f);
    short vh = f2b(vn);
    cath[(long)n * 512 + 256 + h] = vh;
    catl[(long)n * 512 + 256 + h] = f2b(vn - b2f(vh));
}

// ---------------- x/vec update after xv MLP (IN-PLACE) ----------------
__global__ void __launch_bounds__(256) e4_kernel(float* __restrict__ x1,
                                                 float* __restrict__ vecacc,
                                                 const float* __restrict__ vec1,
                                                 const float* __restrict__ vdot,
                                                 const short* __restrict__ xvh_h,
                                                 const short* __restrict__ xvh_l) {
    int idx = blockIdx.x * 256 + threadIdx.x;
    int n = idx >> 8, h = idx & 255;
    long b0 = (long)n * 768 + h;
    float xv1 = b2f(xvh_h[b0])       + b2f(xvh_l[b0]);
    float xv2 = b2f(xvh_h[b0 + 256]) + b2f(xvh_l[b0 + 256]);
    float xv3 = b2f(xvh_h[b0 + 512]) + b2f(xvh_l[b0 + 512]);
    x1[idx] = x1[idx] + (xv1 + xv2 * vdot[idx]) * INV_SQRT_2f;
    #pragma unroll
    for (int d = 0; d < 3; d++) {
        long r = (long)(n * 3 + d) * 256 + h;
        vecacc[r] = vecacc[r] + xv3 * vec1[r];
    }
}

// ---------------- norm over d + concat(x fp32, norm), split out ----------------
__global__ void __launch_bounds__(256) normcat_kernel(const float* __restrict__ xin,
                                                      const short* __restrict__ w,
                                                      short* __restrict__ cath,
                                                      short* __restrict__ catl,
                                                      int Cx, int C, int shift) {
    int idx = blockIdx.x * 256 + threadIdx.x;
    int cols = 1 << shift;
    int n = idx >> shift, c = idx & (cols - 1);
    float v;
    if (c < Cx) {
        v = xin[(long)n * Cx + c];
    } else {
        int cc = c - Cx;
        float s = 0.f;
        #pragma unroll
        for (int d = 0; d < 3; d++) {
            float a = b2f(w[(long)(n * 3 + d) * C + cc]);
            s += a * a;
        }
        v = sqrtf(s);
    }
    short hh = f2b(v);
    cath[idx] = hh;
    catl[idx] = f2b(v - b2f(hh));
}

// ---------------- gated block 1 epilogue ----------------
__global__ void __launch_bounds__(256) gate1_kernel(const float* __restrict__ h1,
                                                    const short* __restrict__ w2h,
                                                    const short* __restrict__ w2l,
                                                    float* __restrict__ x3,
                                                    short* __restrict__ vecCh,
                                                    short* __restrict__ vecCl) {
    int idx = blockIdx.x * 256 + threadIdx.x;
    int n = idx >> 7, c = idx & 127;
    x3[idx] = ssilu_f(h1[(long)n * 256 + c]);
    float vn = h1[(long)n * 256 + 128 + c];
    #pragma unroll
    for (int d = 0; d < 3; d++) {
        long r = (long)(n * 3 + d) * 128 + c;
        float wv = b2f(w2h[r]) + b2f(w2l[r]);
        float v = vn * wv;
        short hh = f2b(v);
        vecCh[r] = hh;
        vecCl[r] = f2b(v - b2f(hh));
    }
}

// ---------------- vecC @ o2_Wv2 (K=128, Nc=1): one wave per row ----------------
__global__ void __launch_bounds__(256) g12_kernel(const short* __restrict__ vecCh,
                                                  const short* __restrict__ vecCl,
                                                  const float* __restrict__ Wv2,
                                                  float* __restrict__ w4) {
    int row = blockIdx.x * 4 + (threadIdx.x >> 6);
    int lane = threadIdx.x & 63;
    long r0 = (long)row * 128 + lane;
    float v0 = b2f(vecCh[r0]) + b2f(vecCl[r0]);
    float v1 = b2f(vecCh[r0 + 64]) + b2f(vecCl[r0 + 64]);
    float s = v0 * Wv2[lane] + v1 * Wv2[64 + lane];
    #pragma unroll
    for (int off = 32; off > 0; off >>= 1) s += __shfl_down(s, off);
    if (lane == 0) w4[row] = s;
}

// ---------------- final: out[n,d] = (t5[n,:]@Wu2[:,1] + b2[1]) * w4[n,d] ----------
__global__ void __launch_bounds__(256) final_kernel(const float* __restrict__ t5,
                                                    const float* __restrict__ Wu2,
                                                    const float* __restrict__ bu2,
                                                    const float* __restrict__ w4,
                                                    float* __restrict__ out) {
    int n = blockIdx.x * 4 + (threadIdx.x >> 6);
    int lane = threadIdx.x & 63;
    float s = t5[(long)n * 128 + lane] * Wu2[lane * 2 + 1] +
              t5[(long)n * 128 + 64 + lane] * Wu2[(64 + lane) * 2 + 1];
    #pragma unroll
    for (int off = 32; off > 0; off >>= 1) s += __shfl_down(s, off);
    float val = __shfl(s, 0) + bu2[1];
    if (lane < 3) out[(long)n * 3 + lane] = val * w4[(long)n * 3 + lane];
}

extern "C" void kernel_launch(void* const* d_in, const int* in_sizes, int n_in,
                              void* d_out, int out_size, void* d_ws, size_t ws_size,
                              hipStream_t stream) {
    const float* x          = (const float*)d_in[0];
    const float* vec        = (const float*)d_in[1];
    const float* edge_rbf   = (const float*)d_in[2];
    const float* edge_vector= (const float*)d_in[3];
    const float* ln_g       = (const float*)d_in[4];
    const float* ln_b       = (const float*)d_in[5];
    const float* W_x1       = (const float*)d_in[6];
    const float* b_x1       = (const float*)d_in[7];
    const float* W_x2       = (const float*)d_in[8];
    const float* b_x2       = (const float*)d_in[9];
    const float* W_rbf      = (const float*)d_in[10];
    const float* b_rbf      = (const float*)d_in[11];
    const float* W_vp       = (const float*)d_in[12];
    const float* W_xv1      = (const float*)d_in[13];
    const float* b_xv1      = (const float*)d_in[14];
    const float* W_xv2      = (const float*)d_in[15];
    const float* b_xv2      = (const float*)d_in[16];
    const float* o1_Wv1     = (const float*)d_in[17];
    const float* o1_Wv2     = (const float*)d_in[18];
    const float* o1_Wu1     = (const float*)d_in[19];
    const float* o1_bu1     = (const float*)d_in[20];
    const float* o1_Wu2     = (const float*)d_in[21];
    const float* o1_bu2     = (const float*)d_in[22];
    const float* o2_Wv1     = (const float*)d_in[23];
    const float* o2_Wv2     = (const float*)d_in[24];
    const float* o2_Wu1     = (const float*)d_in[25];
    const float* o2_bu1     = (const float*)d_in[26];
    const float* o2_Wu2     = (const float*)d_in[27];
    const float* o2_bu2     = (const float*)d_in[28];
    const int*   edge_index = (const int*)d_in[29];
    float* out = (float*)d_out;
    float* ws  = (float*)d_ws;

    const size_t S = (size_t)NN * 256;
    const size_t Q = S / 4;              // 1,048,576 floats = 4 MiB
    // ---- arena in units of Q; peak 52Q = 208 MiB (proven safe) ----
    float* x1      = ws;                     // Q0-3   (fp32 S)
    float* vecacc  = ws + 4 * Q;             // Q4-15  (fp32 3S)
    short* wtb     = (short*)(ws + 16 * Q);  // Q16-17 weights hi + lo
    const long WLO = 1114112;
    // phase 1
    short* xln_h = (short*)(ws + 18 * Q);    // Q18-19 (dead after t1 gemm)
    short* xln_l = (short*)(ws + 20 * Q);    // Q20-21
    short* t1_h  = (short*)(ws + 22 * Q);    // Q22-23 (dead after xh gemm)
    short* t1_l  = (short*)(ws + 24 * Q);    // Q24-25
    float* xh    = ws + 30 * Q;              // Q30-41 (fp32 3S, dead after gather)
    // phase 2 sort scratch (dead before vdot is written)
    int* rowptr    = (int*)(ws + 48 * Q);    // NN+1
    int* cursor    = rowptr + (NN + 1);      // NN
    int* perm      = cursor + NN;            // EE
    int* dsts      = perm + EE;              // EE
    int* srcs      = dsts + EE;              // EE
    float* evs     = (float*)(srcs + EE);    // 3*EE  (total ~6.4 MB < 16 MB)
    // phase 3 (vah/val_ produced by split4 after edge kernel)
    short* vah   = (short*)(ws + 18 * Q);    // Q18-23 (3S bf16)
    short* val_  = (short*)(ws + 24 * Q);    // Q24-29
    float* vec1  = ws + 30 * Q;              // Q30-41 (fp32 3S, live till e4)
    short* vec2b = (short*)(ws + 42 * Q);    // Q42-47 (bf16 3S)
    float* vdot  = ws + 48 * Q;              // Q48-51 (fp32 S, live till e4)
    short* catb_h = (short*)(ws + 18 * Q);   // Q18-21 (vah dead after vp gemms)
    short* catb_l = (short*)(ws + 22 * Q);   // Q22-25
    short* t2_h  = (short*)(ws + 26 * Q);    // Q26-27
    short* t2_l  = (short*)(ws + 28 * Q);    // Q28-29
    short* xvh_h = (short*)(ws + 18 * Q);    // Q18-23 (catb dead)
    short* xvh_l = (short*)(ws + 42 * Q);    // Q42-47 (vec2 dead)
    // phase 4
    short* vah2  = (short*)(ws + 18 * Q);    // Q18-23
    short* val2  = (short*)(ws + 24 * Q);    // Q24-29
    short* w1b   = (short*)(ws + 30 * Q);    // Q30-35 (bf16 3S)
    short* w2_h  = (short*)(ws + 36 * Q);    // Q36-38
    short* w2_l  = (short*)(ws + 39 * Q);    // Q39-41
    short* cat2_h = (short*)(ws + 42 * Q);   // Q42-45
    short* cat2_l = (short*)(ws + 46 * Q);   // Q46-49
    short* t4_h  = (short*)(ws + 18 * Q);    // Q18-19
    short* t4_l  = (short*)(ws + 20 * Q);    // Q20-21
    float* h1    = ws + 22 * Q;              // Q22-25 (fp32 S)
    float* x3    = ws + 26 * Q;              // Q26-27 (fp32 S/2)
    short* vecC_h = (short*)(ws + 28 * Q);   // Q28-30
    short* vecC_l = (short*)(ws + 31 * Q);   // Q31-33
    // phase 5
    short* w3b   = (short*)(ws + 34 * Q);    // Q34-36
    float* w4    = ws + 37 * Q;              // Q37
    short* cat3_h = (short*)(ws + 38 * Q);   // Q38-39
    short* cat3_l = (short*)(ws + 40 * Q);   // Q40-41
    float* t5    = ws + 42 * Q;              // Q42-43

    // weight hi/lo offsets (shorts)
    short* WT_x1    = wtb;
    short* WT_x2    = wtb + 65536;
    short* WT_vp    = wtb + 262144;
    short* WT_xv1   = wtb + 393216;
    short* WT_xv2   = wtb + 524288;
    short* WT_o1Wv1 = wtb + 720896;
    short* WT_o1Wv2 = wtb + 786432;
    short* WT_o1Wu1 = wtb + 819200;
    short* WT_o1Wu2 = wtb + 950272;
    short* WT_o2Wv1 = wtb + 1015808;
    short* WT_o2Wu1 = wtb + 1032192;
    short* WT_rbf   = wtb + 1064960;         // 768 x 64

    // Phase 0: all weight transposes + splits in one launch (incl. W_rbf^T)
    WtArgs wa;
    const float* wsrc[12] = {W_x1, W_x2, W_vp, W_xv1, W_xv2, o1_Wv1, o1_Wv2,
                             o1_Wu1, o1_Wu2, o2_Wv1, o2_Wu1, W_rbf};
    int wk[12] = {256, 256, 256, 512, 256, 256, 256, 512, 256, 128, 256, 64};
    int wn[12] = {256, 768, 512, 256, 768, 256, 128, 256, 256, 128, 128, 768};
    int off = 0;
    for (int i = 0; i < 12; i++) {
        wa.W[i] = wsrc[i]; wa.K[i] = wk[i]; wa.N[i] = wn[i];
        wa.off[i] = off; off += wk[i] * wn[i];
    }
    wa.off[12] = off;  // 1,114,112
    wt_split_all<<<off / 256, 256, 0, stream>>>(wa, wtb, wtb + WLO);

    // init vec accumulation target (x1 = x is folded into ln_kernel)
    hipMemcpyAsync(vecacc, vec, 3 * S * sizeof(float), hipMemcpyDeviceToDevice, stream);

    // Phase 1: node MLP (+ x1 init)
    ln_kernel<<<NN, 256, 0, stream>>>(x, ln_g, ln_b, xln_h, xln_l, x1);
    mfma_gemm<<<dim3(NN / 128, 4), 256, 0, stream>>>(xln_h, xln_l, WT_x1, WT_x1 + WLO,
                                                     b_x1, t1_h, t1_l, NN, 256, 256, 1);
    mfma_gemm<<<dim3(NN / 128, 12), 256, 0, stream>>>(t1_h, t1_l, WT_x2, WT_x2 + WLO,
                                                      b_x2, xh, nullptr, NN, 256, 768, 0);

    // Phase 2: sort edges by dst; edge-parallel fused gather (atomics)
    zero_kernel<<<(NN + 255) / 256, 256, 0, stream>>>(cursor, NN);
    hist_kernel<<<EE / 256, 256, 0, stream>>>(edge_index, cursor);
    scan_kernel<<<1, 256, 0, stream>>>(cursor, rowptr);
    scatter_kernel<<<EE / 256, 256, 0, stream>>>(edge_index, edge_vector, cursor,
                                                 perm, dsts, srcs, evs);
    edge_gather_kernel<<<EE / 128, 512, 0, stream>>>(
        edge_rbf, WT_rbf, WT_rbf + WLO, b_rbf, xh, vec,
        perm, dsts, srcs, evs, x1, vecacc);
    // hi/lo split of vecacc for the phase-3 GEMMs
    split4_kernel<<<3 * S / 1024, 256, 0, stream>>>(vecacc, vah, val_);

    // Phase 3: vp, vdot/vnorm, xv MLP, in-place updates
    mfma_gemm<<<dim3(3 * NN / 128, 4), 256, 0, stream>>>(vah, val_, WT_vp, WT_vp + WLO,
                                                         nullptr, vec1, nullptr,
                                                         3 * NN, 256, 256, 0);
    mfma_gemm<<<dim3(3 * NN / 128, 4), 256, 0, stream>>>(vah, val_, WT_vp + 65536,
                                                         WT_vp + WLO + 65536,
                                                         nullptr, vec2b, nullptr,
                                                         3 * NN, 256, 256, 2);
    vdot_cat_kernel<<<NN, 256, 0, stream>>>(vec1, vec2b, x1, vdot, catb_h, catb_l);
    mfma_gemm<<<dim3(NN / 128, 4), 256, 0, stream>>>(catb_h, catb_l, WT_xv1, WT_xv1 + WLO,
                                                     b_xv1, t2_h, t2_l, NN, 512, 256, 1);
    mfma_gemm<<<dim3(NN / 128, 12), 256, 0, stream>>>(t2_h, t2_l, WT_xv2, WT_xv2 + WLO,
                                                      b_xv2, xvh_h, xvh_l, NN, 256, 768, 0);
    e4_kernel<<<NN, 256, 0, stream>>>(x1, vecacc, vec1, vdot, xvh_h, xvh_l);

    // Phase 4: gated equivariant block 1
    split4_kernel<<<3 * S / 1024, 256, 0, stream>>>(vecacc, vah2, val2);
    mfma_gemm<<<dim3(3 * NN / 128, 4), 256, 0, stream>>>(vah2, val2, WT_o1Wv1, WT_o1Wv1 + WLO,
                                                         nullptr, w1b, nullptr,
                                                         3 * NN, 256, 256, 2);
    mfma_gemm<<<dim3(3 * NN / 128, 2), 256, 0, stream>>>(vah2, val2, WT_o1Wv2, WT_o1Wv2 + WLO,
                                                         nullptr, w2_h, w2_l,
                                                         3 * NN, 256, 128, 0);
    normcat_kernel<<<NN * 512 / 256, 256, 0, stream>>>(x1, w1b, cat2_h, cat2_l, 256, 256, 9);
    mfma_gemm<<<dim3(NN / 128, 4), 256, 0, stream>>>(cat2_h, cat2_l, WT_o1Wu1, WT_o1Wu1 + WLO,
                                                     o1_bu1, t4_h, t4_l, NN, 512, 256, 1);
    mfma_gemm<<<dim3(NN / 128, 4), 256, 0, stream>>>(t4_h, t4_l, WT_o1Wu2, WT_o1Wu2 + WLO,
                                                     o1_bu2, h1, nullptr, NN, 256, 256, 0);
    gate1_kernel<<<NN * 128 / 256, 256, 0, stream>>>(h1, w2_h, w2_l, x3, vecC_h, vecC_l);

    // Phase 5: gated equivariant block 2 + output
    mfma_gemm<<<dim3(3 * NN / 128, 2), 256, 0, stream>>>(vecC_h, vecC_l, WT_o2Wv1,
                                                         WT_o2Wv1 + WLO, nullptr,
                                                         w3b, nullptr, 3 * NN, 128, 128, 2);
    g12_kernel<<<3 * NN / 4, 256, 0, stream>>>(vecC_h, vecC_l, o2_Wv2, w4);
    normcat_kernel<<<NN * 256 / 256, 256, 0, stream>>>(x3, w3b, cat3_h, cat3_l, 128, 128, 8);
    mfma_gemm<<<dim3(NN / 128, 2), 256, 0, stream>>>(cat3_h, cat3_l, WT_o2Wu1, WT_o2Wu1 + WLO,
                                                     o2_bu1, t5, nullptr, NN, 256, 128, 1);
    final_kernel<<<NN / 4, 256, 0, stream>>>(t5, o2_Wu2, o2_bu2, w4, out);
}

// Round 7
// 1458.807 us; speedup vs baseline: 1.8115x; 1.0140x over previous
//
#include <hip/hip_runtime.h>
#include <math.h>

#define NN 16384
#define EE 262144
#define HH 256

#define INV_SQRT_3f 0.57735026918962576f
#define INV_SQRT_Hf 0.0625f
#define INV_SQRT_2f 0.70710678118654752f
#define SSILU_SCALE 1.6666666666666667f

typedef __attribute__((ext_vector_type(8))) short bf16x8;
typedef __attribute__((ext_vector_type(4))) float f32x4;

__device__ __forceinline__ float ssilu_f(float v) {
    return v * (1.0f / (1.0f + __expf(-v))) * SSILU_SCALE;
}
__device__ __forceinline__ float b2f(short s) {
    unsigned int u = ((unsigned int)(unsigned short)s) << 16;
    return __uint_as_float(u);
}
__device__ __forceinline__ short f2b(float f) {
    unsigned int u = __float_as_uint(f);
    unsigned int r = (u + 0x7fff + ((u >> 16) & 1)) >> 16;
    return (short)r;
}

// ---------------- LayerNorm: one block per row, split-bf16 out ----------------
// also initializes x1 = x (folds away the 128MB-traffic D2D memcpy)
__global__ void __launch_bounds__(256) ln_kernel(const float* __restrict__ x,
                                                 const float* __restrict__ g,
                                                 const float* __restrict__ b,
                                                 short* __restrict__ oh,
                                                 short* __restrict__ ol,
                                                 float* __restrict__ x1) {
    int n = blockIdx.x;
    int t = threadIdx.x;
    float v = x[(long)n * HH + t];
    x1[(long)n * HH + t] = v;
    float s = v, s2 = v * v;
    #pragma unroll
    for (int off = 32; off > 0; off >>= 1) {
        s  += __shfl_down(s, off);
        s2 += __shfl_down(s2, off);
    }
    __shared__ float red[8];
    int wave = t >> 6, lane = t & 63;
    if (lane == 0) { red[wave] = s; red[4 + wave] = s2; }
    __syncthreads();
    __shared__ float mr[2];
    if (t == 0) {
        float ts = red[0] + red[1] + red[2] + red[3];
        float ts2 = red[4] + red[5] + red[6] + red[7];
        float mean = ts * (1.0f / HH);
        float var = ts2 * (1.0f / HH) - mean * mean;
        mr[0] = mean;
        mr[1] = rsqrtf(var + 1e-5f);
    }
    __syncthreads();
    float o = (v - mr[0]) * mr[1] * g[t] + b[t];
    short hh = f2b(o);
    oh[(long)n * HH + t] = hh;
    ol[(long)n * HH + t] = f2b(o - b2f(hh));
}

// ---- ALL weight transposes + hi/lo splits in ONE kernel (incl. W_rbf) ----
struct WtArgs {
    const float* W[12];
    int K[12];
    int N[12];
    int off[13];   // cumulative element offsets; off[12] = total
};

__global__ void __launch_bounds__(256) wt_split_all(WtArgs a,
                                                    short* __restrict__ WTh,
                                                    short* __restrict__ WTl) {
    int idx = blockIdx.x * 256 + threadIdx.x;
    int s = 0;
    #pragma unroll
    for (int i = 1; i < 12; i++) s += (idx >= a.off[i]) ? 1 : 0;
    int local = idx - a.off[s];
    int K = a.K[s], N = a.N[s];
    int k = local / N, n = local - k * N;
    float w = a.W[s][local];
    short hh = f2b(w);
    long o = (long)a.off[s] + (long)n * K + k;
    WTh[o] = hh;
    WTl[o] = f2b(w - b2f(hh));
}

// ---- fp32 -> hi/lo split (count % 1024 == 0) ----
__global__ void __launch_bounds__(256) split4_kernel(const float* __restrict__ in,
                                                     short* __restrict__ h,
                                                     short* __restrict__ l) {
    long i = ((long)blockIdx.x * 256 + threadIdx.x) * 4;
    float4 v = *(const float4*)(in + i);
    short4 oh, ol;
    oh.x = f2b(v.x); ol.x = f2b(v.x - b2f(oh.x));
    oh.y = f2b(v.y); ol.y = f2b(v.y - b2f(oh.y));
    oh.z = f2b(v.z); ol.z = f2b(v.z - b2f(oh.z));
    oh.w = f2b(v.w); ol.w = f2b(v.w - b2f(oh.w));
    *(short4*)(h + i) = oh;
    *(short4*)(l + i) = ol;
}

// ---- split-bf16 MFMA GEMM v2: C = (Ah+Al)(M,K) @ (Wh+Wl)^T(N,K) [+bias][ssilu]
__global__ void __launch_bounds__(256) mfma_gemm(const short* __restrict__ Ah,
                                                 const short* __restrict__ Al,
                                                 const short* __restrict__ Wh,
                                                 const short* __restrict__ Wl,
                                                 const float* __restrict__ bias,
                                                 void* __restrict__ Ch,
                                                 short* __restrict__ Cl,
                                                 int M, int K, int N, int act) {
    int tid = threadIdx.x;
    int wave = tid >> 6, lane = tid & 63;
    int quad = lane >> 4, l16 = lane & 15;
    long bm = (long)blockIdx.x * 128 + wave * 32;
    long bn = (long)blockIdx.y * 64;
    long a0 = (bm + l16) * K + quad * 8;
    long a1 = a0 + (long)16 * K;
    long w0 = (bn + l16) * K + quad * 8;

    f32x4 acc[2][4];
    #pragma unroll
    for (int f = 0; f < 2; f++)
        #pragma unroll
        for (int t = 0; t < 4; t++) acc[f][t] = (f32x4){0.f, 0.f, 0.f, 0.f};

    bf16x8 cah[2], cal[2], cbh[4], cbl[4];
    cah[0] = *(const bf16x8*)(Ah + a0);
    cah[1] = *(const bf16x8*)(Ah + a1);
    cal[0] = *(const bf16x8*)(Al + a0);
    cal[1] = *(const bf16x8*)(Al + a1);
    #pragma unroll
    for (int t = 0; t < 4; t++) {
        long wo = w0 + (long)t * 16 * K;
        cbh[t] = *(const bf16x8*)(Wh + wo);
        cbl[t] = *(const bf16x8*)(Wl + wo);
    }

    for (int k0 = 0; k0 < K; k0 += 32) {
        int k1 = k0 + 32;
        bf16x8 nah[2], nal[2], nbh[4], nbl[4];
        if (k1 < K) {
            nah[0] = *(const bf16x8*)(Ah + a0 + k1);
            nah[1] = *(const bf16x8*)(Ah + a1 + k1);
            nal[0] = *(const bf16x8*)(Al + a0 + k1);
            nal[1] = *(const bf16x8*)(Al + a1 + k1);
            #pragma unroll
            for (int t = 0; t < 4; t++) {
                long wo = w0 + (long)t * 16 * K + k1;
                nbh[t] = *(const bf16x8*)(Wh + wo);
                nbl[t] = *(const bf16x8*)(Wl + wo);
            }
        }
        #pragma unroll
        for (int t = 0; t < 4; t++) {
            #pragma unroll
            for (int f = 0; f < 2; f++) {
                acc[f][t] = __builtin_amdgcn_mfma_f32_16x16x32_bf16(cah[f], cbh[t], acc[f][t], 0, 0, 0);
                acc[f][t] = __builtin_amdgcn_mfma_f32_16x16x32_bf16(cal[f], cbh[t], acc[f][t], 0, 0, 0);
                acc[f][t] = __builtin_amdgcn_mfma_f32_16x16x32_bf16(cah[f], cbl[t], acc[f][t], 0, 0, 0);
            }
        }
        if (k1 < K) {
            cah[0] = nah[0]; cah[1] = nah[1];
            cal[0] = nal[0]; cal[1] = nal[1];
            #pragma unroll
            for (int t = 0; t < 4; t++) { cbh[t] = nbh[t]; cbl[t] = nbl[t]; }
        }
    }

    #pragma unroll
    for (int f = 0; f < 2; f++) {
        long row0 = bm + f * 16 + quad * 4;
        #pragma unroll
        for (int t = 0; t < 4; t++) {
            long col = bn + t * 16 + l16;
            float bv = bias ? bias[col] : 0.f;
            #pragma unroll
            for (int r = 0; r < 4; r++) {
                float v = acc[f][t][r] + bv;
                if (act & 1) v = ssilu_f(v);
                long idx = (row0 + r) * N + col;
                if (Cl) {
                    short hh = f2b(v);
                    ((short*)Ch)[idx] = hh;
                    Cl[idx] = f2b(v - b2f(hh));
                } else if (act & 2) {
                    ((short*)Ch)[idx] = f2b(v);
                } else {
                    ((float*)Ch)[idx] = v;
                }
            }
        }
    }
}

// ---------------- edge sort (counting sort by dst) ----------------
__global__ void __launch_bounds__(256) zero_kernel(int* __restrict__ p, int n) {
    int i = blockIdx.x * 256 + threadIdx.x;
    if (i < n) p[i] = 0;
}

__global__ void __launch_bounds__(256) hist_kernel(const int* __restrict__ eidx,
                                                   int* __restrict__ cnt) {
    int e = blockIdx.x * 256 + threadIdx.x;
    atomicAdd(&cnt[eidx[EE + e]], 1);
}

__global__ void __launch_bounds__(256) scan_kernel(int* __restrict__ cursor,
                                                   int* __restrict__ rowptr) {
    int t = threadIdx.x;
    int base_i = t * 64;
    int tsum = 0;
    for (int i = 0; i < 64; i++) tsum += cursor[base_i + i];
    __shared__ int ls[256];
    ls[t] = tsum;
    __syncthreads();
    for (int off = 1; off < 256; off <<= 1) {
        int v = (t >= off) ? ls[t - off] : 0;
        __syncthreads();
        ls[t] += v;
        __syncthreads();
    }
    int running = ls[t] - tsum;
    for (int i = 0; i < 64; i++) {
        int c = cursor[base_i + i];
        rowptr[base_i + i] = running;
        cursor[base_i + i] = running;
        running += c;
    }
    if (t == 255) rowptr[NN] = running;
}

// scatter: also materialize dst/src/ev in sorted order for the edge kernel
__global__ void __launch_bounds__(256) scatter_kernel(const int* __restrict__ eidx,
                                                      const float* __restrict__ ev,
                                                      int* __restrict__ cursor,
                                                      int* __restrict__ perm,
                                                      int* __restrict__ dsts,
                                                      int* __restrict__ srcs,
                                                      float* __restrict__ evs) {
    int e = blockIdx.x * 256 + threadIdx.x;
    int s_ = eidx[e];
    int d_ = eidx[EE + e];
    int pos = atomicAdd(&cursor[d_], 1);
    perm[pos] = e;
    dsts[pos] = d_;
    srcs[pos] = s_;
    evs[pos * 3 + 0] = ev[e * 3 + 0];
    evs[pos * 3 + 1] = ev[e * 3 + 1];
    evs[pos * 3 + 2] = ev[e * 3 + 2];
}

// ---------------- Edge-parallel fused rbf-GEMM + gather + atomic reduce -------
// v5: consume loops restructured for MEMORY-LEVEL PARALLELISM. Round-6 showed
// 90% occupancy with all pipes idle and VGPR=32: the branchy run-accumulate
// loop forced the compiler to issue each gather load right before its use
// (MLP ~1-2). Fix: per tile, a branch-free unrolled batch loop computes each
// row's contribution into registers (16 independent loads in flight; sec1 in
// 4-row batches of 16 loads), THEN the branchy run-accumulate runs over
// registers. Same math, same in-run order, same atomics.
__global__ void __launch_bounds__(512) edge_gather_kernel(
        const float* __restrict__ rbf,
        const short* __restrict__ Wrh,
        const short* __restrict__ Wrl,
        const float* __restrict__ b_rbf,
        const float* __restrict__ xh,
        const float* __restrict__ vec,
        const int* __restrict__ perm,
        const int* __restrict__ dsts,
        const int* __restrict__ srcs,
        const float* __restrict__ evs,
        float* __restrict__ x1,
        float* __restrict__ vecacc) {
    int tid = threadIdx.x;
    int wave = tid >> 6, lane = tid & 63;
    int quad = lane >> 4, l16 = lane & 15;
    int bm = blockIdx.x * 128;
    int base = wave * 16;              // this wave's 16 rows

    __shared__ __align__(16) float mlds[128][66];
    __shared__ int dst_s[128], src_s[128];
    __shared__ float ev_s[128][3];

    // per-wave staging: lanes 0-15 stage this wave's 16 rows (same-wave
    // in-order DS => no barrier needed before this wave reads them)
    if (lane < 16) {
        int i = base + lane;
        dst_s[i] = dsts[bm + i];
        src_s[i] = srcs[bm + i];
        ev_s[i][0] = evs[(long)(bm + i) * 3 + 0];
        ev_s[i][1] = evs[(long)(bm + i) * 3 + 1];
        ev_s[i][2] = evs[(long)(bm + i) * 3 + 2];
    }

    // ---- A fragment ONCE: 16 rbf rows via perm, fp32 -> split hi/lo in regs --
    int e0 = perm[bm + base + l16];
    bf16x8 afh[2], afl[2];             // [ks] — 16 VGPR, pinned
    {
        long ebase = (long)e0 * 64 + quad * 8;
        #pragma unroll
        for (int ks = 0; ks < 2; ks++) {
            float4 ua = *(const float4*)(rbf + ebase + ks * 32);
            float4 ub = *(const float4*)(rbf + ebase + ks * 32 + 4);
            float vv[8] = {ua.x, ua.y, ua.z, ua.w, ub.x, ub.y, ub.z, ub.w};
            bf16x8 hh, ll;
            #pragma unroll
            for (int j = 0; j < 8; j++) {
                short hb = f2b(vv[j]);
                hh[j] = hb;
                ll[j] = f2b(vv[j] - b2f(hb));
            }
            afh[ks] = hh;
            afl[ks] = ll;
        }
    }

    for (int sec = 0; sec < 3; sec++) {
        for (int tile = 0; tile < 4; tile++) {
            int bn = sec * 256 + tile * 64;
            // ---- MFMA round: m[base..base+15, bn..bn+63] ----
            f32x4 acc[4];
            #pragma unroll
            for (int t = 0; t < 4; t++) {
                float bv = b_rbf[bn + t * 16 + l16];
                acc[t] = (f32x4){bv, bv, bv, bv};
                #pragma unroll
                for (int ks = 0; ks < 2; ks++) {
                    long wo = (long)(bn + t * 16 + l16) * 64 + ks * 32 + quad * 8;
                    bf16x8 bh = *(const bf16x8*)(Wrh + wo);
                    bf16x8 bl = *(const bf16x8*)(Wrl + wo);
                    acc[t] = __builtin_amdgcn_mfma_f32_16x16x32_bf16(afh[ks], bh, acc[t], 0, 0, 0);
                    acc[t] = __builtin_amdgcn_mfma_f32_16x16x32_bf16(afl[ks], bh, acc[t], 0, 0, 0);
                    acc[t] = __builtin_amdgcn_mfma_f32_16x16x32_bf16(afh[ks], bl, acc[t], 0, 0, 0);
                }
            }
            // write this wave's 16 rows (only this wave reads them back)
            #pragma unroll
            for (int t = 0; t < 4; t++)
                #pragma unroll
                for (int r = 0; r < 4; r++)
                    mlds[base + quad * 4 + r][t * 16 + l16] = acc[t][r];

            // ---- consume: wave owns its 16 rows; lane owns one column ----
            int colx = tile * 64 + lane;          // 0..255 within section
            if (sec == 0) {
                // branch-free batch: 16 independent xh loads in flight
                float pv[16];
                #pragma unroll
                for (int i = 0; i < 16; i++) {
                    long xb = (long)src_s[base + i] * 768;
                    pv[i] = mlds[base + i][lane] * xh[xb + colx];
                }
                float a = 0.f;
                int dprev = dst_s[base];
                #pragma unroll
                for (int i = 0; i < 16; i++) {
                    int d = dst_s[base + i];
                    if (d != dprev) {
                        atomicAdd(&x1[(long)dprev * 256 + colx], a);
                        a = 0.f;
                        dprev = d;
                    }
                    a += pv[i];
                }
                atomicAdd(&x1[(long)dprev * 256 + colx], a);
            } else if (sec == 1) {
                float a0 = 0.f, a1 = 0.f, a2 = 0.f;
                int dprev = dst_s[base];
                #pragma unroll 1
                for (int b = 0; b < 4; b++) {
                    // branch-free batch: 16 independent loads (4 rows x 4) in flight
                    float p0[4], p1[4], p2[4];
                    #pragma unroll
                    for (int j = 0; j < 4; j++) {
                        int i = b * 4 + j;
                        long xb = (long)src_s[base + i] * 768;
                        float m2 = mlds[base + i][lane] * (INV_SQRT_3f * INV_SQRT_Hf) *
                                   xh[xb + 256 + colx];
                        p0[j] = vec[xb + colx] * m2;
                        p1[j] = vec[xb + 256 + colx] * m2;
                        p2[j] = vec[xb + 512 + colx] * m2;
                    }
                    #pragma unroll
                    for (int j = 0; j < 4; j++) {
                        int i = b * 4 + j;
                        int d = dst_s[base + i];
                        if (d != dprev) {
                            long vb = (long)dprev * 768 + colx;
                            atomicAdd(&vecacc[vb], a0);
                            atomicAdd(&vecacc[vb + 256], a1);
                            atomicAdd(&vecacc[vb + 512], a2);
                            a0 = a1 = a2 = 0.f;
                            dprev = d;
                        }
                        a0 += p0[j]; a1 += p1[j]; a2 += p2[j];
                    }
                }
                long vb = (long)dprev * 768 + colx;
                atomicAdd(&vecacc[vb], a0);
                atomicAdd(&vecacc[vb + 256], a1);
                atomicAdd(&vecacc[vb + 512], a2);
            } else {
                // branch-free batch: 16 independent xh loads in flight
                float pm[16];
                #pragma unroll
                for (int i = 0; i < 16; i++) {
                    long xb = (long)src_s[base + i] * 768;
                    pm[i] = mlds[base + i][lane] * INV_SQRT_Hf * xh[xb + 512 + colx];
                }
                float a0 = 0.f, a1 = 0.f, a2 = 0.f;
                int dprev = dst_s[base];
                #pragma unroll
                for (int i = 0; i < 16; i++) {
                    int d = dst_s[base + i];
                    if (d != dprev) {
                        long vb = (long)dprev * 768 + colx;
                        atomicAdd(&vecacc[vb], a0);
                        atomicAdd(&vecacc[vb + 256], a1);
                        atomicAdd(&vecacc[vb + 512], a2);
                        a0 = a1 = a2 = 0.f;
                        dprev = d;
                    }
                    a0 += pm[i] * ev_s[base + i][0];
                    a1 += pm[i] * ev_s[base + i][1];
                    a2 += pm[i] * ev_s[base + i][2];
                }
                long vb = (long)dprev * 768 + colx;
                atomicAdd(&vecacc[vb], a0);
                atomicAdd(&vecacc[vb + 256], a1);
                atomicAdd(&vecacc[vb + 512], a2);
            }
        }
    }
}

// ---------------- vec_dot + vnorm + cat(x, vnorm), split out ----------------
__global__ void __launch_bounds__(256) vdot_cat_kernel(const float* __restrict__ vec1,
                                                       const short* __restrict__ vec2,
                                                       const float* __restrict__ x1,
                                                       float* __restrict__ vdot,
                                                       short* __restrict__ cath,
                                                       short* __restrict__ catl) {
    int idx = blockIdx.x * 256 + threadIdx.x;
    int n = idx >> 8, h = idx & 255;
    float dsum = 0.f, s2 = 0.f;
    #pragma unroll
    for (int d = 0; d < 3; d++) {
        long r = (long)(n * 3 + d) * 256 + h;
        float a = vec1[r];
        float b = b2f(vec2[r]);
        dsum += a * b;
        s2 += b * b;
    }
    vdot[idx] = dsum * INV_SQRT_Hf;
    float xv = x1[idx];
    short hh = f2b(xv);
    cath[(long)n * 512 + h] = hh;
    catl[(long)n * 512 + h] = f2b(xv - b2f(hh));
    float vn = sqrtf(s2 + 1e-8f);
    short vh = f2b(vn);
    cath[(long)n * 512 + 256 + h] = vh;
    catl[(long)n * 512 + 256 + h] = f2b(vn - b2f(vh));
}

// ---------------- x/vec update after xv MLP (IN-PLACE) ----------------
__global__ void __launch_bounds__(256) e4_kernel(float* __restrict__ x1,
                                                 float* __restrict__ vecacc,
                                                 const float* __restrict__ vec1,
                                                 const float* __restrict__ vdot,
                                                 const short* __restrict__ xvh_h,
                                                 const short* __restrict__ xvh_l) {
    int idx = blockIdx.x * 256 + threadIdx.x;
    int n = idx >> 8, h = idx & 255;
    long b0 = (long)n * 768 + h;
    float xv1 = b2f(xvh_h[b0])       + b2f(xvh_l[b0]);
    float xv2 = b2f(xvh_h[b0 + 256]) + b2f(xvh_l[b0 + 256]);
    float xv3 = b2f(xvh_h[b0 + 512]) + b2f(xvh_l[b0 + 512]);
    x1[idx] = x1[idx] + (xv1 + xv2 * vdot[idx]) * INV_SQRT_2f;
    #pragma unroll
    for (int d = 0; d < 3; d++) {
        long r = (long)(n * 3 + d) * 256 + h;
        vecacc[r] = vecacc[r] + xv3 * vec1[r];
    }
}

// ---------------- norm over d + concat(x fp32, norm), split out ----------------
__global__ void __launch_bounds__(256) normcat_kernel(const float* __restrict__ xin,
                                                      const short* __restrict__ w,
                                                      short* __restrict__ cath,
                                                      short* __restrict__ catl,
                                                      int Cx, int C, int shift) {
    int idx = blockIdx.x * 256 + threadIdx.x;
    int cols = 1 << shift;
    int n = idx >> shift, c = idx & (cols - 1);
    float v;
    if (c < Cx) {
        v = xin[(long)n * Cx + c];
    } else {
        int cc = c - Cx;
        float s = 0.f;
        #pragma unroll
        for (int d = 0; d < 3; d++) {
            float a = b2f(w[(long)(n * 3 + d) * C + cc]);
            s += a * a;
        }
        v = sqrtf(s);
    }
    short hh = f2b(v);
    cath[idx] = hh;
    catl[idx] = f2b(v - b2f(hh));
}

// ---------------- gated block 1 epilogue ----------------
__global__ void __launch_bounds__(256) gate1_kernel(const float* __restrict__ h1,
                                                    const short* __restrict__ w2h,
                                                    const short* __restrict__ w2l,
                                                    float* __restrict__ x3,
                                                    short* __restrict__ vecCh,
                                                    short* __restrict__ vecCl) {
    int idx = blockIdx.x * 256 + threadIdx.x;
    int n = idx >> 7, c = idx & 127;
    x3[idx] = ssilu_f(h1[(long)n * 256 + c]);
    float vn = h1[(long)n * 256 + 128 + c];
    #pragma unroll
    for (int d = 0; d < 3; d++) {
        long r = (long)(n * 3 + d) * 128 + c;
        float wv = b2f(w2h[r]) + b2f(w2l[r]);
        float v = vn * wv;
        short hh = f2b(v);
        vecCh[r] = hh;
        vecCl[r] = f2b(v - b2f(hh));
    }
}

// ---------------- vecC @ o2_Wv2 (K=128, Nc=1): one wave per row ----------------
__global__ void __launch_bounds__(256) g12_kernel(const short* __restrict__ vecCh,
                                                  const short* __restrict__ vecCl,
                                                  const float* __restrict__ Wv2,
                                                  float* __restrict__ w4) {
    int row = blockIdx.x * 4 + (threadIdx.x >> 6);
    int lane = threadIdx.x & 63;
    long r0 = (long)row * 128 + lane;
    float v0 = b2f(vecCh[r0]) + b2f(vecCl[r0]);
    float v1 = b2f(vecCh[r0 + 64]) + b2f(vecCl[r0 + 64]);
    float s = v0 * Wv2[lane] + v1 * Wv2[64 + lane];
    #pragma unroll
    for (int off = 32; off > 0; off >>= 1) s += __shfl_down(s, off);
    if (lane == 0) w4[row] = s;
}

// ---------------- final: out[n,d] = (t5[n,:]@Wu2[:,1] + b2[1]) * w4[n,d] ----------
__global__ void __launch_bounds__(256) final_kernel(const float* __restrict__ t5,
                                                    const float* __restrict__ Wu2,
                                                    const float* __restrict__ bu2,
                                                    const float* __restrict__ w4,
                                                    float* __restrict__ out) {
    int n = blockIdx.x * 4 + (threadIdx.x >> 6);
    int lane = threadIdx.x & 63;
    float s = t5[(long)n * 128 + lane] * Wu2[lane * 2 + 1] +
              t5[(long)n * 128 + 64 + lane] * Wu2[(64 + lane) * 2 + 1];
    #pragma unroll
    for (int off = 32; off > 0; off >>= 1) s += __shfl_down(s, off);
    float val = __shfl(s, 0) + bu2[1];
    if (lane < 3) out[(long)n * 3 + lane] = val * w4[(long)n * 3 + lane];
}

extern "C" void kernel_launch(void* const* d_in, const int* in_sizes, int n_in,
                              void* d_out, int out_size, void* d_ws, size_t ws_size,
                              hipStream_t stream) {
    const float* x          = (const float*)d_in[0];
    const float* vec        = (const float*)d_in[1];
    const float* edge_rbf   = (const float*)d_in[2];
    const float* edge_vector= (const float*)d_in[3];
    const float* ln_g       = (const float*)d_in[4];
    const float* ln_b       = (const float*)d_in[5];
    const float* W_x1       = (const float*)d_in[6];
    const float* b_x1       = (const float*)d_in[7];
    const float* W_x2       = (const float*)d_in[8];
    const float* b_x2       = (const float*)d_in[9];
    const float* W_rbf      = (const float*)d_in[10];
    const float* b_rbf      = (const float*)d_in[11];
    const float* W_vp       = (const float*)d_in[12];
    const float* W_xv1      = (const float*)d_in[13];
    const float* b_xv1      = (const float*)d_in[14];
    const float* W_xv2      = (const float*)d_in[15];
    const float* b_xv2      = (const float*)d_in[16];
    const float* o1_Wv1     = (const float*)d_in[17];
    const float* o1_Wv2     = (const float*)d_in[18];
    const float* o1_Wu1     = (const float*)d_in[19];
    const float* o1_bu1     = (const float*)d_in[20];
    const float* o1_Wu2     = (const float*)d_in[21];
    const float* o1_bu2     = (const float*)d_in[22];
    const float* o2_Wv1     = (const float*)d_in[23];
    const float* o2_Wv2     = (const float*)d_in[24];
    const float* o2_Wu1     = (const float*)d_in[25];
    const float* o2_bu1     = (const float*)d_in[26];
    const float* o2_Wu2     = (const float*)d_in[27];
    const float* o2_bu2     = (const float*)d_in[28];
    const int*   edge_index = (const int*)d_in[29];
    float* out = (float*)d_out;
    float* ws  = (float*)d_ws;

    const size_t S = (size_t)NN * 256;
    const size_t Q = S / 4;              // 1,048,576 floats = 4 MiB
    // ---- arena in units of Q; peak 52Q = 208 MiB (proven safe) ----
    float* x1      = ws;                     // Q0-3   (fp32 S)
    float* vecacc  = ws + 4 * Q;             // Q4-15  (fp32 3S)
    short* wtb     = (short*)(ws + 16 * Q);  // Q16-17 weights hi + lo
    const long WLO = 1114112;
    // phase 1
    short* xln_h = (short*)(ws + 18 * Q);    // Q18-19 (dead after t1 gemm)
    short* xln_l = (short*)(ws + 20 * Q);    // Q20-21
    short* t1_h  = (short*)(ws + 22 * Q);    // Q22-23 (dead after xh gemm)
    short* t1_l  = (short*)(ws + 24 * Q);    // Q24-25
    float* xh    = ws + 30 * Q;              // Q30-41 (fp32 3S, dead after gather)
    // phase 2 sort scratch (dead before vdot is written)
    int* rowptr    = (int*)(ws + 48 * Q);    // NN+1
    int* cursor    = rowptr + (NN + 1);      // NN
    int* perm      = cursor + NN;            // EE
    int* dsts      = perm + EE;              // EE
    int* srcs      = dsts + EE;              // EE
    float* evs     = (float*)(srcs + EE);    // 3*EE  (total ~6.4 MB < 16 MB)
    // phase 3 (vah/val_ produced by split4 after edge kernel)
    short* vah   = (short*)(ws + 18 * Q);    // Q18-23 (3S bf16)
    short* val_  = (short*)(ws + 24 * Q);    // Q24-29
    float* vec1  = ws + 30 * Q;              // Q30-41 (fp32 3S, live till e4)
    short* vec2b = (short*)(ws + 42 * Q);    // Q42-47 (bf16 3S)
    float* vdot  = ws + 48 * Q;              // Q48-51 (fp32 S, live till e4)
    short* catb_h = (short*)(ws + 18 * Q);   // Q18-21 (vah dead after vp gemms)
    short* catb_l = (short*)(ws + 22 * Q);   // Q22-25
    short* t2_h  = (short*)(ws + 26 * Q);    // Q26-27
    short* t2_l  = (short*)(ws + 28 * Q);    // Q28-29
    short* xvh_h = (short*)(ws + 18 * Q);    // Q18-23 (catb dead)
    short* xvh_l = (short*)(ws + 42 * Q);    // Q42-47 (vec2 dead)
    // phase 4
    short* vah2  = (short*)(ws + 18 * Q);    // Q18-23
    short* val2  = (short*)(ws + 24 * Q);    // Q24-29
    short* w1b   = (short*)(ws + 30 * Q);    // Q30-35 (bf16 3S)
    short* w2_h  = (short*)(ws + 36 * Q);    // Q36-38
    short* w2_l  = (short*)(ws + 39 * Q);    // Q39-41
    short* cat2_h = (short*)(ws + 42 * Q);   // Q42-45
    short* cat2_l = (short*)(ws + 46 * Q);   // Q46-49
    short* t4_h  = (short*)(ws + 18 * Q);    // Q18-19
    short* t4_l  = (short*)(ws + 20 * Q);    // Q20-21
    float* h1    = ws + 22 * Q;              // Q22-25 (fp32 S)
    float* x3    = ws + 26 * Q;              // Q26-27 (fp32 S/2)
    short* vecC_h = (short*)(ws + 28 * Q);   // Q28-30
    short* vecC_l = (short*)(ws + 31 * Q);   // Q31-33
    // phase 5
    short* w3b   = (short*)(ws + 34 * Q);    // Q34-36
    float* w4    = ws + 37 * Q;              // Q37
    short* cat3_h = (short*)(ws + 38 * Q);   // Q38-39
    short* cat3_l = (short*)(ws + 40 * Q);   // Q40-41
    float* t5    = ws + 42 * Q;              // Q42-43

    // weight hi/lo offsets (shorts)
    short* WT_x1    = wtb;
    short* WT_x2    = wtb + 65536;
    short* WT_vp    = wtb + 262144;
    short* WT_xv1   = wtb + 393216;
    short* WT_xv2   = wtb + 524288;
    short* WT_o1Wv1 = wtb + 720896;
    short* WT_o1Wv2 = wtb + 786432;
    short* WT_o1Wu1 = wtb + 819200;
    short* WT_o1Wu2 = wtb + 950272;
    short* WT_o2Wv1 = wtb + 1015808;
    short* WT_o2Wu1 = wtb + 1032192;
    short* WT_rbf   = wtb + 1064960;         // 768 x 64

    // Phase 0: all weight transposes + splits in one launch (incl. W_rbf^T)
    WtArgs wa;
    const float* wsrc[12] = {W_x1, W_x2, W_vp, W_xv1, W_xv2, o1_Wv1, o1_Wv2,
                             o1_Wu1, o1_Wu2, o2_Wv1, o2_Wu1, W_rbf};
    int wk[12] = {256, 256, 256, 512, 256, 256, 256, 512, 256, 128, 256, 64};
    int wn[12] = {256, 768, 512, 256, 768, 256, 128, 256, 256, 128, 128, 768};
    int off = 0;
    for (int i = 0; i < 12; i++) {
        wa.W[i] = wsrc[i]; wa.K[i] = wk[i]; wa.N[i] = wn[i];
        wa.off[i] = off; off += wk[i] * wn[i];
    }
    wa.off[12] = off;  // 1,114,112
    wt_split_all<<<off / 256, 256, 0, stream>>>(wa, wtb, wtb + WLO);

    // init vec accumulation target (x1 = x is folded into ln_kernel)
    hipMemcpyAsync(vecacc, vec, 3 * S * sizeof(float), hipMemcpyDeviceToDevice, stream);

    // Phase 1: node MLP (+ x1 init)
    ln_kernel<<<NN, 256, 0, stream>>>(x, ln_g, ln_b, xln_h, xln_l, x1);
    mfma_gemm<<<dim3(NN / 128, 4), 256, 0, stream>>>(xln_h, xln_l, WT_x1, WT_x1 + WLO,
                                                     b_x1, t1_h, t1_l, NN, 256, 256, 1);
    mfma_gemm<<<dim3(NN / 128, 12), 256, 0, stream>>>(t1_h, t1_l, WT_x2, WT_x2 + WLO,
                                                      b_x2, xh, nullptr, NN, 256, 768, 0);

    // Phase 2: sort edges by dst; edge-parallel fused gather (atomics)
    zero_kernel<<<(NN + 255) / 256, 256, 0, stream>>>(cursor, NN);
    hist_kernel<<<EE / 256, 256, 0, stream>>>(edge_index, cursor);
    scan_kernel<<<1, 256, 0, stream>>>(cursor, rowptr);
    scatter_kernel<<<EE / 256, 256, 0, stream>>>(edge_index, edge_vector, cursor,
                                                 perm, dsts, srcs, evs);
    edge_gather_kernel<<<EE / 128, 512, 0, stream>>>(
        edge_rbf, WT_rbf, WT_rbf + WLO, b_rbf, xh, vec,
        perm, dsts, srcs, evs, x1, vecacc);
    // hi/lo split of vecacc for the phase-3 GEMMs
    split4_kernel<<<3 * S / 1024, 256, 0, stream>>>(vecacc, vah, val_);

    // Phase 3: vp, vdot/vnorm, xv MLP, in-place updates
    mfma_gemm<<<dim3(3 * NN / 128, 4), 256, 0, stream>>>(vah, val_, WT_vp, WT_vp + WLO,
                                                         nullptr, vec1, nullptr,
                                                         3 * NN, 256, 256, 0);
    mfma_gemm<<<dim3(3 * NN / 128, 4), 256, 0, stream>>>(vah, val_, WT_vp + 65536,
                                                         WT_vp + WLO + 65536,
                                                         nullptr, vec2b, nullptr,
                                                         3 * NN, 256, 256, 2);
    vdot_cat_kernel<<<NN, 256, 0, stream>>>(vec1, vec2b, x1, vdot, catb_h, catb_l);
    mfma_gemm<<<dim3(NN / 128, 4), 256, 0, stream>>>(catb_h, catb_l, WT_xv1, WT_xv1 + WLO,
                                                     b_xv1, t2_h, t2_l, NN, 512, 256, 1);
    mfma_gemm<<<dim3(NN / 128, 12), 256, 0, stream>>>(t2_h, t2_l, WT_xv2, WT_xv2 + WLO,
                                                      b_xv2, xvh_h, xvh_l, NN, 256, 768, 0);
    e4_kernel<<<NN, 256, 0, stream>>>(x1, vecacc, vec1, vdot, xvh_h, xvh_l);

    // Phase 4: gated equivariant block 1
    split4_kernel<<<3 * S / 1024, 256, 0, stream>>>(vecacc, vah2, val2);
    mfma_gemm<<<dim3(3 * NN / 128, 4), 256, 0, stream>>>(vah2, val2, WT_o1Wv1, WT_o1Wv1 + WLO,
                                                         nullptr, w1b, nullptr,
                                                         3 * NN, 256, 256, 2);
    mfma_gemm<<<dim3(3 * NN / 128, 2), 256, 0, stream>>>(vah2, val2, WT_o1Wv2, WT_o1Wv2 + WLO,
                                                         nullptr, w2_h, w2_l,
                                                         3 * NN, 256, 128, 0);
    normcat_kernel<<<NN * 512 / 256, 256, 0, stream>>>(x1, w1b, cat2_h, cat2_l, 256, 256, 9);
    mfma_gemm<<<dim3(NN / 128, 4), 256, 0, stream>>>(cat2_h, cat2_l, WT_o1Wu1, WT_o1Wu1 + WLO,
                                                     o1_bu1, t4_h, t4_l, NN, 512, 256, 1);
    mfma_gemm<<<dim3(NN / 128, 4), 256, 0, stream>>>(t4_h, t4_l, WT_o1Wu2, WT_o1Wu2 + WLO,
                                                     o1_bu2, h1, nullptr, NN, 256, 256, 0);
    gate1_kernel<<<NN * 128 / 256, 256, 0, stream>>>(h1, w2_h, w2_l, x3, vecC_h, vecC_l);

    // Phase 5: gated equivariant block 2 + output
    mfma_gemm<<<dim3(3 * NN / 128, 2), 256, 0, stream>>>(vecC_h, vecC_l, WT_o2Wv1,
                                                         WT_o2Wv1 + WLO, nullptr,
                                                         w3b, nullptr, 3 * NN, 128, 128, 2);
    g12_kernel<<<3 * NN / 4, 256, 0, stream>>>(vecC_h, vecC_l, o2_Wv2, w4);
    normcat_kernel<<<NN * 256 / 256, 256, 0, stream>>>(x3, w3b, cat3_h, cat3_l, 128, 128, 8);
    mfma_gemm<<<dim3(NN / 128, 2), 256, 0, stream>>>(cat3_h, cat3_l, WT_o2Wu1, WT_o2Wu1 + WLO,
                                                     o2_bu1, t5, nullptr, NN, 256, 128, 1);
    final_kernel<<<NN / 4, 256, 0, stream>>>(t5, o2_Wu2, o2_bu2, w4, out);
}

// Round 8
// 1455.017 us; speedup vs baseline: 1.8162x; 1.0026x over previous
//
#include <hip/hip_runtime.h>
#include <math.h>

#define NN 16384
#define EE 262144
#define HH 256

#define INV_SQRT_3f 0.57735026918962576f
#define INV_SQRT_Hf 0.0625f
#define INV_SQRT_2f 0.70710678118654752f
#define SSILU_SCALE 1.6666666666666667f

typedef __attribute__((ext_vector_type(8))) short bf16x8;
typedef __attribute__((ext_vector_type(4))) float f32x4;

__device__ __forceinline__ float ssilu_f(float v) {
    return v * (1.0f / (1.0f + __expf(-v))) * SSILU_SCALE;
}
__device__ __forceinline__ float b2f(short s) {
    unsigned int u = ((unsigned int)(unsigned short)s) << 16;
    return __uint_as_float(u);
}
__device__ __forceinline__ short f2b(float f) {
    unsigned int u = __float_as_uint(f);
    unsigned int r = (u + 0x7fff + ((u >> 16) & 1)) >> 16;
    return (short)r;
}
// fp32x8 -> split hi/lo bf16x8 in registers (same rounding as the old split4)
__device__ __forceinline__ void cvt8(float4 a, float4 b, bf16x8& h, bf16x8& l) {
    float v[8] = {a.x, a.y, a.z, a.w, b.x, b.y, b.z, b.w};
    #pragma unroll
    for (int j = 0; j < 8; j++) {
        short hh = f2b(v[j]);
        h[j] = hh;
        l[j] = f2b(v[j] - b2f(hh));
    }
}

// ---------------- LayerNorm: one block per row, fp32 out + x1 init ----------------
__global__ void __launch_bounds__(256) ln_kernel(const float* __restrict__ x,
                                                 const float* __restrict__ g,
                                                 const float* __restrict__ b,
                                                 float* __restrict__ o_,
                                                 float* __restrict__ x1) {
    int n = blockIdx.x;
    int t = threadIdx.x;
    float v = x[(long)n * HH + t];
    x1[(long)n * HH + t] = v;
    float s = v, s2 = v * v;
    #pragma unroll
    for (int off = 32; off > 0; off >>= 1) {
        s  += __shfl_down(s, off);
        s2 += __shfl_down(s2, off);
    }
    __shared__ float red[8];
    int wave = t >> 6, lane = t & 63;
    if (lane == 0) { red[wave] = s; red[4 + wave] = s2; }
    __syncthreads();
    __shared__ float mr[2];
    if (t == 0) {
        float ts = red[0] + red[1] + red[2] + red[3];
        float ts2 = red[4] + red[5] + red[6] + red[7];
        float mean = ts * (1.0f / HH);
        float var = ts2 * (1.0f / HH) - mean * mean;
        mr[0] = mean;
        mr[1] = rsqrtf(var + 1e-5f);
    }
    __syncthreads();
    o_[(long)n * HH + t] = (v - mr[0]) * mr[1] * g[t] + b[t];
}

// ---- ALL weight transposes + hi/lo splits in ONE kernel (incl. W_rbf) ----
struct WtArgs {
    const float* W[12];
    int K[12];
    int N[12];
    int off[13];   // cumulative element offsets; off[12] = total
};

__global__ void __launch_bounds__(256) wt_split_all(WtArgs a,
                                                    short* __restrict__ WTh,
                                                    short* __restrict__ WTl) {
    int idx = blockIdx.x * 256 + threadIdx.x;
    int s = 0;
    #pragma unroll
    for (int i = 1; i < 12; i++) s += (idx >= a.off[i]) ? 1 : 0;
    int local = idx - a.off[s];
    int K = a.K[s], N = a.N[s];
    int k = local / N, n = local - k * N;
    float w = a.W[s][local];
    short hh = f2b(w);
    long o = (long)a.off[s] + (long)n * K + k;
    WTh[o] = hh;
    WTl[o] = f2b(w - b2f(hh));
}

// ---- split-bf16 MFMA GEMM v3: fp32 A, in-register hi/lo split ----
// C = A(M,K fp32) @ (Wh+Wl)^T(N,K) [+bias][epilogue per act]
// act 0: fp32 out C1          act 1: ssilu + fp32 out C1
// act 2: bf16 out C1          act 3: split out (C1 hi, C2 lo)
// act 4: col<256 -> fp32 C1[row*256+col]; col>=256 -> bf16 C2[row*256+col-256]
// act 5: col<256 -> bf16 C1[row*256+col]; col>=256 -> fp32 C2[row*128+col-256]
__global__ void __launch_bounds__(256) mfma_gemm(const float* __restrict__ A,
                                                 const short* __restrict__ Wh,
                                                 const short* __restrict__ Wl,
                                                 const float* __restrict__ bias,
                                                 void* __restrict__ C1,
                                                 void* __restrict__ C2,
                                                 int M, int K, int N, int act) {
    int tid = threadIdx.x;
    int wave = tid >> 6, lane = tid & 63;
    int quad = lane >> 4, l16 = lane & 15;
    long bm = (long)blockIdx.x * 128 + wave * 32;
    long bn = (long)blockIdx.y * 64;
    long a0 = (bm + l16) * K + quad * 8;
    long a1 = a0 + (long)16 * K;
    long w0 = (bn + l16) * K + quad * 8;

    f32x4 acc[2][4];
    #pragma unroll
    for (int f = 0; f < 2; f++)
        #pragma unroll
        for (int t = 0; t < 4; t++) acc[f][t] = (f32x4){0.f, 0.f, 0.f, 0.f};

    bf16x8 cah[2], cal[2], cbh[4], cbl[4];
    cvt8(*(const float4*)(A + a0), *(const float4*)(A + a0 + 4), cah[0], cal[0]);
    cvt8(*(const float4*)(A + a1), *(const float4*)(A + a1 + 4), cah[1], cal[1]);
    #pragma unroll
    for (int t = 0; t < 4; t++) {
        long wo = w0 + (long)t * 16 * K;
        cbh[t] = *(const bf16x8*)(Wh + wo);
        cbl[t] = *(const bf16x8*)(Wl + wo);
    }

    for (int k0 = 0; k0 < K; k0 += 32) {
        int k1 = k0 + 32;
        float4 n0a, n0b, n1a, n1b;
        bf16x8 nbh[4], nbl[4];
        if (k1 < K) {
            n0a = *(const float4*)(A + a0 + k1);
            n0b = *(const float4*)(A + a0 + k1 + 4);
            n1a = *(const float4*)(A + a1 + k1);
            n1b = *(const float4*)(A + a1 + k1 + 4);
            #pragma unroll
            for (int t = 0; t < 4; t++) {
                long wo = w0 + (long)t * 16 * K + k1;
                nbh[t] = *(const bf16x8*)(Wh + wo);
                nbl[t] = *(const bf16x8*)(Wl + wo);
            }
        }
        #pragma unroll
        for (int t = 0; t < 4; t++) {
            #pragma unroll
            for (int f = 0; f < 2; f++) {
                acc[f][t] = __builtin_amdgcn_mfma_f32_16x16x32_bf16(cah[f], cbh[t], acc[f][t], 0, 0, 0);
                acc[f][t] = __builtin_amdgcn_mfma_f32_16x16x32_bf16(cal[f], cbh[t], acc[f][t], 0, 0, 0);
                acc[f][t] = __builtin_amdgcn_mfma_f32_16x16x32_bf16(cah[f], cbl[t], acc[f][t], 0, 0, 0);
            }
        }
        if (k1 < K) {
            cvt8(n0a, n0b, cah[0], cal[0]);
            cvt8(n1a, n1b, cah[1], cal[1]);
            #pragma unroll
            for (int t = 0; t < 4; t++) { cbh[t] = nbh[t]; cbl[t] = nbl[t]; }
        }
    }

    #pragma unroll
    for (int f = 0; f < 2; f++) {
        long row0 = bm + f * 16 + quad * 4;
        #pragma unroll
        for (int t = 0; t < 4; t++) {
            long col = bn + t * 16 + l16;
            float bv = bias ? bias[col] : 0.f;
            #pragma unroll
            for (int r = 0; r < 4; r++) {
                float v = acc[f][t][r] + bv;
                long row = row0 + r;
                if (act == 4) {
                    if (col < 256) ((float*)C1)[row * 256 + col] = v;
                    else           ((short*)C2)[row * 256 + col - 256] = f2b(v);
                } else if (act == 5) {
                    if (col < 256) ((short*)C1)[row * 256 + col] = f2b(v);
                    else           ((float*)C2)[row * 128 + col - 256] = v;
                } else {
                    long idx = row * N + col;
                    if (act == 3) {
                        short hh = f2b(v);
                        ((short*)C1)[idx] = hh;
                        ((short*)C2)[idx] = f2b(v - b2f(hh));
                    } else if (act == 2) {
                        ((short*)C1)[idx] = f2b(v);
                    } else {
                        if (act == 1) v = ssilu_f(v);
                        ((float*)C1)[idx] = v;
                    }
                }
            }
        }
    }
}

// ---------------- edge sort (counting sort by dst) ----------------
__global__ void __launch_bounds__(256) zero_kernel(int* __restrict__ p, int n) {
    int i = blockIdx.x * 256 + threadIdx.x;
    if (i < n) p[i] = 0;
}

__global__ void __launch_bounds__(256) hist_kernel(const int* __restrict__ eidx,
                                                   int* __restrict__ cnt) {
    int e = blockIdx.x * 256 + threadIdx.x;
    atomicAdd(&cnt[eidx[EE + e]], 1);
}

__global__ void __launch_bounds__(256) scan_kernel(int* __restrict__ cursor,
                                                   int* __restrict__ rowptr) {
    int t = threadIdx.x;
    int base_i = t * 64;
    int tsum = 0;
    for (int i = 0; i < 64; i++) tsum += cursor[base_i + i];
    __shared__ int ls[256];
    ls[t] = tsum;
    __syncthreads();
    for (int off = 1; off < 256; off <<= 1) {
        int v = (t >= off) ? ls[t - off] : 0;
        __syncthreads();
        ls[t] += v;
        __syncthreads();
    }
    int running = ls[t] - tsum;
    for (int i = 0; i < 64; i++) {
        int c = cursor[base_i + i];
        rowptr[base_i + i] = running;
        cursor[base_i + i] = running;
        running += c;
    }
    if (t == 255) rowptr[NN] = running;
}

// scatter: also materialize dst/src/ev in sorted order for the edge kernel
__global__ void __launch_bounds__(256) scatter_kernel(const int* __restrict__ eidx,
                                                      const float* __restrict__ ev,
                                                      int* __restrict__ cursor,
                                                      int* __restrict__ perm,
                                                      int* __restrict__ dsts,
                                                      int* __restrict__ srcs,
                                                      float* __restrict__ evs) {
    int e = blockIdx.x * 256 + threadIdx.x;
    int s_ = eidx[e];
    int d_ = eidx[EE + e];
    int pos = atomicAdd(&cursor[d_], 1);
    perm[pos] = e;
    dsts[pos] = d_;
    srcs[pos] = s_;
    evs[pos * 3 + 0] = ev[e * 3 + 0];
    evs[pos * 3 + 1] = ev[e * 3 + 1];
    evs[pos * 3 + 2] = ev[e * 3 + 2];
}

// ---------------- Edge-parallel fused rbf-GEMM + gather + atomic reduce -------
// (unchanged from round 7: 8 waves x 16 edges, barrier-free, batched MLP consume)
__global__ void __launch_bounds__(512) edge_gather_kernel(
        const float* __restrict__ rbf,
        const short* __restrict__ Wrh,
        const short* __restrict__ Wrl,
        const float* __restrict__ b_rbf,
        const float* __restrict__ xh,
        const float* __restrict__ vec,
        const int* __restrict__ perm,
        const int* __restrict__ dsts,
        const int* __restrict__ srcs,
        const float* __restrict__ evs,
        float* __restrict__ x1,
        float* __restrict__ vecacc) {
    int tid = threadIdx.x;
    int wave = tid >> 6, lane = tid & 63;
    int quad = lane >> 4, l16 = lane & 15;
    int bm = blockIdx.x * 128;
    int base = wave * 16;              // this wave's 16 rows

    __shared__ __align__(16) float mlds[128][66];
    __shared__ int dst_s[128], src_s[128];
    __shared__ float ev_s[128][3];

    if (lane < 16) {
        int i = base + lane;
        dst_s[i] = dsts[bm + i];
        src_s[i] = srcs[bm + i];
        ev_s[i][0] = evs[(long)(bm + i) * 3 + 0];
        ev_s[i][1] = evs[(long)(bm + i) * 3 + 1];
        ev_s[i][2] = evs[(long)(bm + i) * 3 + 2];
    }

    int e0 = perm[bm + base + l16];
    bf16x8 afh[2], afl[2];
    {
        long ebase = (long)e0 * 64 + quad * 8;
        #pragma unroll
        for (int ks = 0; ks < 2; ks++) {
            float4 ua = *(const float4*)(rbf + ebase + ks * 32);
            float4 ub = *(const float4*)(rbf + ebase + ks * 32 + 4);
            cvt8(ua, ub, afh[ks], afl[ks]);
        }
    }

    for (int sec = 0; sec < 3; sec++) {
        for (int tile = 0; tile < 4; tile++) {
            int bn = sec * 256 + tile * 64;
            f32x4 acc[4];
            #pragma unroll
            for (int t = 0; t < 4; t++) {
                float bv = b_rbf[bn + t * 16 + l16];
                acc[t] = (f32x4){bv, bv, bv, bv};
                #pragma unroll
                for (int ks = 0; ks < 2; ks++) {
                    long wo = (long)(bn + t * 16 + l16) * 64 + ks * 32 + quad * 8;
                    bf16x8 bh = *(const bf16x8*)(Wrh + wo);
                    bf16x8 bl = *(const bf16x8*)(Wrl + wo);
                    acc[t] = __builtin_amdgcn_mfma_f32_16x16x32_bf16(afh[ks], bh, acc[t], 0, 0, 0);
                    acc[t] = __builtin_amdgcn_mfma_f32_16x16x32_bf16(afl[ks], bh, acc[t], 0, 0, 0);
                    acc[t] = __builtin_amdgcn_mfma_f32_16x16x32_bf16(afh[ks], bl, acc[t], 0, 0, 0);
                }
            }
            #pragma unroll
            for (int t = 0; t < 4; t++)
                #pragma unroll
                for (int r = 0; r < 4; r++)
                    mlds[base + quad * 4 + r][t * 16 + l16] = acc[t][r];

            int colx = tile * 64 + lane;
            if (sec == 0) {
                float pv[16];
                #pragma unroll
                for (int i = 0; i < 16; i++) {
                    long xb = (long)src_s[base + i] * 768;
                    pv[i] = mlds[base + i][lane] * xh[xb + colx];
                }
                float a = 0.f;
                int dprev = dst_s[base];
                #pragma unroll
                for (int i = 0; i < 16; i++) {
                    int d = dst_s[base + i];
                    if (d != dprev) {
                        atomicAdd(&x1[(long)dprev * 256 + colx], a);
                        a = 0.f;
                        dprev = d;
                    }
                    a += pv[i];
                }
                atomicAdd(&x1[(long)dprev * 256 + colx], a);
            } else if (sec == 1) {
                float a0 = 0.f, a1 = 0.f, a2 = 0.f;
                int dprev = dst_s[base];
                #pragma unroll 1
                for (int b = 0; b < 4; b++) {
                    float p0[4], p1[4], p2[4];
                    #pragma unroll
                    for (int j = 0; j < 4; j++) {
                        int i = b * 4 + j;
                        long xb = (long)src_s[base + i] * 768;
                        float m2 = mlds[base + i][lane] * (INV_SQRT_3f * INV_SQRT_Hf) *
                                   xh[xb + 256 + colx];
                        p0[j] = vec[xb + colx] * m2;
                        p1[j] = vec[xb + 256 + colx] * m2;
                        p2[j] = vec[xb + 512 + colx] * m2;
                    }
                    #pragma unroll
                    for (int j = 0; j < 4; j++) {
                        int i = b * 4 + j;
                        int d = dst_s[base + i];
                        if (d != dprev) {
                            long vb = (long)dprev * 768 + colx;
                            atomicAdd(&vecacc[vb], a0);
                            atomicAdd(&vecacc[vb + 256], a1);
                            atomicAdd(&vecacc[vb + 512], a2);
                            a0 = a1 = a2 = 0.f;
                            dprev = d;
                        }
                        a0 += p0[j]; a1 += p1[j]; a2 += p2[j];
                    }
                }
                long vb = (long)dprev * 768 + colx;
                atomicAdd(&vecacc[vb], a0);
                atomicAdd(&vecacc[vb + 256], a1);
                atomicAdd(&vecacc[vb + 512], a2);
            } else {
                float pm[16];
                #pragma unroll
                for (int i = 0; i < 16; i++) {
                    long xb = (long)src_s[base + i] * 768;
                    pm[i] = mlds[base + i][lane] * INV_SQRT_Hf * xh[xb + 512 + colx];
                }
                float a0 = 0.f, a1 = 0.f, a2 = 0.f;
                int dprev = dst_s[base];
                #pragma unroll
                for (int i = 0; i < 16; i++) {
                    int d = dst_s[base + i];
                    if (d != dprev) {
                        long vb = (long)dprev * 768 + colx;
                        atomicAdd(&vecacc[vb], a0);
                        atomicAdd(&vecacc[vb + 256], a1);
                        atomicAdd(&vecacc[vb + 512], a2);
                        a0 = a1 = a2 = 0.f;
                        dprev = d;
                    }
                    a0 += pm[i] * ev_s[base + i][0];
                    a1 += pm[i] * ev_s[base + i][1];
                    a2 += pm[i] * ev_s[base + i][2];
                }
                long vb = (long)dprev * 768 + colx;
                atomicAdd(&vecacc[vb], a0);
                atomicAdd(&vecacc[vb + 256], a1);
                atomicAdd(&vecacc[vb + 512], a2);
            }
        }
    }
}

// ---------------- vec_dot + vnorm + cat(x, vnorm) fp32 ----------------
__global__ void __launch_bounds__(256) vdot_cat_kernel(const float* __restrict__ vec1,
                                                       const short* __restrict__ vec2,
                                                       const float* __restrict__ x1,
                                                       float* __restrict__ vdot,
                                                       float* __restrict__ cat) {
    int idx = blockIdx.x * 256 + threadIdx.x;
    int n = idx >> 8, h = idx & 255;
    float dsum = 0.f, s2 = 0.f;
    #pragma unroll
    for (int d = 0; d < 3; d++) {
        long r = (long)(n * 3 + d) * 256 + h;
        float a = vec1[r];
        float b = b2f(vec2[r]);
        dsum += a * b;
        s2 += b * b;
    }
    vdot[idx] = dsum * INV_SQRT_Hf;
    cat[(long)n * 512 + h] = x1[idx];
    cat[(long)n * 512 + 256 + h] = sqrtf(s2 + 1e-8f);
}

// ---------------- x/vec update after xv MLP (IN-PLACE) ----------------
__global__ void __launch_bounds__(256) e4_kernel(float* __restrict__ x1,
                                                 float* __restrict__ vecacc,
                                                 const float* __restrict__ vec1,
                                                 const float* __restrict__ vdot,
                                                 const short* __restrict__ xvh_h,
                                                 const short* __restrict__ xvh_l) {
    int idx = blockIdx.x * 256 + threadIdx.x;
    int n = idx >> 8, h = idx & 255;
    long b0 = (long)n * 768 + h;
    float xv1 = b2f(xvh_h[b0])       + b2f(xvh_l[b0]);
    float xv2 = b2f(xvh_h[b0 + 256]) + b2f(xvh_l[b0 + 256]);
    float xv3 = b2f(xvh_h[b0 + 512]) + b2f(xvh_l[b0 + 512]);
    x1[idx] = x1[idx] + (xv1 + xv2 * vdot[idx]) * INV_SQRT_2f;
    #pragma unroll
    for (int d = 0; d < 3; d++) {
        long r = (long)(n * 3 + d) * 256 + h;
        vecacc[r] = vecacc[r] + xv3 * vec1[r];
    }
}

// ---------------- norm over d + concat(x fp32, norm) fp32 ----------------
__global__ void __launch_bounds__(256) normcat_kernel(const float* __restrict__ xin,
                                                      const short* __restrict__ w,
                                                      float* __restrict__ cat,
                                                      int Cx, int C, int shift) {
    int idx = blockIdx.x * 256 + threadIdx.x;
    int cols = 1 << shift;
    int n = idx >> shift, c = idx & (cols - 1);
    float v;
    if (c < Cx) {
        v = xin[(long)n * Cx + c];
    } else {
        int cc = c - Cx;
        float s = 0.f;
        #pragma unroll
        for (int d = 0; d < 3; d++) {
            float a = b2f(w[(long)(n * 3 + d) * C + cc]);
            s += a * a;
        }
        v = sqrtf(s);
    }
    cat[idx] = v;
}

// ---------------- gated block 1 epilogue (fp32 in/out) ----------------
__global__ void __launch_bounds__(256) gate1_kernel(const float* __restrict__ h1,
                                                    const float* __restrict__ w2,
                                                    float* __restrict__ x3,
                                                    float* __restrict__ vecC) {
    int idx = blockIdx.x * 256 + threadIdx.x;
    int n = idx >> 7, c = idx & 127;
    x3[idx] = ssilu_f(h1[(long)n * 256 + c]);
    float vn = h1[(long)n * 256 + 128 + c];
    #pragma unroll
    for (int d = 0; d < 3; d++) {
        long r = (long)(n * 3 + d) * 128 + c;
        vecC[r] = vn * w2[r];
    }
}

// ---------------- vecC @ o2_Wv2 (K=128, Nc=1): one wave per row ----------------
__global__ void __launch_bounds__(256) g12_kernel(const float* __restrict__ vecC,
                                                  const float* __restrict__ Wv2,
                                                  float* __restrict__ w4) {
    int row = blockIdx.x * 4 + (threadIdx.x >> 6);
    int lane = threadIdx.x & 63;
    long r0 = (long)row * 128 + lane;
    float s = vecC[r0] * Wv2[lane] + vecC[r0 + 64] * Wv2[64 + lane];
    #pragma unroll
    for (int off = 32; off > 0; off >>= 1) s += __shfl_down(s, off);
    if (lane == 0) w4[row] = s;
}

// ---------------- final: out[n,d] = (t5[n,:]@Wu2[:,1] + b2[1]) * w4[n,d] ----------
__global__ void __launch_bounds__(256) final_kernel(const float* __restrict__ t5,
                                                    const float* __restrict__ Wu2,
                                                    const float* __restrict__ bu2,
                                                    const float* __restrict__ w4,
                                                    float* __restrict__ out) {
    int n = blockIdx.x * 4 + (threadIdx.x >> 6);
    int lane = threadIdx.x & 63;
    float s = t5[(long)n * 128 + lane] * Wu2[lane * 2 + 1] +
              t5[(long)n * 128 + 64 + lane] * Wu2[(64 + lane) * 2 + 1];
    #pragma unroll
    for (int off = 32; off > 0; off >>= 1) s += __shfl_down(s, off);
    float val = __shfl(s, 0) + bu2[1];
    if (lane < 3) out[(long)n * 3 + lane] = val * w4[(long)n * 3 + lane];
}

extern "C" void kernel_launch(void* const* d_in, const int* in_sizes, int n_in,
                              void* d_out, int out_size, void* d_ws, size_t ws_size,
                              hipStream_t stream) {
    const float* x          = (const float*)d_in[0];
    const float* vec        = (const float*)d_in[1];
    const float* edge_rbf   = (const float*)d_in[2];
    const float* edge_vector= (const float*)d_in[3];
    const float* ln_g       = (const float*)d_in[4];
    const float* ln_b       = (const float*)d_in[5];
    const float* W_x1       = (const float*)d_in[6];
    const float* b_x1       = (const float*)d_in[7];
    const float* W_x2       = (const float*)d_in[8];
    const float* b_x2       = (const float*)d_in[9];
    const float* W_rbf      = (const float*)d_in[10];
    const float* b_rbf      = (const float*)d_in[11];
    const float* W_vp       = (const float*)d_in[12];
    const float* W_xv1      = (const float*)d_in[13];
    const float* b_xv1      = (const float*)d_in[14];
    const float* W_xv2      = (const float*)d_in[15];
    const float* b_xv2      = (const float*)d_in[16];
    const float* o1_Wv1     = (const float*)d_in[17];
    const float* o1_Wv2     = (const float*)d_in[18];
    const float* o1_Wu1     = (const float*)d_in[19];
    const float* o1_bu1     = (const float*)d_in[20];
    const float* o1_Wu2     = (const float*)d_in[21];
    const float* o1_bu2     = (const float*)d_in[22];
    const float* o2_Wv1     = (const float*)d_in[23];
    const float* o2_Wv2     = (const float*)d_in[24];
    const float* o2_Wu1     = (const float*)d_in[25];
    const float* o2_bu1     = (const float*)d_in[26];
    const float* o2_Wu2     = (const float*)d_in[27];
    const float* o2_bu2     = (const float*)d_in[28];
    const int*   edge_index = (const int*)d_in[29];
    float* out = (float*)d_out;
    float* ws  = (float*)d_ws;

    const size_t S = (size_t)NN * 256;
    const size_t Q = S / 4;              // 1,048,576 floats = 4 MiB
    // ---- arena in units of Q; peak 52Q = 208 MiB (proven safe) ----
    float* x1      = ws;                     // Q0-3   (fp32 S)
    float* vecacc  = ws + 4 * Q;             // Q4-15  (fp32 3S)
    short* wtb     = (short*)(ws + 16 * Q);  // Q16-17 weights hi + lo
    const long WLO = 1114112;
    // phase 1 (all fp32 now)
    float* xln   = ws + 18 * Q;              // Q18-21 (fp32 S, dead after t1 gemm)
    float* t1    = ws + 22 * Q;              // Q22-25 (fp32 S, dead after xh gemm)
    float* xh    = ws + 30 * Q;              // Q30-41 (fp32 3S, dead after gather)
    // phase 2 sort scratch (dead before vdot is written)
    int* rowptr    = (int*)(ws + 48 * Q);    // NN+1
    int* cursor    = rowptr + (NN + 1);      // NN
    int* perm      = cursor + NN;            // EE
    int* dsts      = perm + EE;              // EE
    int* srcs      = dsts + EE;              // EE
    float* evs     = (float*)(srcs + EE);    // 3*EE
    // phase 3
    float* vec1  = ws + 30 * Q;              // Q30-41 (fp32 3S, live till e4)
    short* vec2b = (short*)(ws + 42 * Q);    // Q42-47 (bf16 3S)
    float* vdot  = ws + 48 * Q;              // Q48-51 (fp32 S, live till e4)
    float* cat   = ws + 18 * Q;              // Q18-25 (fp32 2S; xln/t1 dead)
    float* t2    = ws + 26 * Q;              // Q26-29 (fp32 S)
    short* xvh_h = (short*)(ws + 18 * Q);    // Q18-23 (cat dead after xv1 gemm)
    short* xvh_l = (short*)(ws + 42 * Q);    // Q42-47 (vec2b dead after vdot_cat)
    // phase 4
    short* w1b   = (short*)(ws + 30 * Q);    // Q30-35 (bf16 3S; vec1 dead after e4)
    float* w2    = ws + 36 * Q;              // Q36-41 (fp32 3*NN*128)
    float* cat2  = ws + 42 * Q;              // Q42-49 (fp32 2S; xvh_l/vdot dead)
    float* t4    = ws + 18 * Q;              // Q18-21 (fp32 S; xvh_h dead)
    float* h1    = ws + 22 * Q;              // Q22-25 (fp32 S)
    float* x3    = ws + 26 * Q;              // Q26-27 (fp32 S/2)
    float* vecC  = ws + 28 * Q;              // Q28-33 (fp32 3*NN*128)
    // phase 5
    short* w3b   = (short*)(ws + 34 * Q);    // Q34-36 (bf16 3*NN*128)
    float* w4    = ws + 37 * Q;              // Q37
    float* cat3  = ws + 38 * Q;              // Q38-41 (fp32 NN*256)
    float* t5    = ws + 42 * Q;              // Q42-43

    // weight hi/lo offsets (shorts)
    short* WT_x1    = wtb;
    short* WT_x2    = wtb + 65536;
    short* WT_vp    = wtb + 262144;          // [n<512][k<256] contiguous -> fused vp
    short* WT_xv1   = wtb + 393216;
    short* WT_xv2   = wtb + 524288;
    short* WT_o1Wv1 = wtb + 720896;          // [n<256][k<256]; o1Wv2 follows -> fused N=384
    short* WT_o1Wv2 = wtb + 786432;
    short* WT_o1Wu1 = wtb + 819200;
    short* WT_o1Wu2 = wtb + 950272;
    short* WT_o2Wv1 = wtb + 1015808;
    short* WT_o2Wu1 = wtb + 1032192;
    short* WT_rbf   = wtb + 1064960;         // 768 x 64

    // Phase 0: all weight transposes + splits in one launch (incl. W_rbf^T)
    WtArgs wa;
    const float* wsrc[12] = {W_x1, W_x2, W_vp, W_xv1, W_xv2, o1_Wv1, o1_Wv2,
                             o1_Wu1, o1_Wu2, o2_Wv1, o2_Wu1, W_rbf};
    int wk[12] = {256, 256, 256, 512, 256, 256, 256, 512, 256, 128, 256, 64};
    int wn[12] = {256, 768, 512, 256, 768, 256, 128, 256, 256, 128, 128, 768};
    int off = 0;
    for (int i = 0; i < 12; i++) {
        wa.W[i] = wsrc[i]; wa.K[i] = wk[i]; wa.N[i] = wn[i];
        wa.off[i] = off; off += wk[i] * wn[i];
    }
    wa.off[12] = off;  // 1,114,112
    wt_split_all<<<off / 256, 256, 0, stream>>>(wa, wtb, wtb + WLO);

    // init vec accumulation target (x1 = x is folded into ln_kernel)
    hipMemcpyAsync(vecacc, vec, 3 * S * sizeof(float), hipMemcpyDeviceToDevice, stream);

    // Phase 1: node MLP (+ x1 init)
    ln_kernel<<<NN, 256, 0, stream>>>(x, ln_g, ln_b, xln, x1);
    mfma_gemm<<<dim3(NN / 128, 4), 256, 0, stream>>>(xln, WT_x1, WT_x1 + WLO,
                                                     b_x1, t1, nullptr, NN, 256, 256, 1);
    mfma_gemm<<<dim3(NN / 128, 12), 256, 0, stream>>>(t1, WT_x2, WT_x2 + WLO,
                                                      b_x2, xh, nullptr, NN, 256, 768, 0);

    // Phase 2: sort edges by dst; edge-parallel fused gather (atomics)
    zero_kernel<<<(NN + 255) / 256, 256, 0, stream>>>(cursor, NN);
    hist_kernel<<<EE / 256, 256, 0, stream>>>(edge_index, cursor);
    scan_kernel<<<1, 256, 0, stream>>>(cursor, rowptr);
    scatter_kernel<<<EE / 256, 256, 0, stream>>>(edge_index, edge_vector, cursor,
                                                 perm, dsts, srcs, evs);
    edge_gather_kernel<<<EE / 128, 512, 0, stream>>>(
        edge_rbf, WT_rbf, WT_rbf + WLO, b_rbf, xh, vec,
        perm, dsts, srcs, evs, x1, vecacc);

    // Phase 3: fused vp (N=512: cols<256 -> fp32 vec1, >=256 -> bf16 vec2b)
    mfma_gemm<<<dim3(3 * NN / 128, 8), 256, 0, stream>>>(vecacc, WT_vp, WT_vp + WLO,
                                                         nullptr, vec1, vec2b,
                                                         3 * NN, 256, 512, 4);
    vdot_cat_kernel<<<NN, 256, 0, stream>>>(vec1, vec2b, x1, vdot, cat);
    mfma_gemm<<<dim3(NN / 128, 4), 256, 0, stream>>>(cat, WT_xv1, WT_xv1 + WLO,
                                                     b_xv1, t2, nullptr, NN, 512, 256, 1);
    mfma_gemm<<<dim3(NN / 128, 12), 256, 0, stream>>>(t2, WT_xv2, WT_xv2 + WLO,
                                                      b_xv2, xvh_h, xvh_l, NN, 256, 768, 3);
    e4_kernel<<<NN, 256, 0, stream>>>(x1, vecacc, vec1, vdot, xvh_h, xvh_l);

    // Phase 4: fused o1Wv (N=384: cols<256 -> bf16 w1b, >=256 -> fp32 w2)
    mfma_gemm<<<dim3(3 * NN / 128, 6), 256, 0, stream>>>(vecacc, WT_o1Wv1, WT_o1Wv1 + WLO,
                                                         nullptr, w1b, w2,
                                                         3 * NN, 256, 384, 5);
    normcat_kernel<<<NN * 512 / 256, 256, 0, stream>>>(x1, w1b, cat2, 256, 256, 9);
    mfma_gemm<<<dim3(NN / 128, 4), 256, 0, stream>>>(cat2, WT_o1Wu1, WT_o1Wu1 + WLO,
                                                     o1_bu1, t4, nullptr, NN, 512, 256, 1);
    mfma_gemm<<<dim3(NN / 128, 4), 256, 0, stream>>>(t4, WT_o1Wu2, WT_o1Wu2 + WLO,
                                                     o1_bu2, h1, nullptr, NN, 256, 256, 0);
    gate1_kernel<<<NN * 128 / 256, 256, 0, stream>>>(h1, w2, x3, vecC);

    // Phase 5: gated equivariant block 2 + output
    mfma_gemm<<<dim3(3 * NN / 128, 2), 256, 0, stream>>>(vecC, WT_o2Wv1, WT_o2Wv1 + WLO,
                                                         nullptr, w3b, nullptr,
                                                         3 * NN, 128, 128, 2);
    g12_kernel<<<3 * NN / 4, 256, 0, stream>>>(vecC, o2_Wv2, w4);
    normcat_kernel<<<NN * 256 / 256, 256, 0, stream>>>(x3, w3b, cat3, 128, 128, 8);
    mfma_gemm<<<dim3(NN / 128, 2), 256, 0, stream>>>(cat3, WT_o2Wu1, WT_o2Wu1 + WLO,
                                                     o2_bu1, t5, nullptr, NN, 256, 128, 1);
    final_kernel<<<NN / 4, 256, 0, stream>>>(t5, o2_Wu2, o2_bu2, w4, out);
}

// Round 10
// 1440.294 us; speedup vs baseline: 1.8348x; 1.0102x over previous
//
#include <hip/hip_runtime.h>
#include <math.h>

#define NN 16384
#define EE 262144
#define HH 256

#define INV_SQRT_3f 0.57735026918962576f
#define INV_SQRT_Hf 0.0625f
#define INV_SQRT_2f 0.70710678118654752f
#define SSILU_SCALE 1.6666666666666667f

typedef __attribute__((ext_vector_type(8))) short bf16x8;
typedef __attribute__((ext_vector_type(4))) float f32x4;

__device__ __forceinline__ float ssilu_f(float v) {
    return v * (1.0f / (1.0f + __expf(-v))) * SSILU_SCALE;
}
__device__ __forceinline__ float b2f(short s) {
    unsigned int u = ((unsigned int)(unsigned short)s) << 16;
    return __uint_as_float(u);
}
__device__ __forceinline__ short f2b(float f) {
    unsigned int u = __float_as_uint(f);
    unsigned int r = (u + 0x7fff + ((u >> 16) & 1)) >> 16;
    return (short)r;
}
// fp32x8 -> split hi/lo bf16x8 in registers (same rounding as the old split4)
__device__ __forceinline__ void cvt8(float4 a, float4 b, bf16x8& h, bf16x8& l) {
    float v[8] = {a.x, a.y, a.z, a.w, b.x, b.y, b.z, b.w};
    #pragma unroll
    for (int j = 0; j < 8; j++) {
        short hh = f2b(v[j]);
        h[j] = hh;
        l[j] = f2b(v[j] - b2f(hh));
    }
}
// same, from native ext-vector f32x4 (usable with __builtin_nontemporal_load)
__device__ __forceinline__ void cvt8v(f32x4 a, f32x4 b, bf16x8& h, bf16x8& l) {
    float v[8] = {a.x, a.y, a.z, a.w, b.x, b.y, b.z, b.w};
    #pragma unroll
    for (int j = 0; j < 8; j++) {
        short hh = f2b(v[j]);
        h[j] = hh;
        l[j] = f2b(v[j] - b2f(hh));
    }
}

// ---------------- LayerNorm: one block per row, fp32 out + x1 init ----------------
__global__ void __launch_bounds__(256) ln_kernel(const float* __restrict__ x,
                                                 const float* __restrict__ g,
                                                 const float* __restrict__ b,
                                                 float* __restrict__ o_,
                                                 float* __restrict__ x1) {
    int n = blockIdx.x;
    int t = threadIdx.x;
    float v = x[(long)n * HH + t];
    x1[(long)n * HH + t] = v;
    float s = v, s2 = v * v;
    #pragma unroll
    for (int off = 32; off > 0; off >>= 1) {
        s  += __shfl_down(s, off);
        s2 += __shfl_down(s2, off);
    }
    __shared__ float red[8];
    int wave = t >> 6, lane = t & 63;
    if (lane == 0) { red[wave] = s; red[4 + wave] = s2; }
    __syncthreads();
    __shared__ float mr[2];
    if (t == 0) {
        float ts = red[0] + red[1] + red[2] + red[3];
        float ts2 = red[4] + red[5] + red[6] + red[7];
        float mean = ts * (1.0f / HH);
        float var = ts2 * (1.0f / HH) - mean * mean;
        mr[0] = mean;
        mr[1] = rsqrtf(var + 1e-5f);
    }
    __syncthreads();
    o_[(long)n * HH + t] = (v - mr[0]) * mr[1] * g[t] + b[t];
}

// ---- ALL weight transposes + hi/lo splits in ONE kernel (incl. W_rbf) ----
struct WtArgs {
    const float* W[12];
    int K[12];
    int N[12];
    int off[13];   // cumulative element offsets; off[12] = total
};

__global__ void __launch_bounds__(256) wt_split_all(WtArgs a,
                                                    short* __restrict__ WTh,
                                                    short* __restrict__ WTl) {
    int idx = blockIdx.x * 256 + threadIdx.x;
    int s = 0;
    #pragma unroll
    for (int i = 1; i < 12; i++) s += (idx >= a.off[i]) ? 1 : 0;
    int local = idx - a.off[s];
    int K = a.K[s], N = a.N[s];
    int k = local / N, n = local - k * N;
    float w = a.W[s][local];
    short hh = f2b(w);
    long o = (long)a.off[s] + (long)n * K + k;
    WTh[o] = hh;
    WTl[o] = f2b(w - b2f(hh));
}

// ---- split-bf16 MFMA GEMM v3: fp32 A, in-register hi/lo split ----
// C = A(M,K fp32) @ (Wh+Wl)^T(N,K) [+bias][epilogue per act]
// act 0: fp32 out C1          act 1: ssilu + fp32 out C1
// act 2: bf16 out C1          act 3: split out (C1 hi, C2 lo)
// act 4: col<256 -> fp32 C1[row*256+col]; col>=256 -> bf16 C2[row*256+col-256]
// act 5: col<256 -> bf16 C1[row*256+col]; col>=256 -> fp32 C2[row*128+col-256]
__global__ void __launch_bounds__(256) mfma_gemm(const float* __restrict__ A,
                                                 const short* __restrict__ Wh,
                                                 const short* __restrict__ Wl,
                                                 const float* __restrict__ bias,
                                                 void* __restrict__ C1,
                                                 void* __restrict__ C2,
                                                 int M, int K, int N, int act) {
    int tid = threadIdx.x;
    int wave = tid >> 6, lane = tid & 63;
    int quad = lane >> 4, l16 = lane & 15;
    long bm = (long)blockIdx.x * 128 + wave * 32;
    long bn = (long)blockIdx.y * 64;
    long a0 = (bm + l16) * K + quad * 8;
    long a1 = a0 + (long)16 * K;
    long w0 = (bn + l16) * K + quad * 8;

    f32x4 acc[2][4];
    #pragma unroll
    for (int f = 0; f < 2; f++)
        #pragma unroll
        for (int t = 0; t < 4; t++) acc[f][t] = (f32x4){0.f, 0.f, 0.f, 0.f};

    bf16x8 cah[2], cal[2], cbh[4], cbl[4];
    cvt8(*(const float4*)(A + a0), *(const float4*)(A + a0 + 4), cah[0], cal[0]);
    cvt8(*(const float4*)(A + a1), *(const float4*)(A + a1 + 4), cah[1], cal[1]);
    #pragma unroll
    for (int t = 0; t < 4; t++) {
        long wo = w0 + (long)t * 16 * K;
        cbh[t] = *(const bf16x8*)(Wh + wo);
        cbl[t] = *(const bf16x8*)(Wl + wo);
    }

    for (int k0 = 0; k0 < K; k0 += 32) {
        int k1 = k0 + 32;
        float4 n0a, n0b, n1a, n1b;
        bf16x8 nbh[4], nbl[4];
        if (k1 < K) {
            n0a = *(const float4*)(A + a0 + k1);
            n0b = *(const float4*)(A + a0 + k1 + 4);
            n1a = *(const float4*)(A + a1 + k1);
            n1b = *(const float4*)(A + a1 + k1 + 4);
            #pragma unroll
            for (int t = 0; t < 4; t++) {
                long wo = w0 + (long)t * 16 * K + k1;
                nbh[t] = *(const bf16x8*)(Wh + wo);
                nbl[t] = *(const bf16x8*)(Wl + wo);
            }
        }
        #pragma unroll
        for (int t = 0; t < 4; t++) {
            #pragma unroll
            for (int f = 0; f < 2; f++) {
                acc[f][t] = __builtin_amdgcn_mfma_f32_16x16x32_bf16(cah[f], cbh[t], acc[f][t], 0, 0, 0);
                acc[f][t] = __builtin_amdgcn_mfma_f32_16x16x32_bf16(cal[f], cbh[t], acc[f][t], 0, 0, 0);
                acc[f][t] = __builtin_amdgcn_mfma_f32_16x16x32_bf16(cah[f], cbl[t], acc[f][t], 0, 0, 0);
            }
        }
        if (k1 < K) {
            cvt8(n0a, n0b, cah[0], cal[0]);
            cvt8(n1a, n1b, cah[1], cal[1]);
            #pragma unroll
            for (int t = 0; t < 4; t++) { cbh[t] = nbh[t]; cbl[t] = nbl[t]; }
        }
    }

    #pragma unroll
    for (int f = 0; f < 2; f++) {
        long row0 = bm + f * 16 + quad * 4;
        #pragma unroll
        for (int t = 0; t < 4; t++) {
            long col = bn + t * 16 + l16;
            float bv = bias ? bias[col] : 0.f;
            #pragma unroll
            for (int r = 0; r < 4; r++) {
                float v = acc[f][t][r] + bv;
                long row = row0 + r;
                if (act == 4) {
                    if (col < 256) ((float*)C1)[row * 256 + col] = v;
                    else           ((short*)C2)[row * 256 + col - 256] = f2b(v);
                } else if (act == 5) {
                    if (col < 256) ((short*)C1)[row * 256 + col] = f2b(v);
                    else           ((float*)C2)[row * 128 + col - 256] = v;
                } else {
                    long idx = row * N + col;
                    if (act == 3) {
                        short hh = f2b(v);
                        ((short*)C1)[idx] = hh;
                        ((short*)C2)[idx] = f2b(v - b2f(hh));
                    } else if (act == 2) {
                        ((short*)C1)[idx] = f2b(v);
                    } else {
                        if (act == 1) v = ssilu_f(v);
                        ((float*)C1)[idx] = v;
                    }
                }
            }
        }
    }
}

// ---------------- edge sort (counting sort by dst) ----------------
__global__ void __launch_bounds__(256) zero_kernel(int* __restrict__ p, int n) {
    int i = blockIdx.x * 256 + threadIdx.x;
    if (i < n) p[i] = 0;
}

__global__ void __launch_bounds__(256) hist_kernel(const int* __restrict__ eidx,
                                                   int* __restrict__ cnt) {
    int e = blockIdx.x * 256 + threadIdx.x;
    atomicAdd(&cnt[eidx[EE + e]], 1);
}

__global__ void __launch_bounds__(256) scan_kernel(int* __restrict__ cursor,
                                                   int* __restrict__ rowptr) {
    int t = threadIdx.x;
    int base_i = t * 64;
    int tsum = 0;
    for (int i = 0; i < 64; i++) tsum += cursor[base_i + i];
    __shared__ int ls[256];
    ls[t] = tsum;
    __syncthreads();
    for (int off = 1; off < 256; off <<= 1) {
        int v = (t >= off) ? ls[t - off] : 0;
        __syncthreads();
        ls[t] += v;
        __syncthreads();
    }
    int running = ls[t] - tsum;
    for (int i = 0; i < 64; i++) {
        int c = cursor[base_i + i];
        rowptr[base_i + i] = running;
        cursor[base_i + i] = running;
        running += c;
    }
    if (t == 255) rowptr[NN] = running;
}

// scatter: also materialize dst/src/ev in sorted order for the edge kernel
__global__ void __launch_bounds__(256) scatter_kernel(const int* __restrict__ eidx,
                                                      const float* __restrict__ ev,
                                                      int* __restrict__ cursor,
                                                      int* __restrict__ perm,
                                                      int* __restrict__ dsts,
                                                      int* __restrict__ srcs,
                                                      float* __restrict__ evs) {
    int e = blockIdx.x * 256 + threadIdx.x;
    int s_ = eidx[e];
    int d_ = eidx[EE + e];
    int pos = atomicAdd(&cursor[d_], 1);
    perm[pos] = e;
    dsts[pos] = d_;
    srcs[pos] = s_;
    evs[pos * 3 + 0] = ev[e * 3 + 0];
    evs[pos * 3 + 1] = ev[e * 3 + 1];
    evs[pos * 3 + 2] = ev[e * 3 + 2];
}

// ---------------- Edge-parallel fused rbf-GEMM + gather + atomic reduce -------
// v6b: STREAMING OPERANDS GO NON-TEMPORAL (compile-fixed: nt loads through the
// native ext-vector f32x4, not HIP float4). FETCH_SIZE showed 777 MB vs ~230 MB
// compulsory: the read-once streams (rbf 64MB, perm/dsts/srcs/evs 7MB) were
// allocating in L3 and evicting the gather-hot xh/vec/accumulator lines
// (working set ~233MB ~= 256MB L3). nt keeps L3 for the hot data.
__global__ void __launch_bounds__(512) edge_gather_kernel(
        const float* __restrict__ rbf,
        const short* __restrict__ Wrh,
        const short* __restrict__ Wrl,
        const float* __restrict__ b_rbf,
        const float* __restrict__ xh,
        const float* __restrict__ vec,
        const int* __restrict__ perm,
        const int* __restrict__ dsts,
        const int* __restrict__ srcs,
        const float* __restrict__ evs,
        float* __restrict__ x1,
        float* __restrict__ vecacc) {
    int tid = threadIdx.x;
    int wave = tid >> 6, lane = tid & 63;
    int quad = lane >> 4, l16 = lane & 15;
    int bm = blockIdx.x * 128;
    int base = wave * 16;              // this wave's 16 rows

    __shared__ __align__(16) float mlds[128][66];
    __shared__ int dst_s[128], src_s[128];
    __shared__ float ev_s[128][3];

    if (lane < 16) {
        int i = base + lane;
        dst_s[i] = __builtin_nontemporal_load(dsts + bm + i);
        src_s[i] = __builtin_nontemporal_load(srcs + bm + i);
        ev_s[i][0] = __builtin_nontemporal_load(evs + (long)(bm + i) * 3 + 0);
        ev_s[i][1] = __builtin_nontemporal_load(evs + (long)(bm + i) * 3 + 1);
        ev_s[i][2] = __builtin_nontemporal_load(evs + (long)(bm + i) * 3 + 2);
    }

    int e0 = __builtin_nontemporal_load(perm + bm + base + l16);
    bf16x8 afh[2], afl[2];
    {
        long ebase = (long)e0 * 64 + quad * 8;
        #pragma unroll
        for (int ks = 0; ks < 2; ks++) {
            f32x4 ua = __builtin_nontemporal_load(
                reinterpret_cast<const f32x4*>(rbf + ebase + ks * 32));
            f32x4 ub = __builtin_nontemporal_load(
                reinterpret_cast<const f32x4*>(rbf + ebase + ks * 32 + 4));
            cvt8v(ua, ub, afh[ks], afl[ks]);
        }
    }

    for (int sec = 0; sec < 3; sec++) {
        for (int tile = 0; tile < 4; tile++) {
            int bn = sec * 256 + tile * 64;
            f32x4 acc[4];
            #pragma unroll
            for (int t = 0; t < 4; t++) {
                float bv = b_rbf[bn + t * 16 + l16];
                acc[t] = (f32x4){bv, bv, bv, bv};
                #pragma unroll
                for (int ks = 0; ks < 2; ks++) {
                    long wo = (long)(bn + t * 16 + l16) * 64 + ks * 32 + quad * 8;
                    bf16x8 bh = *(const bf16x8*)(Wrh + wo);
                    bf16x8 bl = *(const bf16x8*)(Wrl + wo);
                    acc[t] = __builtin_amdgcn_mfma_f32_16x16x32_bf16(afh[ks], bh, acc[t], 0, 0, 0);
                    acc[t] = __builtin_amdgcn_mfma_f32_16x16x32_bf16(afl[ks], bh, acc[t], 0, 0, 0);
                    acc[t] = __builtin_amdgcn_mfma_f32_16x16x32_bf16(afh[ks], bl, acc[t], 0, 0, 0);
                }
            }
            #pragma unroll
            for (int t = 0; t < 4; t++)
                #pragma unroll
                for (int r = 0; r < 4; r++)
                    mlds[base + quad * 4 + r][t * 16 + l16] = acc[t][r];

            int colx = tile * 64 + lane;
            if (sec == 0) {
                float pv[16];
                #pragma unroll
                for (int i = 0; i < 16; i++) {
                    long xb = (long)src_s[base + i] * 768;
                    pv[i] = mlds[base + i][lane] * xh[xb + colx];
                }
                float a = 0.f;
                int dprev = dst_s[base];
                #pragma unroll
                for (int i = 0; i < 16; i++) {
                    int d = dst_s[base + i];
                    if (d != dprev) {
                        atomicAdd(&x1[(long)dprev * 256 + colx], a);
                        a = 0.f;
                        dprev = d;
                    }
                    a += pv[i];
                }
                atomicAdd(&x1[(long)dprev * 256 + colx], a);
            } else if (sec == 1) {
                float a0 = 0.f, a1 = 0.f, a2 = 0.f;
                int dprev = dst_s[base];
                #pragma unroll 1
                for (int b = 0; b < 4; b++) {
                    float p0[4], p1[4], p2[4];
                    #pragma unroll
                    for (int j = 0; j < 4; j++) {
                        int i = b * 4 + j;
                        long xb = (long)src_s[base + i] * 768;
                        float m2 = mlds[base + i][lane] * (INV_SQRT_3f * INV_SQRT_Hf) *
                                   xh[xb + 256 + colx];
                        p0[j] = vec[xb + colx] * m2;
                        p1[j] = vec[xb + 256 + colx] * m2;
                        p2[j] = vec[xb + 512 + colx] * m2;
                    }
                    #pragma unroll
                    for (int j = 0; j < 4; j++) {
                        int i = b * 4 + j;
                        int d = dst_s[base + i];
                        if (d != dprev) {
                            long vb = (long)dprev * 768 + colx;
                            atomicAdd(&vecacc[vb], a0);
                            atomicAdd(&vecacc[vb + 256], a1);
                            atomicAdd(&vecacc[vb + 512], a2);
                            a0 = a1 = a2 = 0.f;
                            dprev = d;
                        }
                        a0 += p0[j]; a1 += p1[j]; a2 += p2[j];
                    }
                }
                long vb = (long)dprev * 768 + colx;
                atomicAdd(&vecacc[vb], a0);
                atomicAdd(&vecacc[vb + 256], a1);
                atomicAdd(&vecacc[vb + 512], a2);
            } else {
                float pm[16];
                #pragma unroll
                for (int i = 0; i < 16; i++) {
                    long xb = (long)src_s[base + i] * 768;
                    pm[i] = mlds[base + i][lane] * INV_SQRT_Hf * xh[xb + 512 + colx];
                }
                float a0 = 0.f, a1 = 0.f, a2 = 0.f;
                int dprev = dst_s[base];
                #pragma unroll
                for (int i = 0; i < 16; i++) {
                    int d = dst_s[base + i];
                    if (d != dprev) {
                        long vb = (long)dprev * 768 + colx;
                        atomicAdd(&vecacc[vb], a0);
                        atomicAdd(&vecacc[vb + 256], a1);
                        atomicAdd(&vecacc[vb + 512], a2);
                        a0 = a1 = a2 = 0.f;
                        dprev = d;
                    }
                    a0 += pm[i] * ev_s[base + i][0];
                    a1 += pm[i] * ev_s[base + i][1];
                    a2 += pm[i] * ev_s[base + i][2];
                }
                long vb = (long)dprev * 768 + colx;
                atomicAdd(&vecacc[vb], a0);
                atomicAdd(&vecacc[vb + 256], a1);
                atomicAdd(&vecacc[vb + 512], a2);
            }
        }
    }
}

// ---------------- vec_dot + vnorm + cat(x, vnorm) fp32 ----------------
__global__ void __launch_bounds__(256) vdot_cat_kernel(const float* __restrict__ vec1,
                                                       const short* __restrict__ vec2,
                                                       const float* __restrict__ x1,
                                                       float* __restrict__ vdot,
                                                       float* __restrict__ cat) {
    int idx = blockIdx.x * 256 + threadIdx.x;
    int n = idx >> 8, h = idx & 255;
    float dsum = 0.f, s2 = 0.f;
    #pragma unroll
    for (int d = 0; d < 3; d++) {
        long r = (long)(n * 3 + d) * 256 + h;
        float a = vec1[r];
        float b = b2f(vec2[r]);
        dsum += a * b;
        s2 += b * b;
    }
    vdot[idx] = dsum * INV_SQRT_Hf;
    cat[(long)n * 512 + h] = x1[idx];
    cat[(long)n * 512 + 256 + h] = sqrtf(s2 + 1e-8f);
}

// ---------------- x/vec update after xv MLP (IN-PLACE) ----------------
__global__ void __launch_bounds__(256) e4_kernel(float* __restrict__ x1,
                                                 float* __restrict__ vecacc,
                                                 const float* __restrict__ vec1,
                                                 const float* __restrict__ vdot,
                                                 const short* __restrict__ xvh_h,
                                                 const short* __restrict__ xvh_l) {
    int idx = blockIdx.x * 256 + threadIdx.x;
    int n = idx >> 8, h = idx & 255;
    long b0 = (long)n * 768 + h;
    float xv1 = b2f(xvh_h[b0])       + b2f(xvh_l[b0]);
    float xv2 = b2f(xvh_h[b0 + 256]) + b2f(xvh_l[b0 + 256]);
    float xv3 = b2f(xvh_h[b0 + 512]) + b2f(xvh_l[b0 + 512]);
    x1[idx] = x1[idx] + (xv1 + xv2 * vdot[idx]) * INV_SQRT_2f;
    #pragma unroll
    for (int d = 0; d < 3; d++) {
        long r = (long)(n * 3 + d) * 256 + h;
        vecacc[r] = vecacc[r] + xv3 * vec1[r];
    }
}

// ---------------- norm over d + concat(x fp32, norm) fp32 ----------------
__global__ void __launch_bounds__(256) normcat_kernel(const float* __restrict__ xin,
                                                      const short* __restrict__ w,
                                                      float* __restrict__ cat,
                                                      int Cx, int C, int shift) {
    int idx = blockIdx.x * 256 + threadIdx.x;
    int cols = 1 << shift;
    int n = idx >> shift, c = idx & (cols - 1);
    float v;
    if (c < Cx) {
        v = xin[(long)n * Cx + c];
    } else {
        int cc = c - Cx;
        float s = 0.f;
        #pragma unroll
        for (int d = 0; d < 3; d++) {
            float a = b2f(w[(long)(n * 3 + d) * C + cc]);
            s += a * a;
        }
        v = sqrtf(s);
    }
    cat[idx] = v;
}

// ---------------- gated block 1 epilogue (fp32 in/out) ----------------
__global__ void __launch_bounds__(256) gate1_kernel(const float* __restrict__ h1,
                                                    const float* __restrict__ w2,
                                                    float* __restrict__ x3,
                                                    float* __restrict__ vecC) {
    int idx = blockIdx.x * 256 + threadIdx.x;
    int n = idx >> 7, c = idx & 127;
    x3[idx] = ssilu_f(h1[(long)n * 256 + c]);
    float vn = h1[(long)n * 256 + 128 + c];
    #pragma unroll
    for (int d = 0; d < 3; d++) {
        long r = (long)(n * 3 + d) * 128 + c;
        vecC[r] = vn * w2[r];
    }
}

// ---------------- vecC @ o2_Wv2 (K=128, Nc=1): one wave per row ----------------
__global__ void __launch_bounds__(256) g12_kernel(const float* __restrict__ vecC,
                                                  const float* __restrict__ Wv2,
                                                  float* __restrict__ w4) {
    int row = blockIdx.x * 4 + (threadIdx.x >> 6);
    int lane = threadIdx.x & 63;
    long r0 = (long)row * 128 + lane;
    float s = vecC[r0] * Wv2[lane] + vecC[r0 + 64] * Wv2[64 + lane];
    #pragma unroll
    for (int off = 32; off > 0; off >>= 1) s += __shfl_down(s, off);
    if (lane == 0) w4[row] = s;
}

// ---------------- final: out[n,d] = (t5[n,:]@Wu2[:,1] + b2[1]) * w4[n,d] ----------
__global__ void __launch_bounds__(256) final_kernel(const float* __restrict__ t5,
                                                    const float* __restrict__ Wu2,
                                                    const float* __restrict__ bu2,
                                                    const float* __restrict__ w4,
                                                    float* __restrict__ out) {
    int n = blockIdx.x * 4 + (threadIdx.x >> 6);
    int lane = threadIdx.x & 63;
    float s = t5[(long)n * 128 + lane] * Wu2[lane * 2 + 1] +
              t5[(long)n * 128 + 64 + lane] * Wu2[(64 + lane) * 2 + 1];
    #pragma unroll
    for (int off = 32; off > 0; off >>= 1) s += __shfl_down(s, off);
    float val = __shfl(s, 0) + bu2[1];
    if (lane < 3) out[(long)n * 3 + lane] = val * w4[(long)n * 3 + lane];
}

extern "C" void kernel_launch(void* const* d_in, const int* in_sizes, int n_in,
                              void* d_out, int out_size, void* d_ws, size_t ws_size,
                              hipStream_t stream) {
    const float* x          = (const float*)d_in[0];
    const float* vec        = (const float*)d_in[1];
    const float* edge_rbf   = (const float*)d_in[2];
    const float* edge_vector= (const float*)d_in[3];
    const float* ln_g       = (const float*)d_in[4];
    const float* ln_b       = (const float*)d_in[5];
    const float* W_x1       = (const float*)d_in[6];
    const float* b_x1       = (const float*)d_in[7];
    const float* W_x2       = (const float*)d_in[8];
    const float* b_x2       = (const float*)d_in[9];
    const float* W_rbf      = (const float*)d_in[10];
    const float* b_rbf      = (const float*)d_in[11];
    const float* W_vp       = (const float*)d_in[12];
    const float* W_xv1      = (const float*)d_in[13];
    const float* b_xv1      = (const float*)d_in[14];
    const float* W_xv2      = (const float*)d_in[15];
    const float* b_xv2      = (const float*)d_in[16];
    const float* o1_Wv1     = (const float*)d_in[17];
    const float* o1_Wv2     = (const float*)d_in[18];
    const float* o1_Wu1     = (const float*)d_in[19];
    const float* o1_bu1     = (const float*)d_in[20];
    const float* o1_Wu2     = (const float*)d_in[21];
    const float* o1_bu2     = (const float*)d_in[22];
    const float* o2_Wv1     = (const float*)d_in[23];
    const float* o2_Wv2     = (const float*)d_in[24];
    const float* o2_Wu1     = (const float*)d_in[25];
    const float* o2_bu1     = (const float*)d_in[26];
    const float* o2_Wu2     = (const float*)d_in[27];
    const float* o2_bu2     = (const float*)d_in[28];
    const int*   edge_index = (const int*)d_in[29];
    float* out = (float*)d_out;
    float* ws  = (float*)d_ws;

    const size_t S = (size_t)NN * 256;
    const size_t Q = S / 4;              // 1,048,576 floats = 4 MiB
    // ---- arena in units of Q; peak 52Q = 208 MiB (proven safe) ----
    float* x1      = ws;                     // Q0-3   (fp32 S)
    float* vecacc  = ws + 4 * Q;             // Q4-15  (fp32 3S)
    short* wtb     = (short*)(ws + 16 * Q);  // Q16-17 weights hi + lo
    const long WLO = 1114112;
    // phase 1 (all fp32 now)
    float* xln   = ws + 18 * Q;              // Q18-21 (fp32 S, dead after t1 gemm)
    float* t1    = ws + 22 * Q;              // Q22-25 (fp32 S, dead after xh gemm)
    float* xh    = ws + 30 * Q;              // Q30-41 (fp32 3S, dead after gather)
    // phase 2 sort scratch (dead before vdot is written)
    int* rowptr    = (int*)(ws + 48 * Q);    // NN+1
    int* cursor    = rowptr + (NN + 1);      // NN
    int* perm      = cursor + NN;            // EE
    int* dsts      = perm + EE;              // EE
    int* srcs      = dsts + EE;              // EE
    float* evs     = (float*)(srcs + EE);    // 3*EE
    // phase 3
    float* vec1  = ws + 30 * Q;              // Q30-41 (fp32 3S, live till e4)
    short* vec2b = (short*)(ws + 42 * Q);    // Q42-47 (bf16 3S)
    float* vdot  = ws + 48 * Q;              // Q48-51 (fp32 S, live till e4)
    float* cat   = ws + 18 * Q;              // Q18-25 (fp32 2S; xln/t1 dead)
    float* t2    = ws + 26 * Q;              // Q26-29 (fp32 S)
    short* xvh_h = (short*)(ws + 18 * Q);    // Q18-23 (cat dead after xv1 gemm)
    short* xvh_l = (short*)(ws + 42 * Q);    // Q42-47 (vec2b dead after vdot_cat)
    // phase 4
    short* w1b   = (short*)(ws + 30 * Q);    // Q30-35 (bf16 3S; vec1 dead after e4)
    float* w2    = ws + 36 * Q;              // Q36-41 (fp32 3*NN*128)
    float* cat2  = ws + 42 * Q;              // Q42-49 (fp32 2S; xvh_l/vdot dead)
    float* t4    = ws + 18 * Q;              // Q18-21 (fp32 S; xvh_h dead)
    float* h1    = ws + 22 * Q;              // Q22-25 (fp32 S)
    float* x3    = ws + 26 * Q;              // Q26-27 (fp32 S/2)
    float* vecC  = ws + 28 * Q;              // Q28-33 (fp32 3*NN*128)
    // phase 5
    short* w3b   = (short*)(ws + 34 * Q);    // Q34-36 (bf16 3*NN*128)
    float* w4    = ws + 37 * Q;              // Q37
    float* cat3  = ws + 38 * Q;              // Q38-41 (fp32 NN*256)
    float* t5    = ws + 42 * Q;              // Q42-43

    // weight hi/lo offsets (shorts)
    short* WT_x1    = wtb;
    short* WT_x2    = wtb + 65536;
    short* WT_vp    = wtb + 262144;          // [n<512][k<256] contiguous -> fused vp
    short* WT_xv1   = wtb + 393216;
    short* WT_xv2   = wtb + 524288;
    short* WT_o1Wv1 = wtb + 720896;          // [n<256][k<256]; o1Wv2 follows -> fused N=384
    short* WT_o1Wv2 = wtb + 786432;
    short* WT_o1Wu1 = wtb + 819200;
    short* WT_o1Wu2 = wtb + 950272;
    short* WT_o2Wv1 = wtb + 1015808;
    short* WT_o2Wu1 = wtb + 1032192;
    short* WT_rbf   = wtb + 1064960;         // 768 x 64

    // Phase 0: all weight transposes + splits in one launch (incl. W_rbf^T)
    WtArgs wa;
    const float* wsrc[12] = {W_x1, W_x2, W_vp, W_xv1, W_xv2, o1_Wv1, o1_Wv2,
                             o1_Wu1, o1_Wu2, o2_Wv1, o2_Wu1, W_rbf};
    int wk[12] = {256, 256, 256, 512, 256, 256, 256, 512, 256, 128, 256, 64};
    int wn[12] = {256, 768, 512, 256, 768, 256, 128, 256, 256, 128, 128, 768};
    int off = 0;
    for (int i = 0; i < 12; i++) {
        wa.W[i] = wsrc[i]; wa.K[i] = wk[i]; wa.N[i] = wn[i];
        wa.off[i] = off; off += wk[i] * wn[i];
    }
    wa.off[12] = off;  // 1,114,112
    wt_split_all<<<off / 256, 256, 0, stream>>>(wa, wtb, wtb + WLO);

    // init vec accumulation target (x1 = x is folded into ln_kernel)
    hipMemcpyAsync(vecacc, vec, 3 * S * sizeof(float), hipMemcpyDeviceToDevice, stream);

    // Phase 1: node MLP (+ x1 init)
    ln_kernel<<<NN, 256, 0, stream>>>(x, ln_g, ln_b, xln, x1);
    mfma_gemm<<<dim3(NN / 128, 4), 256, 0, stream>>>(xln, WT_x1, WT_x1 + WLO,
                                                     b_x1, t1, nullptr, NN, 256, 256, 1);
    mfma_gemm<<<dim3(NN / 128, 12), 256, 0, stream>>>(t1, WT_x2, WT_x2 + WLO,
                                                      b_x2, xh, nullptr, NN, 256, 768, 0);

    // Phase 2: sort edges by dst; edge-parallel fused gather (atomics)
    zero_kernel<<<(NN + 255) / 256, 256, 0, stream>>>(cursor, NN);
    hist_kernel<<<EE / 256, 256, 0, stream>>>(edge_index, cursor);
    scan_kernel<<<1, 256, 0, stream>>>(cursor, rowptr);
    scatter_kernel<<<EE / 256, 256, 0, stream>>>(edge_index, edge_vector, cursor,
                                                 perm, dsts, srcs, evs);
    edge_gather_kernel<<<EE / 128, 512, 0, stream>>>(
        edge_rbf, WT_rbf, WT_rbf + WLO, b_rbf, xh, vec,
        perm, dsts, srcs, evs, x1, vecacc);

    // Phase 3: fused vp (N=512: cols<256 -> fp32 vec1, >=256 -> bf16 vec2b)
    mfma_gemm<<<dim3(3 * NN / 128, 8), 256, 0, stream>>>(vecacc, WT_vp, WT_vp + WLO,
                                                         nullptr, vec1, vec2b,
                                                         3 * NN, 256, 512, 4);
    vdot_cat_kernel<<<NN, 256, 0, stream>>>(vec1, vec2b, x1, vdot, cat);
    mfma_gemm<<<dim3(NN / 128, 4), 256, 0, stream>>>(cat, WT_xv1, WT_xv1 + WLO,
                                                     b_xv1, t2, nullptr, NN, 512, 256, 1);
    mfma_gemm<<<dim3(NN / 128, 12), 256, 0, stream>>>(t2, WT_xv2, WT_xv2 + WLO,
                                                      b_xv2, xvh_h, xvh_l, NN, 256, 768, 3);
    e4_kernel<<<NN, 256, 0, stream>>>(x1, vecacc, vec1, vdot, xvh_h, xvh_l);

    // Phase 4: fused o1Wv (N=384: cols<256 -> bf16 w1b, >=256 -> fp32 w2)
    mfma_gemm<<<dim3(3 * NN / 128, 6), 256, 0, stream>>>(vecacc, WT_o1Wv1, WT_o1Wv1 + WLO,
                                                         nullptr, w1b, w2,
                                                         3 * NN, 256, 384, 5);
    normcat_kernel<<<NN * 512 / 256, 256, 0, stream>>>(x1, w1b, cat2, 256, 256, 9);
    mfma_gemm<<<dim3(NN / 128, 4), 256, 0, stream>>>(cat2, WT_o1Wu1, WT_o1Wu1 + WLO,
                                                     o1_bu1, t4, nullptr, NN, 512, 256, 1);
    mfma_gemm<<<dim3(NN / 128, 4), 256, 0, stream>>>(t4, WT_o1Wu2, WT_o1Wu2 + WLO,
                                                     o1_bu2, h1, nullptr, NN, 256, 256, 0);
    gate1_kernel<<<NN * 128 / 256, 256, 0, stream>>>(h1, w2, x3, vecC);

    // Phase 5: gated equivariant block 2 + output
    mfma_gemm<<<dim3(3 * NN / 128, 2), 256, 0, stream>>>(vecC, WT_o2Wv1, WT_o2Wv1 + WLO,
                                                         nullptr, w3b, nullptr,
                                                         3 * NN, 128, 128, 2);
    g12_kernel<<<3 * NN / 4, 256, 0, stream>>>(vecC, o2_Wv2, w4);
    normcat_kernel<<<NN * 256 / 256, 256, 0, stream>>>(x3, w3b, cat3, 128, 128, 8);
    mfma_gemm<<<dim3(NN / 128, 2), 256, 0, stream>>>(cat3, WT_o2Wu1, WT_o2Wu1 + WLO,
                                                     o2_bu1, t5, nullptr, NN, 256, 128, 1);
    final_kernel<<<NN / 4, 256, 0, stream>>>(t5, o2_Wu2, o2_bu2, w4, out);
}